// Round 1
// baseline (1952.163 us; speedup 1.0000x reference)
//
#include <hip/hip_runtime.h>
#include <hip/hip_cooperative_groups.h>

namespace cg = cooperative_groups;

#define NN 2048          // nodes
#define MD 1024          // mem/input dim
#define NOUT 4096        // 3M (iou) + M (f) output columns

typedef __attribute__((ext_vector_type(8))) short short8;   // 8 x bf16 fragment
typedef __attribute__((ext_vector_type(4))) float f4;

__device__ __forceinline__ unsigned short f2bf(float f) {
  unsigned u = __float_as_uint(f);
  u += 0x7fffu + ((u >> 16) & 1u);      // RNE
  return (unsigned short)(u >> 16);
}
__device__ __forceinline__ float sigm(float x) { return 1.0f / (1.0f + __expf(-x)); }
__device__ __forceinline__ float tanh_(float x) { return 1.0f - 2.0f / (1.0f + __expf(2.0f * x)); }

// ---------------- fp32 -> bf16 conversion (vector x4) ----------------
__global__ __launch_bounds__(256) void cvt_bf16_kernel(const float* __restrict__ s,
                                                       unsigned short* __restrict__ d, int n4) {
  int i = blockIdx.x * 256 + threadIdx.x;
  if (i < n4) {
    f4 v = *((const f4*)s + i);
    unsigned lo = f2bf(v[0]) | ((unsigned)f2bf(v[1]) << 16);
    unsigned hi = f2bf(v[2]) | ((unsigned)f2bf(v[3]) << 16);
    uint2 r; r.x = lo; r.y = hi;
    *((uint2*)d + i) = r;
  }
}

// ---------------- prep: depth (pointer doubling) + counting sorts ----------------
__global__ __launch_bounds__(1024) void prep_kernel(const int* __restrict__ parent,
                                                    int* __restrict__ order_d,
                                                    int* __restrict__ doff,
                                                    int* __restrict__ order_p,
                                                    int* __restrict__ poff,
                                                    int* __restrict__ maxd_out) {
  __shared__ int s_anc[NN], s_anc2[NN];
  __shared__ int s_dep[NN], s_dep2[NN];
  __shared__ int s_cnt[NN + 3];
  __shared__ int s_sc1[NN + 3], s_sc2[NN + 3];
  __shared__ int s_maxd;
  const int tid = threadIdx.x;

  for (int t = tid; t < NN; t += 1024) {
    int pv = parent[t];                 // in (t, NN-1] for t<NN-1 ; NN for root
    bool root = (t == NN - 1);
    s_anc[t] = root ? (NN - 1) : pv;    // root self-loops
    s_dep[t] = root ? 0 : 1;
  }
  if (tid == 0) s_maxd = 0;
  __syncthreads();

  for (int it = 0; it < 11; ++it) {     // 2^11 >= NN
    for (int t = tid; t < NN; t += 1024) {
      int a = s_anc[t];
      s_dep2[t] = s_dep[t] + s_dep[a];
      s_anc2[t] = s_anc[a];
    }
    __syncthreads();
    for (int t = tid; t < NN; t += 1024) { s_dep[t] = s_dep2[t]; s_anc[t] = s_anc2[t]; }
    __syncthreads();
  }
  for (int t = tid; t < NN; t += 1024) atomicMax(&s_maxd, s_dep[t]);

  // ---- sort nodes by depth ----
  for (int i = tid; i < NN + 3; i += 1024) s_cnt[i] = 0;
  __syncthreads();
  for (int t = tid; t < NN; t += 1024) atomicAdd(&s_cnt[s_dep[t]], 1);
  __syncthreads();
  {
    const int L = NN + 1;               // depth values 0..NN-1, scan L entries
    for (int i = tid; i < L; i += 1024) s_sc1[i] = s_cnt[i];
    __syncthreads();
    int* src = s_sc1; int* dst = s_sc2;
    for (int o = 1; o < L; o <<= 1) {
      for (int i = tid; i < L; i += 1024) dst[i] = src[i] + ((i >= o) ? src[i - o] : 0);
      __syncthreads();
      int* tmp = src; src = dst; dst = tmp;
    }
    for (int i = tid; i < L + 1; i += 1024) {
      int v = (i == 0) ? 0 : src[i - 1];
      doff[i] = v;
      if (i < L) s_cnt[i] = v;          // cursor
    }
    __syncthreads();
    for (int t = tid; t < NN; t += 1024) {
      int pos = atomicAdd(&s_cnt[s_dep[t]], 1);
      order_d[pos] = t;
    }
    __syncthreads();
  }

  // ---- sort nodes by parent (children of p contiguous: [poff[p], poff[p+1])) ----
  for (int i = tid; i < NN + 3; i += 1024) s_cnt[i] = 0;
  __syncthreads();
  for (int t = tid; t < NN; t += 1024) atomicAdd(&s_cnt[parent[t]], 1);
  __syncthreads();
  {
    const int L = NN + 2;               // parent values 1..NN
    for (int i = tid; i < L; i += 1024) s_sc1[i] = s_cnt[i];
    __syncthreads();
    int* src = s_sc1; int* dst = s_sc2;
    for (int o = 1; o < L; o <<= 1) {
      for (int i = tid; i < L; i += 1024) dst[i] = src[i] + ((i >= o) ? src[i - o] : 0);
      __syncthreads();
      int* tmp = src; src = dst; dst = tmp;
    }
    for (int i = tid; i < L; i += 1024) {
      int v = (i == 0) ? 0 : src[i - 1];
      poff[i] = v;
      s_cnt[i] = v;                     // cursor
    }
    __syncthreads();
    for (int t = tid; t < NN; t += 1024) {
      int pos = atomicAdd(&s_cnt[parent[t]], 1);
      order_p[pos] = t;
    }
    __syncthreads();
  }
  if (tid == 0) *maxd_out = s_maxd;
}

// ---------------- bf16 MFMA 64x64 tile (B^T GEMM), single-buffered LDS ----------------
// C[row, col] = sum_k A[row,k] * B[col,k]   (A rows optionally gathered)
template <bool GATHER>
__device__ void gemm_tile(const unsigned short* __restrict__ A,
                          const int* __restrict__ rowidx, int nrows,
                          int m0, const unsigned short* __restrict__ B, int n0,
                          float* __restrict__ C,
                          const float* __restrict__ bias0, const float* __restrict__ bias1,
                          unsigned short* ldsA, unsigned short* ldsB) {
  const int tid = threadIdx.x;
  const int lane = tid & 63;
  const int wave = tid >> 6;
  const int wr = wave >> 1, wc = wave & 1;     // 2x2 wave grid, 32x32 per wave
  f4 acc[2][2] = {};
  const int sr = tid >> 2;                     // staging row 0..63
  const int sc = (tid & 3) << 3;               // staging col chunk (8 bf16)
  int ar = m0 + sr;
  int arow;
  if (GATHER) arow = rowidx[(ar < nrows) ? ar : 0];
  else        arow = (ar < nrows) ? ar : 0;
  const unsigned short* agp = A + (size_t)arow * MD + sc;
  const unsigned short* bgp = B + (size_t)(n0 + sr) * MD + sc;
  const int lr = lane & 15;
  const int kq = (lane >> 4) << 3;             // k-quarter: 8 contiguous bf16 per lane

  for (int k0 = 0; k0 < MD; k0 += 32) {
    uint4 av = *(const uint4*)(agp + k0);
    uint4 bv = *(const uint4*)(bgp + k0);
    __syncthreads();
    *(uint4*)&ldsA[sr * 40 + sc] = av;         // row stride 40 (80B) to spread banks
    *(uint4*)&ldsB[sr * 40 + sc] = bv;
    __syncthreads();
    short8 a0 = *(const short8*)&ldsA[(wr * 32 + lr) * 40 + kq];
    short8 a1 = *(const short8*)&ldsA[(wr * 32 + 16 + lr) * 40 + kq];
    short8 b0 = *(const short8*)&ldsB[(wc * 32 + lr) * 40 + kq];
    short8 b1 = *(const short8*)&ldsB[(wc * 32 + 16 + lr) * 40 + kq];
    acc[0][0] = __builtin_amdgcn_mfma_f32_16x16x32_bf16(a0, b0, acc[0][0], 0, 0, 0);
    acc[0][1] = __builtin_amdgcn_mfma_f32_16x16x32_bf16(a0, b1, acc[0][1], 0, 0, 0);
    acc[1][0] = __builtin_amdgcn_mfma_f32_16x16x32_bf16(a1, b0, acc[1][0], 0, 0, 0);
    acc[1][1] = __builtin_amdgcn_mfma_f32_16x16x32_bf16(a1, b1, acc[1][1], 0, 0, 0);
  }
  // C/D layout (m89): col = lane&15, row = (lane>>4)*4 + reg
  for (int r = 0; r < 2; ++r)
    for (int c = 0; c < 2; ++c)
      for (int q = 0; q < 4; ++q) {
        int row = m0 + wr * 32 + r * 16 + (lane >> 4) * 4 + q;
        int col = n0 + wc * 32 + c * 16 + lr;
        if (row < nrows) {
          float v = acc[r][c][q];
          if (bias0) v += (col < 3072) ? bias0[col] : bias1[col - 3072];
          int crow = GATHER ? rowidx[row] : row;
          C[(size_t)crow * NOUT + col] = v;
        }
      }
}

// ---------------- pre-GEMM: XW = Xbf16 @ [Wioux;Wfx]^T + [bioux;bfx] ----------------
__global__ __launch_bounds__(256) void pregemm_kernel(const unsigned short* __restrict__ Xb,
                                                      const unsigned short* __restrict__ Wb,
                                                      float* __restrict__ XW,
                                                      const float* __restrict__ bioux,
                                                      const float* __restrict__ bfx) {
  __shared__ alignas(16) unsigned short ldsA[64 * 40];
  __shared__ alignas(16) unsigned short ldsB[64 * 40];
  int tn = blockIdx.x & 63;
  int tm = blockIdx.x >> 6;
  gemm_tile<false>(Xb, nullptr, NN, tm * 64, Wb, tn * 64, XW, bioux, bfx, ldsA, ldsB);
}

// ---------------- cooperative depth-wavefront recurrence ----------------
struct RP {
  const int* doff;
  const int* order_d;
  const int* poff;
  const int* order_p;
  const int* maxd;
  const float* XW;          // [NN, 4096]: cols 0..3071 ioux_all(+bias), 3072..4095 fx_all(+bias)
  float* G;                 // [NN, 4096]: per-node h @ [Wiouh;Wfh]^T
  unsigned short* Hb;       // [NN, 1024] bf16 h
  float* Cb;                // [NN, 1024] fp32 c
  const unsigned short* Wrec; // [4096,1024] bf16 [Wiouh;Wfh]
  const float* biouh;
  const float* bfh;
  float* out;               // [2048]: c_root | h_root
};

__global__ __launch_bounds__(256) void recur_kernel(RP p) {
  cg::grid_group grid = cg::this_grid();
  __shared__ alignas(16) unsigned short ldsA[64 * 40];
  __shared__ alignas(16) unsigned short ldsB[64 * 40];
  const int maxd = *p.maxd;
  const int gstride = gridDim.x * 256;

  for (int d = maxd; d >= 0; --d) {
    const int beg = p.doff[d], end = p.doff[d + 1];
    const int nd = end - beg;

    // -------- Phase A: elementwise gates for depth-d nodes --------
    // task = (node i, 4-col group j)
    const int ntask = nd * 256;
    for (int idx = blockIdx.x * 256 + threadIdx.x; idx < ntask; idx += gstride) {
      const int i = idx >> 8;
      const int j = (idx & 255) << 2;
      const int t = p.order_d[beg + i];
      const float* xw = p.XW + (size_t)t * NOUT;
      f4 ai = *(const f4*)(xw + j)        + *(const f4*)(p.biouh + j);
      f4 ao = *(const f4*)(xw + 1024 + j) + *(const f4*)(p.biouh + 1024 + j);
      f4 au = *(const f4*)(xw + 2048 + j) + *(const f4*)(p.biouh + 2048 + j);
      f4 fxv = *(const f4*)(xw + 3072 + j) + *(const f4*)(p.bfh + j); // fx_all[t] + bfh
      f4 fc = {0.f, 0.f, 0.f, 0.f};
      const int cb = p.poff[t], ce = p.poff[t + 1];
      for (int k = cb; k < ce; ++k) {        // children (exactly depth d+1, G/Cb ready)
        const int u = p.order_p[k];
        const float* gu = p.G + (size_t)u * NOUT;
        ai += *(const f4*)(gu + j);
        ao += *(const f4*)(gu + 1024 + j);
        au += *(const f4*)(gu + 2048 + j);
        f4 gf = *(const f4*)(gu + 3072 + j);
        f4 cu = *(const f4*)(p.Cb + (size_t)u * MD + j);
        for (int q = 0; q < 4; ++q) fc[q] += sigm(gf[q] + fxv[q]) * cu[q];
      }
      f4 cvv, hvv;
      for (int q = 0; q < 4; ++q) {
        float iv = sigm(ai[q]);
        float ov = sigm(ao[q]);
        float uv = tanh_(au[q]);
        float cv = iv * uv + fc[q];
        float hv = ov * tanh_(cv);
        cvv[q] = cv; hvv[q] = hv;
      }
      *(f4*)(p.Cb + (size_t)t * MD + j) = cvv;
      unsigned lo = f2bf(hvv[0]) | ((unsigned)f2bf(hvv[1]) << 16);
      unsigned hi = f2bf(hvv[2]) | ((unsigned)f2bf(hvv[3]) << 16);
      uint2 hp; hp.x = lo; hp.y = hi;
      *(uint2*)(p.Hb + (size_t)t * MD + j) = hp;
      if (t == NN - 1) {                     // root: write output (c | h) fp32
        *(f4*)(p.out + j) = cvv;
        *(f4*)(p.out + 1024 + j) = hvv;
      }
    }
    grid.sync();

    // -------- Phase B: G[level nodes] = h @ [Wiouh;Wfh]^T (skip for root) --------
    if (d > 0) {
      const int mt = (nd + 63) >> 6;
      const int ntile = mt * 64;             // 64 col tiles of 64
      for (int tile = blockIdx.x; tile < ntile; tile += gridDim.x) {
        const int tm = tile >> 6;
        const int tn = tile & 63;
        gemm_tile<true>(p.Hb, p.order_d + beg, nd, tm * 64, p.Wrec, tn * 64,
                        p.G, nullptr, nullptr, ldsA, ldsB);
      }
      grid.sync();
    }
  }
}

// ---------------- launch ----------------
extern "C" void kernel_launch(void* const* d_in, const int* in_sizes, int n_in,
                              void* d_out, int out_size, void* d_ws, size_t ws_size,
                              hipStream_t stream) {
  const float* X     = (const float*)d_in[0];   // [2048,1024]
  const int*   parent= (const int*)d_in[1];     // [2048]
  const float* Wioux = (const float*)d_in[2];   // [3072,1024]
  const float* bioux = (const float*)d_in[3];   // [3072]
  const float* Wiouh = (const float*)d_in[4];   // [3072,1024]
  const float* biouh = (const float*)d_in[5];   // [3072]
  const float* Wfx   = (const float*)d_in[6];   // [1024,1024]
  const float* bfx   = (const float*)d_in[7];   // [1024]
  const float* Wfh   = (const float*)d_in[8];   // [1024,1024]
  const float* bfh   = (const float*)d_in[9];   // [1024]
  float* out = (float*)d_out;

  char* ws = (char*)d_ws;
  size_t o = 0;
  auto alloc = [&](size_t bytes) { size_t r = o; o += (bytes + 255) & ~(size_t)255; return r; };
  unsigned short* Xb   = (unsigned short*)(ws + alloc((size_t)NN * MD * 2));
  unsigned short* Wpre = (unsigned short*)(ws + alloc((size_t)NOUT * MD * 2));
  unsigned short* Wrec = (unsigned short*)(ws + alloc((size_t)NOUT * MD * 2));
  float* XW            = (float*)(ws + alloc((size_t)NN * NOUT * 4));
  float* G             = (float*)(ws + alloc((size_t)NN * NOUT * 4));
  unsigned short* Hb   = (unsigned short*)(ws + alloc((size_t)NN * MD * 2));
  float* Cb            = (float*)(ws + alloc((size_t)NN * MD * 4));
  int* order_d         = (int*)(ws + alloc((NN + 4) * 4));
  int* doff            = (int*)(ws + alloc((NN + 4) * 4));
  int* order_p         = (int*)(ws + alloc((NN + 4) * 4));
  int* poff            = (int*)(ws + alloc((NN + 4) * 4));
  int* maxd            = (int*)(ws + alloc(256));
  // total ~101 MB — relies on ws_size being at least that.

  // bf16 conversions
  {
    int n4;
    n4 = NN * MD / 4;
    cvt_bf16_kernel<<<(n4 + 255) / 256, 256, 0, stream>>>(X, Xb, n4);
    n4 = 3072 * MD / 4;
    cvt_bf16_kernel<<<(n4 + 255) / 256, 256, 0, stream>>>(Wioux, Wpre, n4);
    n4 = 1024 * MD / 4;
    cvt_bf16_kernel<<<(n4 + 255) / 256, 256, 0, stream>>>(Wfx, Wpre + (size_t)3072 * MD, n4);
    n4 = 3072 * MD / 4;
    cvt_bf16_kernel<<<(n4 + 255) / 256, 256, 0, stream>>>(Wiouh, Wrec, n4);
    n4 = 1024 * MD / 4;
    cvt_bf16_kernel<<<(n4 + 255) / 256, 256, 0, stream>>>(Wfh, Wrec + (size_t)3072 * MD, n4);
  }

  prep_kernel<<<1, 1024, 0, stream>>>(parent, order_d, doff, order_p, poff, maxd);

  pregemm_kernel<<<(NN / 64) * (NOUT / 64), 256, 0, stream>>>(Xb, Wpre, XW, bioux, bfx);

  RP p;
  p.doff = doff; p.order_d = order_d; p.poff = poff; p.order_p = order_p; p.maxd = maxd;
  p.XW = XW; p.G = G; p.Hb = Hb; p.Cb = Cb; p.Wrec = Wrec;
  p.biouh = biouh; p.bfh = bfh; p.out = out;
  void* args[] = {&p};
  hipLaunchCooperativeKernel((const void*)recur_kernel, dim3(512), dim3(256), args, 0, stream);

  (void)in_sizes; (void)n_in; (void)out_size; (void)ws_size;
}

// Round 2
// 946.591 us; speedup vs baseline: 2.0623x; 2.0623x over previous
//
#include <hip/hip_runtime.h>
#include <hip/hip_cooperative_groups.h>

namespace cg = cooperative_groups;

#define NN 2048          // nodes
#define MD 1024          // mem/input dim
#define NOUT 4096        // 3M (iou) + M (f) output columns
#define GBLK 128         // cooperative grid blocks (one 32-col W strip each)
#define GTHR 512         // threads per block (8 waves)

typedef __attribute__((ext_vector_type(8))) short short8;   // 8 x bf16 fragment
typedef __attribute__((ext_vector_type(4))) float f4;

__device__ __forceinline__ unsigned short f2bf(float f) {
  unsigned u = __float_as_uint(f);
  u += 0x7fffu + ((u >> 16) & 1u);      // RNE
  return (unsigned short)(u >> 16);
}
__device__ __forceinline__ float sigm(float x) { return 1.0f / (1.0f + __expf(-x)); }
__device__ __forceinline__ float tanh_(float x) { return 1.0f - 2.0f / (1.0f + __expf(2.0f * x)); }

// ---------------- fp32 -> bf16 conversion (vector x4) ----------------
__global__ __launch_bounds__(256) void cvt_bf16_kernel(const float* __restrict__ s,
                                                       unsigned short* __restrict__ d, int n4) {
  int i = blockIdx.x * 256 + threadIdx.x;
  if (i < n4) {
    f4 v = *((const f4*)s + i);
    unsigned lo = f2bf(v[0]) | ((unsigned)f2bf(v[1]) << 16);
    unsigned hi = f2bf(v[2]) | ((unsigned)f2bf(v[3]) << 16);
    uint2 r; r.x = lo; r.y = hi;
    *((uint2*)d + i) = r;
  }
}

// ---------------- combined bias: biasC = [bioux+biouh ; bfx+bfh] ----------------
__global__ __launch_bounds__(256) void bias_combine_kernel(const float* __restrict__ bioux,
                                                           const float* __restrict__ biouh,
                                                           const float* __restrict__ bfx,
                                                           const float* __restrict__ bfh,
                                                           float* __restrict__ biasC) {
  int i = blockIdx.x * 256 + threadIdx.x;
  if (i < 3072) biasC[i] = bioux[i] + biouh[i];
  else if (i < 4096) biasC[i] = bfx[i - 3072] + bfh[i - 3072];
}

// ---------------- prep: depth (pointer doubling) + counting sorts ----------------
__global__ __launch_bounds__(1024) void prep_kernel(const int* __restrict__ parent,
                                                    int* __restrict__ order_d,
                                                    int* __restrict__ doff,
                                                    int* __restrict__ order_p,
                                                    int* __restrict__ poff,
                                                    int* __restrict__ maxd_out) {
  __shared__ int s_anc[NN], s_anc2[NN];
  __shared__ int s_dep[NN], s_dep2[NN];
  __shared__ int s_cnt[NN + 3];
  __shared__ int s_sc1[NN + 3], s_sc2[NN + 3];
  __shared__ int s_maxd;
  const int tid = threadIdx.x;

  for (int t = tid; t < NN; t += 1024) {
    int pv = parent[t];                 // in (t, NN-1] for t<NN-1 ; NN for root
    bool root = (t == NN - 1);
    s_anc[t] = root ? (NN - 1) : pv;    // root self-loops
    s_dep[t] = root ? 0 : 1;
  }
  if (tid == 0) s_maxd = 0;
  __syncthreads();

  for (int it = 0; it < 11; ++it) {     // 2^11 >= NN
    for (int t = tid; t < NN; t += 1024) {
      int a = s_anc[t];
      s_dep2[t] = s_dep[t] + s_dep[a];
      s_anc2[t] = s_anc[a];
    }
    __syncthreads();
    for (int t = tid; t < NN; t += 1024) { s_dep[t] = s_dep2[t]; s_anc[t] = s_anc2[t]; }
    __syncthreads();
  }
  for (int t = tid; t < NN; t += 1024) atomicMax(&s_maxd, s_dep[t]);

  // ---- sort nodes by depth ----
  for (int i = tid; i < NN + 3; i += 1024) s_cnt[i] = 0;
  __syncthreads();
  for (int t = tid; t < NN; t += 1024) atomicAdd(&s_cnt[s_dep[t]], 1);
  __syncthreads();
  {
    const int L = NN + 1;
    for (int i = tid; i < L; i += 1024) s_sc1[i] = s_cnt[i];
    __syncthreads();
    int* src = s_sc1; int* dst = s_sc2;
    for (int o = 1; o < L; o <<= 1) {
      for (int i = tid; i < L; i += 1024) dst[i] = src[i] + ((i >= o) ? src[i - o] : 0);
      __syncthreads();
      int* tmp = src; src = dst; dst = tmp;
    }
    for (int i = tid; i < L + 1; i += 1024) {
      int v = (i == 0) ? 0 : src[i - 1];
      doff[i] = v;
      if (i < L) s_cnt[i] = v;          // cursor
    }
    __syncthreads();
    for (int t = tid; t < NN; t += 1024) {
      int pos = atomicAdd(&s_cnt[s_dep[t]], 1);
      order_d[pos] = t;
    }
    __syncthreads();
  }

  // ---- sort nodes by parent (children of p contiguous: [poff[p], poff[p+1])) ----
  for (int i = tid; i < NN + 3; i += 1024) s_cnt[i] = 0;
  __syncthreads();
  for (int t = tid; t < NN; t += 1024) atomicAdd(&s_cnt[parent[t]], 1);
  __syncthreads();
  {
    const int L = NN + 2;
    for (int i = tid; i < L; i += 1024) s_sc1[i] = s_cnt[i];
    __syncthreads();
    int* src = s_sc1; int* dst = s_sc2;
    for (int o = 1; o < L; o <<= 1) {
      for (int i = tid; i < L; i += 1024) dst[i] = src[i] + ((i >= o) ? src[i - o] : 0);
      __syncthreads();
      int* tmp = src; src = dst; dst = tmp;
    }
    for (int i = tid; i < L; i += 1024) {
      int v = (i == 0) ? 0 : src[i - 1];
      poff[i] = v;
      s_cnt[i] = v;                     // cursor
    }
    __syncthreads();
    for (int t = tid; t < NN; t += 1024) {
      int pos = atomicAdd(&s_cnt[parent[t]], 1);
      order_p[pos] = t;
    }
    __syncthreads();
  }
  if (tid == 0) *maxd_out = s_maxd;
}

// ---------------- bf16 MFMA 64x64 tile (B^T GEMM) for the pre-GEMM ----------------
__device__ void gemm_tile(const unsigned short* __restrict__ A, int nrows,
                          int m0, const unsigned short* __restrict__ B, int n0,
                          float* __restrict__ C, const float* __restrict__ biasC,
                          unsigned short* ldsA, unsigned short* ldsB) {
  const int tid = threadIdx.x;
  const int lane = tid & 63;
  const int wave = tid >> 6;
  const int wr = wave >> 1, wc = wave & 1;     // 2x2 wave grid, 32x32 per wave
  f4 acc[2][2] = {};
  const int sr = tid >> 2;                     // staging row 0..63
  const int sc = (tid & 3) << 3;               // staging col chunk (8 bf16)
  int ar = m0 + sr;
  int arow = (ar < nrows) ? ar : 0;
  const unsigned short* agp = A + (size_t)arow * MD + sc;
  const unsigned short* bgp = B + (size_t)(n0 + sr) * MD + sc;
  const int lr = lane & 15;
  const int kq = (lane >> 4) << 3;             // k-quarter: 8 contiguous bf16 per lane

  for (int k0 = 0; k0 < MD; k0 += 32) {
    uint4 av = *(const uint4*)(agp + k0);
    uint4 bv = *(const uint4*)(bgp + k0);
    __syncthreads();
    *(uint4*)&ldsA[sr * 40 + sc] = av;         // row stride 40 (80B) to spread banks
    *(uint4*)&ldsB[sr * 40 + sc] = bv;
    __syncthreads();
    short8 a0 = *(const short8*)&ldsA[(wr * 32 + lr) * 40 + kq];
    short8 a1 = *(const short8*)&ldsA[(wr * 32 + 16 + lr) * 40 + kq];
    short8 b0 = *(const short8*)&ldsB[(wc * 32 + lr) * 40 + kq];
    short8 b1 = *(const short8*)&ldsB[(wc * 32 + 16 + lr) * 40 + kq];
    acc[0][0] = __builtin_amdgcn_mfma_f32_16x16x32_bf16(a0, b0, acc[0][0], 0, 0, 0);
    acc[0][1] = __builtin_amdgcn_mfma_f32_16x16x32_bf16(a0, b1, acc[0][1], 0, 0, 0);
    acc[1][0] = __builtin_amdgcn_mfma_f32_16x16x32_bf16(a1, b0, acc[1][0], 0, 0, 0);
    acc[1][1] = __builtin_amdgcn_mfma_f32_16x16x32_bf16(a1, b1, acc[1][1], 0, 0, 0);
  }
  // C/D layout (m89): col = lane&15, row = (lane>>4)*4 + reg
  for (int r = 0; r < 2; ++r)
    for (int c = 0; c < 2; ++c)
      for (int q = 0; q < 4; ++q) {
        int row = m0 + wr * 32 + r * 16 + (lane >> 4) * 4 + q;
        int col = n0 + wc * 32 + c * 16 + lr;
        if (row < nrows) C[(size_t)row * NOUT + col] = acc[r][c][q] + biasC[col];
      }
}

// XW = Xbf16 @ [Wioux;Wfx]^T + biasC  (biasC already includes biouh/bfh folding)
__global__ __launch_bounds__(256) void pregemm_kernel(const unsigned short* __restrict__ Xb,
                                                      const unsigned short* __restrict__ Wb,
                                                      float* __restrict__ XW,
                                                      const float* __restrict__ biasC) {
  __shared__ alignas(16) unsigned short ldsA[64 * 40];
  __shared__ alignas(16) unsigned short ldsB[64 * 40];
  int tn = blockIdx.x & 63;
  int tm = blockIdx.x >> 6;
  gemm_tile(Xb, NN, tm * 64, Wb, tn * 64, XW, biasC, ldsA, ldsB);
}

// ---------------- cooperative depth-wavefront recurrence, W LDS-resident ----------------
struct RP {
  const int* doff;
  const int* order_d;
  const int* poff;
  const int* order_p;
  const int* maxd;
  const float* XW;            // [NN,4096]: iou(+bioux+biouh) | fx(+bfx+bfh)
  float* G;                   // [NN,4096]: per-node h @ [Wiouh;Wfh]^T (no bias)
  unsigned short* Hb;         // [NN,1024] bf16 h
  float* Cb;                  // [NN,1024] fp32 c
  const unsigned short* Wrec; // [4096,1024] bf16 [Wiouh;Wfh]
  float* out;                 // [2048]: c_root | h_root
};

// B-phase step: one K=32 slice -> 2 MFMA into the 2 col-tiles, prefetch A 4 ahead
#define BSTEP(AREG, KS) do {                                                    \
    const int kch_ = ((KS) << 2) + kq;                                          \
    short8 b0_ = *(const short8*)(wb0 + ((kch_ ^ swz) << 3));                   \
    short8 b1_ = *(const short8*)(wb1 + ((kch_ ^ swz) << 3));                   \
    acc0 = __builtin_amdgcn_mfma_f32_16x16x32_bf16(AREG, b0_, acc0, 0, 0, 0);   \
    acc1 = __builtin_amdgcn_mfma_f32_16x16x32_bf16(AREG, b1_, acc1, 0, 0, 0);   \
    if ((KS) + 4 < 32) AREG = *(const short8*)(ap + (((KS) + 4) << 5));         \
  } while (0)

__global__ __launch_bounds__(GTHR) void recur_kernel(RP p) {
  cg::grid_group grid = cg::this_grid();
  __shared__ alignas(16) unsigned short ldsW[32 * MD];   // 64 KiB W strip, swizzled
  const int tid = threadIdx.x;
  const int bid = blockIdx.x;
  const int lane = tid & 63;
  const int wave = tid >> 6;

  // Stage W strip once: G-cols [32*bid, 32*bid+32), all 1024 k.
  // 16B chunk (c, kc) stored at chunk index (kc ^ (c&7)) within row c.
  for (int idx = tid; idx < 32 * 128; idx += GTHR) {
    int c = idx >> 7, kc = idx & 127;
    uint4 v = *(const uint4*)(p.Wrec + (size_t)((bid << 5) + c) * MD + (kc << 3));
    *(uint4*)(ldsW + c * MD + ((kc ^ (c & 7)) << 3)) = v;
  }
  __syncthreads();

  const int maxd = *p.maxd;
  const int gid = bid * GTHR + tid;
  const int gstride = GBLK * GTHR;

  for (int d = maxd; d >= 0; --d) {
    const int beg = p.doff[d];
    const int nd = p.doff[d + 1] - beg;

    // -------- Phase A: gates for depth-d nodes; thread = (node i, 8 cols j) --------
    const int ntask = nd << 7;
    for (int idx = gid; idx < ntask; idx += gstride) {
      const int i = idx >> 7;
      const int j = (idx & 127) << 3;
      const int t = p.order_d[beg + i];
      const float* xw = p.XW + (size_t)t * NOUT;
      f4 ai0 = *(const f4*)(xw + j),        ai1 = *(const f4*)(xw + j + 4);
      f4 ao0 = *(const f4*)(xw + 1024 + j), ao1 = *(const f4*)(xw + 1028 + j);
      f4 au0 = *(const f4*)(xw + 2048 + j), au1 = *(const f4*)(xw + 2052 + j);
      f4 fx0 = *(const f4*)(xw + 3072 + j), fx1 = *(const f4*)(xw + 3076 + j);
      f4 fc0 = {0.f, 0.f, 0.f, 0.f}, fc1 = {0.f, 0.f, 0.f, 0.f};
      for (int k = p.poff[t], ke = p.poff[t + 1]; k < ke; ++k) {
        const int u = p.order_p[k];            // child (depth d+1: G, Cb ready)
        const float* gu = p.G + (size_t)u * NOUT;
        ai0 += *(const f4*)(gu + j);        ai1 += *(const f4*)(gu + j + 4);
        ao0 += *(const f4*)(gu + 1024 + j); ao1 += *(const f4*)(gu + 1028 + j);
        au0 += *(const f4*)(gu + 2048 + j); au1 += *(const f4*)(gu + 2052 + j);
        f4 gf0 = *(const f4*)(gu + 3072 + j), gf1 = *(const f4*)(gu + 3076 + j);
        const float* cu = p.Cb + (size_t)u * MD + j;
        f4 cu0 = *(const f4*)cu, cu1 = *(const f4*)(cu + 4);
        #pragma unroll
        for (int q = 0; q < 4; ++q) {
          fc0[q] += sigm(gf0[q] + fx0[q]) * cu0[q];
          fc1[q] += sigm(gf1[q] + fx1[q]) * cu1[q];
        }
      }
      f4 cv0, cv1, hv0, hv1;
      #pragma unroll
      for (int q = 0; q < 4; ++q) {
        float c0 = sigm(ai0[q]) * tanh_(au0[q]) + fc0[q];
        float c1 = sigm(ai1[q]) * tanh_(au1[q]) + fc1[q];
        cv0[q] = c0; cv1[q] = c1;
        hv0[q] = sigm(ao0[q]) * tanh_(c0);
        hv1[q] = sigm(ao1[q]) * tanh_(c1);
      }
      *(f4*)(p.Cb + (size_t)t * MD + j) = cv0;
      *(f4*)(p.Cb + (size_t)t * MD + j + 4) = cv1;
      uint4 hp;
      hp.x = f2bf(hv0[0]) | ((unsigned)f2bf(hv0[1]) << 16);
      hp.y = f2bf(hv0[2]) | ((unsigned)f2bf(hv0[3]) << 16);
      hp.z = f2bf(hv1[0]) | ((unsigned)f2bf(hv1[1]) << 16);
      hp.w = f2bf(hv1[2]) | ((unsigned)f2bf(hv1[3]) << 16);
      *(uint4*)(p.Hb + (size_t)t * MD + j) = hp;
      if (t == NN - 1) {                       // root: output (c | h) fp32
        *(f4*)(p.out + j) = cv0;  *(f4*)(p.out + j + 4) = cv1;
        *(f4*)(p.out + 1024 + j) = hv0;  *(f4*)(p.out + 1028 + j) = hv1;
      }
    }
    grid.sync();

    // -------- Phase B: G[level] = h @ Wstrip^T, barrier-free, W from LDS --------
    if (d > 0) {
      const int ntr = (nd + 15) >> 4;
      const int lr = lane & 15;
      const int kq = lane >> 4;                 // 0..3
      const int kqo = kq << 3;                  // a-frag k offset within 32
      const int swz = lr & 7;
      const unsigned short* wb0 = ldsW + lr * MD;            // col-tile 0: col lr
      const unsigned short* wb1 = wb0 + 16 * MD;             // col-tile 1: col 16+lr
      for (int rt = wave; rt < ntr; rt += 8) {
        const int r = (rt << 4) + lr;
        const int node = p.order_d[beg + ((r < nd) ? r : 0)];
        const unsigned short* ap = p.Hb + (size_t)node * MD + kqo;
        short8 a0 = *(const short8*)(ap);
        short8 a1 = *(const short8*)(ap + 32);
        short8 a2 = *(const short8*)(ap + 64);
        short8 a3 = *(const short8*)(ap + 96);
        f4 acc0 = {0.f, 0.f, 0.f, 0.f}, acc1 = {0.f, 0.f, 0.f, 0.f};
        #pragma unroll
        for (int kb = 0; kb < 32; kb += 4) {
          BSTEP(a0, kb);
          BSTEP(a1, kb + 1);
          BSTEP(a2, kb + 2);
          BSTEP(a3, kb + 3);
        }
        // C/D: col = lane&15, row = (lane>>4)*4 + q
        const int rbase = (rt << 4) + (kq << 2);
        #pragma unroll
        for (int q = 0; q < 4; ++q) {
          const int rr = rbase + q;
          if (rr < nd) {
            const int nw = p.order_d[beg + rr];
            float* gr = p.G + (size_t)nw * NOUT + (bid << 5) + lr;
            gr[0]  = acc0[q];
            gr[16] = acc1[q];
          }
        }
      }
      grid.sync();
    }
  }
}

// ---------------- launch ----------------
extern "C" void kernel_launch(void* const* d_in, const int* in_sizes, int n_in,
                              void* d_out, int out_size, void* d_ws, size_t ws_size,
                              hipStream_t stream) {
  const float* X     = (const float*)d_in[0];   // [2048,1024]
  const int*   parent= (const int*)d_in[1];     // [2048]
  const float* Wioux = (const float*)d_in[2];   // [3072,1024]
  const float* bioux = (const float*)d_in[3];   // [3072]
  const float* Wiouh = (const float*)d_in[4];   // [3072,1024]
  const float* biouh = (const float*)d_in[5];   // [3072]
  const float* Wfx   = (const float*)d_in[6];   // [1024,1024]
  const float* bfx   = (const float*)d_in[7];   // [1024]
  const float* Wfh   = (const float*)d_in[8];   // [1024,1024]
  const float* bfh   = (const float*)d_in[9];   // [1024]
  float* out = (float*)d_out;

  char* ws = (char*)d_ws;
  size_t o = 0;
  auto alloc = [&](size_t bytes) { size_t r = o; o += (bytes + 255) & ~(size_t)255; return r; };
  unsigned short* Xb   = (unsigned short*)(ws + alloc((size_t)NN * MD * 2));
  unsigned short* Wpre = (unsigned short*)(ws + alloc((size_t)NOUT * MD * 2));
  unsigned short* Wrec = (unsigned short*)(ws + alloc((size_t)NOUT * MD * 2));
  float* XW            = (float*)(ws + alloc((size_t)NN * NOUT * 4));
  float* G             = (float*)(ws + alloc((size_t)NN * NOUT * 4));
  unsigned short* Hb   = (unsigned short*)(ws + alloc((size_t)NN * MD * 2));
  float* Cb            = (float*)(ws + alloc((size_t)NN * MD * 4));
  float* biasC         = (float*)(ws + alloc((size_t)NOUT * 4));
  int* order_d         = (int*)(ws + alloc((NN + 4) * 4));
  int* doff            = (int*)(ws + alloc((NN + 4) * 4));
  int* order_p         = (int*)(ws + alloc((NN + 4) * 4));
  int* poff            = (int*)(ws + alloc((NN + 4) * 4));
  int* maxd            = (int*)(ws + alloc(256));

  // bf16 conversions
  {
    int n4;
    n4 = NN * MD / 4;
    cvt_bf16_kernel<<<(n4 + 255) / 256, 256, 0, stream>>>(X, Xb, n4);
    n4 = 3072 * MD / 4;
    cvt_bf16_kernel<<<(n4 + 255) / 256, 256, 0, stream>>>(Wioux, Wpre, n4);
    n4 = 1024 * MD / 4;
    cvt_bf16_kernel<<<(n4 + 255) / 256, 256, 0, stream>>>(Wfx, Wpre + (size_t)3072 * MD, n4);
    n4 = 3072 * MD / 4;
    cvt_bf16_kernel<<<(n4 + 255) / 256, 256, 0, stream>>>(Wiouh, Wrec, n4);
    n4 = 1024 * MD / 4;
    cvt_bf16_kernel<<<(n4 + 255) / 256, 256, 0, stream>>>(Wfh, Wrec + (size_t)3072 * MD, n4);
  }

  bias_combine_kernel<<<16, 256, 0, stream>>>(bioux, biouh, bfx, bfh, biasC);

  prep_kernel<<<1, 1024, 0, stream>>>(parent, order_d, doff, order_p, poff, maxd);

  pregemm_kernel<<<(NN / 64) * (NOUT / 64), 256, 0, stream>>>(Xb, Wpre, XW, biasC);

  RP p;
  p.doff = doff; p.order_d = order_d; p.poff = poff; p.order_p = order_p; p.maxd = maxd;
  p.XW = XW; p.G = G; p.Hb = Hb; p.Cb = Cb; p.Wrec = Wrec; p.out = out;
  void* args[] = {&p};
  hipLaunchCooperativeKernel((const void*)recur_kernel, dim3(GBLK), dim3(GTHR), args, 0, stream);

  (void)in_sizes; (void)n_in; (void)out_size; (void)ws_size;
}

// Round 3
// 687.700 us; speedup vs baseline: 2.8387x; 1.3765x over previous
//
#include <hip/hip_runtime.h>

#define NN 2048          // nodes
#define MD 1024          // mem/input dim
#define NOUT 4096        // 3M (iou) + M (f) output columns
#define GBLK 128         // cooperative grid blocks (8 cols of each gate per block)
#define GTHR 512         // threads per block (8 waves)

typedef __attribute__((ext_vector_type(8))) short short8;   // 8 x bf16 fragment
typedef __attribute__((ext_vector_type(4))) float f4;

__device__ __forceinline__ unsigned short f2bf(float f) {
  unsigned u = __float_as_uint(f);
  u += 0x7fffu + ((u >> 16) & 1u);      // RNE
  return (unsigned short)(u >> 16);
}
__device__ __forceinline__ float sigm(float x) { return 1.0f / (1.0f + __expf(-x)); }
__device__ __forceinline__ float tanh_(float x) { return 1.0f - 2.0f / (1.0f + __expf(2.0f * x)); }

// ---------------- fp32 -> bf16 conversion (vector x4) ----------------
__global__ __launch_bounds__(256) void cvt_bf16_kernel(const float* __restrict__ s,
                                                       unsigned short* __restrict__ d, int n4) {
  int i = blockIdx.x * 256 + threadIdx.x;
  if (i < n4) {
    f4 v = *((const f4*)s + i);
    unsigned lo = f2bf(v[0]) | ((unsigned)f2bf(v[1]) << 16);
    unsigned hi = f2bf(v[2]) | ((unsigned)f2bf(v[3]) << 16);
    uint2 r; r.x = lo; r.y = hi;
    *((uint2*)d + i) = r;
  }
}

// ---------------- combined bias: biasC = [bioux+biouh ; bfx+bfh] ----------------
__global__ __launch_bounds__(256) void bias_combine_kernel(const float* __restrict__ bioux,
                                                           const float* __restrict__ biouh,
                                                           const float* __restrict__ bfx,
                                                           const float* __restrict__ bfh,
                                                           float* __restrict__ biasC) {
  int i = blockIdx.x * 256 + threadIdx.x;
  if (i < 3072) biasC[i] = bioux[i] + biouh[i];
  else if (i < 4096) biasC[i] = bfx[i - 3072] + bfh[i - 3072];
}

// ---------------- prep: depth, parent-sort, BFS parent-grouped level order ----------------
// meta[pos] = (node, child_begin_pos, child_count, 0); doff[d] = level start positions.
__global__ __launch_bounds__(1024) void prep_kernel(const int* __restrict__ parent,
                                                    int4* __restrict__ meta,
                                                    int* __restrict__ doff_g,
                                                    int* __restrict__ maxd_out,
                                                    int* __restrict__ sync_cnt) {
  __shared__ int s_anc[NN], s_dep[NN];
  __shared__ int s_t1[NN + 2], s_t2[NN + 2];
  __shared__ int s_poff[NN + 2], s_cur[NN + 2];
  __shared__ int s_ordp[NN], s_nord[NN];
  __shared__ int s_doff[NN + 2];
  __shared__ int s_sc[NN], s_sc2[NN];
  __shared__ int s_wsum[17];
  __shared__ int s_maxd;
  const int tid = threadIdx.x;

  if (tid == 0) { s_maxd = 0; *sync_cnt = 0; }
  for (int t = tid; t < NN; t += 1024) {
    bool root = (t == NN - 1);
    s_anc[t] = root ? t : parent[t];
    s_dep[t] = root ? 0 : 1;
  }
  __syncthreads();
  for (int it = 0; it < 11; ++it) {     // 2^11 >= NN
    for (int t = tid; t < NN; t += 1024) { int a = s_anc[t]; s_t1[t] = s_dep[t] + s_dep[a]; s_t2[t] = s_anc[a]; }
    __syncthreads();
    for (int t = tid; t < NN; t += 1024) { s_dep[t] = s_t1[t]; s_anc[t] = s_t2[t]; }
    __syncthreads();
  }
  for (int t = tid; t < NN; t += 1024) atomicMax(&s_maxd, s_dep[t]);

  // ---- counting sort by parent -> s_ordp with offsets s_poff ----
  for (int i = tid; i < NN + 2; i += 1024) s_t2[i] = 0;
  __syncthreads();
  for (int t = tid; t < NN; t += 1024) atomicAdd(&s_t2[parent[t]], 1);
  __syncthreads();
  {
    const int L = NN + 2;
    int* src = s_t2; int* dst = s_t1;
    for (int o = 1; o < L; o <<= 1) {
      for (int i = tid; i < L; i += 1024) dst[i] = src[i] + ((i >= o) ? src[i - o] : 0);
      __syncthreads();
      int* tmp = src; src = dst; dst = tmp;
    }
    for (int i = tid; i < L; i += 1024) { int v = (i ? src[i - 1] : 0); s_poff[i] = v; s_cur[i] = v; }
    __syncthreads();
    for (int t = tid; t < NN; t += 1024) {
      int pos = atomicAdd(&s_cur[parent[t]], 1);
      s_ordp[pos] = t;
    }
    __syncthreads();
    // determinism: sort each parent's bucket ascending (buckets are small)
    for (int p = tid; p < NN + 1; p += 1024) {
      int b = s_poff[p], e = s_poff[p + 1];
      for (int i = b + 1; i < e; ++i) {
        int v = s_ordp[i], j = i - 1;
        while (j >= b && s_ordp[j] > v) { s_ordp[j + 1] = s_ordp[j]; --j; }
        s_ordp[j + 1] = v;
      }
    }
    __syncthreads();
  }

  // ---- counts by depth -> s_doff ----
  for (int i = tid; i < NN + 2; i += 1024) s_t2[i] = 0;
  __syncthreads();
  for (int t = tid; t < NN; t += 1024) atomicAdd(&s_t2[s_dep[t]], 1);
  __syncthreads();
  {
    const int L = NN + 1;
    int* src = s_t2; int* dst = s_t1;
    for (int o = 1; o < L; o <<= 1) {
      for (int i = tid; i < L; i += 1024) dst[i] = src[i] + ((i >= o) ? src[i - o] : 0);
      __syncthreads();
      int* tmp = src; src = dst; dst = tmp;
    }
    for (int i = tid; i < L + 1; i += 1024) s_doff[i] = (i ? src[i - 1] : 0);
    __syncthreads();
  }

  // ---- BFS: parent-grouped order per level ----
  const int maxd = s_maxd;
  if (tid == 0) s_nord[0] = NN - 1;     // root at position 0
  __syncthreads();
  for (int d = 0; d < maxd; ++d) {
    const int lbeg = s_doff[d], lend = s_doff[d + 1];
    const int nd = lend - lbeg;
    if (nd <= 1024) {
      int t = -1, v = 0;
      if (tid < nd) { t = s_nord[lbeg + tid]; v = s_poff[t + 1] - s_poff[t]; }
      #pragma unroll
      for (int o = 1; o < 64; o <<= 1) {
        int u = __shfl_up(v, (unsigned)o, 64);
        if ((tid & 63) >= o) v += u;
      }
      if ((tid & 63) == 63) s_wsum[tid >> 6] = v;
      __syncthreads();
      if (tid < 16) {
        int w = s_wsum[tid];
        #pragma unroll
        for (int o = 1; o < 16; o <<= 1) {
          int u = __shfl_up(w, (unsigned)o, 16);
          if (tid >= o) w += u;
        }
        s_wsum[tid] = w;
      }
      __syncthreads();
      if (tid < nd) {
        int incl = v + ((tid >> 6) ? s_wsum[(tid >> 6) - 1] : 0);
        int cnti = s_poff[t + 1] - s_poff[t];
        int cb = lend + incl - cnti;
        meta[lbeg + tid] = make_int4(t, cb, cnti, 0);
        for (int j = 0; j < cnti; ++j) s_nord[cb + j] = s_ordp[s_poff[t] + j];
      }
      __syncthreads();
    } else {                             // fallback (pathological trees)
      for (int i = tid; i < nd; i += 1024) { int t2 = s_nord[lbeg + i]; s_sc[i] = s_poff[t2 + 1] - s_poff[t2]; }
      __syncthreads();
      for (int o = 1; o < nd; o <<= 1) {
        for (int i = tid; i < nd; i += 1024) s_sc2[i] = s_sc[i] + ((i >= o) ? s_sc[i - o] : 0);
        __syncthreads();
        for (int i = tid; i < nd; i += 1024) s_sc[i] = s_sc2[i];
        __syncthreads();
      }
      for (int i = tid; i < nd; i += 1024) {
        int t2 = s_nord[lbeg + i];
        int cnti = s_poff[t2 + 1] - s_poff[t2];
        int cb = lend + s_sc[i] - cnti;
        meta[lbeg + i] = make_int4(t2, cb, cnti, 0);
        for (int j = 0; j < cnti; ++j) s_nord[cb + j] = s_ordp[s_poff[t2] + j];
      }
      __syncthreads();
    }
  }
  {                                      // deepest level: all leaves
    const int lbeg = s_doff[maxd], lend = s_doff[maxd + 1];
    for (int i = lbeg + tid; i < lend; i += 1024)
      meta[i] = make_int4(s_nord[i], 0, 0, 0);
  }
  for (int i = tid; i <= maxd + 1; i += 1024) doff_g[i] = s_doff[i];
  if (tid == 0) *maxd_out = maxd;
}

// ---------------- bf16 MFMA 64x64 tile (B^T GEMM) for the pre-GEMM ----------------
__device__ void gemm_tile(const unsigned short* __restrict__ A, int nrows,
                          int m0, const unsigned short* __restrict__ B, int n0,
                          float* __restrict__ C, const float* __restrict__ biasC,
                          unsigned short* ldsA, unsigned short* ldsB) {
  const int tid = threadIdx.x;
  const int lane = tid & 63;
  const int wave = tid >> 6;
  const int wr = wave >> 1, wc = wave & 1;
  f4 acc[2][2] = {};
  const int sr = tid >> 2;
  const int sc = (tid & 3) << 3;
  int ar = m0 + sr;
  int arow = (ar < nrows) ? ar : 0;
  const unsigned short* agp = A + (size_t)arow * MD + sc;
  const unsigned short* bgp = B + (size_t)(n0 + sr) * MD + sc;
  const int lr = lane & 15;
  const int kq = (lane >> 4) << 3;

  for (int k0 = 0; k0 < MD; k0 += 32) {
    uint4 av = *(const uint4*)(agp + k0);
    uint4 bv = *(const uint4*)(bgp + k0);
    __syncthreads();
    *(uint4*)&ldsA[sr * 40 + sc] = av;
    *(uint4*)&ldsB[sr * 40 + sc] = bv;
    __syncthreads();
    short8 a0 = *(const short8*)&ldsA[(wr * 32 + lr) * 40 + kq];
    short8 a1 = *(const short8*)&ldsA[(wr * 32 + 16 + lr) * 40 + kq];
    short8 b0 = *(const short8*)&ldsB[(wc * 32 + lr) * 40 + kq];
    short8 b1 = *(const short8*)&ldsB[(wc * 32 + 16 + lr) * 40 + kq];
    acc[0][0] = __builtin_amdgcn_mfma_f32_16x16x32_bf16(a0, b0, acc[0][0], 0, 0, 0);
    acc[0][1] = __builtin_amdgcn_mfma_f32_16x16x32_bf16(a0, b1, acc[0][1], 0, 0, 0);
    acc[1][0] = __builtin_amdgcn_mfma_f32_16x16x32_bf16(a1, b0, acc[1][0], 0, 0, 0);
    acc[1][1] = __builtin_amdgcn_mfma_f32_16x16x32_bf16(a1, b1, acc[1][1], 0, 0, 0);
  }
  for (int r = 0; r < 2; ++r)
    for (int c = 0; c < 2; ++c)
      for (int q = 0; q < 4; ++q) {
        int row = m0 + wr * 32 + r * 16 + (lane >> 4) * 4 + q;
        int col = n0 + wc * 32 + c * 16 + lr;
        if (row < nrows) C[(size_t)row * NOUT + col] = acc[r][c][q] + biasC[col];
      }
}

__global__ __launch_bounds__(256) void pregemm_kernel(const unsigned short* __restrict__ Xb,
                                                      const unsigned short* __restrict__ Wb,
                                                      float* __restrict__ XW,
                                                      const float* __restrict__ biasC) {
  __shared__ alignas(16) unsigned short ldsA[64 * 40];
  __shared__ alignas(16) unsigned short ldsB[64 * 40];
  int tn = blockIdx.x & 63;
  int tm = blockIdx.x >> 6;
  gemm_tile(Xb, NN, tm * 64, Wb, tn * 64, XW, biasC, ldsA, ldsB);
}

// ---------------- cooperative recurrence: 1 grid sync per level ----------------
struct RP {
  const int4* meta;           // [NN] (node, cbeg_pos, cnt, 0)
  const int* doff;            // [NN+2]
  const int* maxd;
  const float* XW;            // [NN][4096] x-side preactivation (+ all biases)
  float* G2;                  // [GBLK][NN][32] block-local: h @ Wstrip^T, position-indexed
  float* CbB;                 // [GBLK][NN][8]  block-local c values (block's 8 cols)
  unsigned short* Hb;         // [NN][1024] bf16 h (global handoff)
  const unsigned short* Wrec; // [4096][1024] bf16 [Wiouh;Wfh]
  float* out;                 // [2048]: c_root | h_root
  int* sync_cnt;
};

__device__ __forceinline__ void gsync(int* cnt, int target) {
  __syncthreads();                       // compiler drains vmcnt before s_barrier
  if (threadIdx.x == 0) {
    __hip_atomic_fetch_add(cnt, 1, __ATOMIC_RELEASE, __HIP_MEMORY_SCOPE_AGENT);
    while (__hip_atomic_load(cnt, __ATOMIC_RELAXED, __HIP_MEMORY_SCOPE_AGENT) < target)
      __builtin_amdgcn_s_sleep(2);
    (void)__hip_atomic_load(cnt, __ATOMIC_ACQUIRE, __HIP_MEMORY_SCOPE_AGENT);
  }
  __syncthreads();
}

// one K=32 slice -> 2 MFMA into the 2 col-tiles, prefetch A 4 ahead
#define BSTEP(AREG, KS) do {                                                    \
    const int kch_ = ((KS) << 2) + kq;                                          \
    short8 b0_ = *(const short8*)(wb0 + ((kch_ ^ swz) << 3));                   \
    short8 b1_ = *(const short8*)(wb1 + ((kch_ ^ swz) << 3));                   \
    acc0 = __builtin_amdgcn_mfma_f32_16x16x32_bf16(AREG, b0_, acc0, 0, 0, 0);   \
    acc1 = __builtin_amdgcn_mfma_f32_16x16x32_bf16(AREG, b1_, acc1, 0, 0, 0);   \
    if ((KS) + 4 < 32) AREG = *(const short8*)(ap + (((KS) + 4) << 5));         \
  } while (0)

__global__ __launch_bounds__(GTHR) void recur_kernel(RP p) {
  // LDS: W strip (32 rows: 8 cols x 4 gates) + meta + doff survive all syncs
  __shared__ alignas(16) unsigned short ldsW[32 * MD];   // 64 KiB
  __shared__ int4 ldsMeta[NN];                           // 32 KiB
  __shared__ int ldsDoff[NN + 2];                        // 8 KiB
  const int tid = threadIdx.x;
  const int bid = blockIdx.x;
  const int lane = tid & 63;
  const int wave = tid >> 6;

  // Stage W strip: LDS row j (0..31) = global W row (j>>3)*1024 + 8*bid + (j&7).
  // 16B chunk kc stored at (kc ^ (j&7)) within the row (bank swizzle).
  for (int idx = tid; idx < 32 * 128; idx += GTHR) {
    int j = idx >> 7, kc = idx & 127;
    uint4 v = *(const uint4*)(p.Wrec +
        (size_t)((j >> 3) * MD + (bid << 3) + (j & 7)) * MD + (kc << 3));
    *(uint4*)(ldsW + j * MD + ((kc ^ (j & 7)) << 3)) = v;
  }
  const int maxd = *p.maxd;
  for (int i = tid; i < NN; i += GTHR) ldsMeta[i] = p.meta[i];
  for (int i = tid; i <= maxd + 1; i += GTHR) ldsDoff[i] = p.doff[i];
  __syncthreads();

  float* G2b  = p.G2  + (size_t)bid * NN * 32;
  float* CbBb = p.CbB + (size_t)bid * NN * 8;
  const int c = tid & 7;
  const int colbase = (bid << 3) + c;    // this thread's h-column (0..1023)
  int step = 0;

  for (int d = maxd; d >= 0; --d) {
    const int lbeg = ldsDoff[d], lend = ldsDoff[d + 1];
    const int nd = lend - lbeg;

    // ---- cell for level d: 8 cols per block, all local reads (G2b/CbB warm L2) ----
    for (int ii = tid >> 3; ii < nd; ii += GTHR / 8) {
      const int pos = lbeg + ii;
      const int4 mt = ldsMeta[pos];
      const int t = mt.x, cbeg = mt.y, cnt = mt.z;
      const float* xw = p.XW + (size_t)t * NOUT + colbase;
      float gi = xw[0];
      float go = xw[1024];
      float gu = xw[2048];
      float gf = xw[3072];
      float fc = 0.f;
      for (int k = 0; k < cnt; ++k) {
        const float* g2 = G2b + (size_t)(cbeg + k) * 32 + c;
        gi += g2[0];
        go += g2[8];
        gu += g2[16];
        fc += sigm(g2[24] + gf) * CbBb[(size_t)(cbeg + k) * 8 + c];
      }
      const float cv = sigm(gi) * tanh_(gu) + fc;
      const float hv = sigm(go) * tanh_(cv);
      CbBb[(size_t)pos * 8 + c] = cv;
      p.Hb[(size_t)t * MD + colbase] = f2bf(hv);
      if (d == 0) { p.out[colbase] = cv; p.out[MD + colbase] = hv; }
    }
    if (d == 0) break;

    // ---- single grid sync: h of level d now visible everywhere ----
    ++step;
    gsync(p.sync_cnt, step * GBLK);

    // ---- gemm: G2b[pos][0..31] = h[node(pos)] @ Wstrip^T for level-d positions ----
    {
      const int ntr = (nd + 15) >> 4;
      const int lr = lane & 15;
      const int kq = lane >> 4;
      const int kqo = kq << 3;
      const int swz = lr & 7;
      const unsigned short* wb0 = ldsW + lr * MD;
      const unsigned short* wb1 = wb0 + 16 * MD;
      for (int rt = wave; rt < ntr; rt += GTHR / 64) {
        const int r = (rt << 4) + lr;
        const int pos = lbeg + ((r < nd) ? r : 0);
        const int node = ldsMeta[pos].x;
        const unsigned short* ap = p.Hb + (size_t)node * MD + kqo;
        short8 a0 = *(const short8*)(ap);
        short8 a1 = *(const short8*)(ap + 32);
        short8 a2 = *(const short8*)(ap + 64);
        short8 a3 = *(const short8*)(ap + 96);
        f4 acc0 = {0.f, 0.f, 0.f, 0.f}, acc1 = {0.f, 0.f, 0.f, 0.f};
        #pragma unroll
        for (int kb = 0; kb < 32; kb += 4) {
          BSTEP(a0, kb);
          BSTEP(a1, kb + 1);
          BSTEP(a2, kb + 2);
          BSTEP(a3, kb + 3);
        }
        // C/D: col = lane&15, row = (lane>>4)*4 + q
        const int rb = (rt << 4) + (kq << 2);
        #pragma unroll
        for (int q = 0; q < 4; ++q) {
          const int rr = rb + q;
          if (rr < nd) {
            float* gr = G2b + (size_t)(lbeg + rr) * 32 + lr;
            gr[0]  = acc0[q];
            gr[16] = acc1[q];
          }
        }
      }
    }
    __syncthreads();   // block-local handoff to next cell (no grid sync needed)
  }
}

// ---------------- launch ----------------
extern "C" void kernel_launch(void* const* d_in, const int* in_sizes, int n_in,
                              void* d_out, int out_size, void* d_ws, size_t ws_size,
                              hipStream_t stream) {
  const float* X     = (const float*)d_in[0];
  const int*   parent= (const int*)d_in[1];
  const float* Wioux = (const float*)d_in[2];
  const float* bioux = (const float*)d_in[3];
  const float* Wiouh = (const float*)d_in[4];
  const float* biouh = (const float*)d_in[5];
  const float* Wfx   = (const float*)d_in[6];
  const float* bfx   = (const float*)d_in[7];
  const float* Wfh   = (const float*)d_in[8];
  const float* bfh   = (const float*)d_in[9];
  float* out = (float*)d_out;

  char* ws = (char*)d_ws;
  size_t o = 0;
  auto alloc = [&](size_t bytes) { size_t r = o; o += (bytes + 255) & ~(size_t)255; return r; };
  unsigned short* Xb   = (unsigned short*)(ws + alloc((size_t)NN * MD * 2));
  unsigned short* Wpre = (unsigned short*)(ws + alloc((size_t)NOUT * MD * 2));
  unsigned short* Wrec = (unsigned short*)(ws + alloc((size_t)NOUT * MD * 2));
  float* XW            = (float*)(ws + alloc((size_t)NN * NOUT * 4));
  float* G2            = (float*)(ws + alloc((size_t)GBLK * NN * 32 * 4));
  float* CbB           = (float*)(ws + alloc((size_t)GBLK * NN * 8 * 4));
  unsigned short* Hb   = (unsigned short*)(ws + alloc((size_t)NN * MD * 2));
  float* biasC         = (float*)(ws + alloc((size_t)NOUT * 4));
  int4* meta           = (int4*)(ws + alloc((size_t)NN * 16));
  int* doff            = (int*)(ws + alloc((NN + 4) * 4));
  int* maxd            = (int*)(ws + alloc(256));
  int* sync_cnt        = (int*)(ws + alloc(256));

  {
    int n4;
    n4 = NN * MD / 4;
    cvt_bf16_kernel<<<(n4 + 255) / 256, 256, 0, stream>>>(X, Xb, n4);
    n4 = 3072 * MD / 4;
    cvt_bf16_kernel<<<(n4 + 255) / 256, 256, 0, stream>>>(Wioux, Wpre, n4);
    n4 = 1024 * MD / 4;
    cvt_bf16_kernel<<<(n4 + 255) / 256, 256, 0, stream>>>(Wfx, Wpre + (size_t)3072 * MD, n4);
    n4 = 3072 * MD / 4;
    cvt_bf16_kernel<<<(n4 + 255) / 256, 256, 0, stream>>>(Wiouh, Wrec, n4);
    n4 = 1024 * MD / 4;
    cvt_bf16_kernel<<<(n4 + 255) / 256, 256, 0, stream>>>(Wfh, Wrec + (size_t)3072 * MD, n4);
  }

  bias_combine_kernel<<<16, 256, 0, stream>>>(bioux, biouh, bfx, bfh, biasC);

  prep_kernel<<<1, 1024, 0, stream>>>(parent, meta, doff, maxd, sync_cnt);

  pregemm_kernel<<<(NN / 64) * (NOUT / 64), 256, 0, stream>>>(Xb, Wpre, XW, biasC);

  RP p;
  p.meta = meta; p.doff = doff; p.maxd = maxd;
  p.XW = XW; p.G2 = G2; p.CbB = CbB; p.Hb = Hb; p.Wrec = Wrec;
  p.out = out; p.sync_cnt = sync_cnt;
  void* args[] = {&p};
  hipLaunchCooperativeKernel((const void*)recur_kernel, dim3(GBLK), dim3(GTHR), args, 0, stream);

  (void)in_sizes; (void)n_in; (void)out_size; (void)ws_size;
}

// Round 4
// 621.574 us; speedup vs baseline: 3.1407x; 1.1064x over previous
//
#include <hip/hip_runtime.h>

#define NN 2048          // nodes
#define MD 1024          // mem/input dim
#define NOUT 4096        // 3M (iou) + M (f) output columns
#define GBLK 128         // cooperative grid blocks (8 cols of each gate per block)
#define GTHR 512         // threads per block (8 waves)

typedef __attribute__((ext_vector_type(8))) short short8;   // 8 x bf16 fragment
typedef __attribute__((ext_vector_type(4))) float f4;

__device__ __forceinline__ unsigned short f2bf(float f) {
  unsigned u = __float_as_uint(f);
  u += 0x7fffu + ((u >> 16) & 1u);      // RNE
  return (unsigned short)(u >> 16);
}
__device__ __forceinline__ float sigm(float x) { return 1.0f / (1.0f + __expf(-x)); }
__device__ __forceinline__ float tanh_(float x) { return 1.0f - 2.0f / (1.0f + __expf(2.0f * x)); }

// ---------------- fp32 -> bf16 conversion (vector x4) ----------------
__global__ __launch_bounds__(256) void cvt_bf16_kernel(const float* __restrict__ s,
                                                       unsigned short* __restrict__ d, int n4) {
  int i = blockIdx.x * 256 + threadIdx.x;
  if (i < n4) {
    f4 v = *((const f4*)s + i);
    unsigned lo = f2bf(v[0]) | ((unsigned)f2bf(v[1]) << 16);
    unsigned hi = f2bf(v[2]) | ((unsigned)f2bf(v[3]) << 16);
    uint2 r; r.x = lo; r.y = hi;
    *((uint2*)d + i) = r;
  }
}

// ---------------- combined bias: biasC = [bioux+biouh ; bfx+bfh] ----------------
__global__ __launch_bounds__(256) void bias_combine_kernel(const float* __restrict__ bioux,
                                                           const float* __restrict__ biouh,
                                                           const float* __restrict__ bfx,
                                                           const float* __restrict__ bfh,
                                                           float* __restrict__ biasC) {
  int i = blockIdx.x * 256 + threadIdx.x;
  if (i < 3072) biasC[i] = bioux[i] + biouh[i];
  else if (i < 4096) biasC[i] = bfx[i - 3072] + bfh[i - 3072];
}

// ---------------- prep: depth, parent-sort, BFS parent-grouped level order ----------------
// meta[pos] = (node, child_begin_pos, child_count, 0); doff[d] = level start positions.
__global__ __launch_bounds__(1024) void prep_kernel(const int* __restrict__ parent,
                                                    int4* __restrict__ meta,
                                                    int* __restrict__ doff_g,
                                                    int* __restrict__ maxd_out,
                                                    int* __restrict__ sync_cnt) {
  __shared__ int s_anc[NN], s_dep[NN];
  __shared__ int s_t1[NN + 2], s_t2[NN + 2];
  __shared__ int s_poff[NN + 2], s_cur[NN + 2];
  __shared__ int s_ordp[NN], s_nord[NN];
  __shared__ int s_doff[NN + 2];
  __shared__ int s_sc[NN], s_sc2[NN];
  __shared__ int s_wsum[17];
  __shared__ int s_maxd;
  const int tid = threadIdx.x;

  if (tid == 0) { s_maxd = 0; *sync_cnt = 0; }
  for (int t = tid; t < NN; t += 1024) {
    bool root = (t == NN - 1);
    s_anc[t] = root ? t : parent[t];
    s_dep[t] = root ? 0 : 1;
  }
  __syncthreads();
  for (int it = 0; it < 11; ++it) {     // 2^11 >= NN
    for (int t = tid; t < NN; t += 1024) { int a = s_anc[t]; s_t1[t] = s_dep[t] + s_dep[a]; s_t2[t] = s_anc[a]; }
    __syncthreads();
    for (int t = tid; t < NN; t += 1024) { s_dep[t] = s_t1[t]; s_anc[t] = s_t2[t]; }
    __syncthreads();
  }
  for (int t = tid; t < NN; t += 1024) atomicMax(&s_maxd, s_dep[t]);

  // ---- counting sort by parent -> s_ordp with offsets s_poff ----
  for (int i = tid; i < NN + 2; i += 1024) s_t2[i] = 0;
  __syncthreads();
  for (int t = tid; t < NN; t += 1024) atomicAdd(&s_t2[parent[t]], 1);
  __syncthreads();
  {
    const int L = NN + 2;
    int* src = s_t2; int* dst = s_t1;
    for (int o = 1; o < L; o <<= 1) {
      for (int i = tid; i < L; i += 1024) dst[i] = src[i] + ((i >= o) ? src[i - o] : 0);
      __syncthreads();
      int* tmp = src; src = dst; dst = tmp;
    }
    for (int i = tid; i < L; i += 1024) { int v = (i ? src[i - 1] : 0); s_poff[i] = v; s_cur[i] = v; }
    __syncthreads();
    for (int t = tid; t < NN; t += 1024) {
      int pos = atomicAdd(&s_cur[parent[t]], 1);
      s_ordp[pos] = t;
    }
    __syncthreads();
    // determinism: sort each parent's bucket ascending (buckets are small)
    for (int p = tid; p < NN + 1; p += 1024) {
      int b = s_poff[p], e = s_poff[p + 1];
      for (int i = b + 1; i < e; ++i) {
        int v = s_ordp[i], j = i - 1;
        while (j >= b && s_ordp[j] > v) { s_ordp[j + 1] = s_ordp[j]; --j; }
        s_ordp[j + 1] = v;
      }
    }
    __syncthreads();
  }

  // ---- counts by depth -> s_doff ----
  for (int i = tid; i < NN + 2; i += 1024) s_t2[i] = 0;
  __syncthreads();
  for (int t = tid; t < NN; t += 1024) atomicAdd(&s_t2[s_dep[t]], 1);
  __syncthreads();
  {
    const int L = NN + 1;
    int* src = s_t2; int* dst = s_t1;
    for (int o = 1; o < L; o <<= 1) {
      for (int i = tid; i < L; i += 1024) dst[i] = src[i] + ((i >= o) ? src[i - o] : 0);
      __syncthreads();
      int* tmp = src; src = dst; dst = tmp;
    }
    for (int i = tid; i < L + 1; i += 1024) s_doff[i] = (i ? src[i - 1] : 0);
    __syncthreads();
  }

  // ---- BFS: parent-grouped order per level ----
  const int maxd = s_maxd;
  if (tid == 0) s_nord[0] = NN - 1;     // root at position 0
  __syncthreads();
  for (int d = 0; d < maxd; ++d) {
    const int lbeg = s_doff[d], lend = s_doff[d + 1];
    const int nd = lend - lbeg;
    if (nd <= 1024) {
      int t = -1, v = 0;
      if (tid < nd) { t = s_nord[lbeg + tid]; v = s_poff[t + 1] - s_poff[t]; }
      #pragma unroll
      for (int o = 1; o < 64; o <<= 1) {
        int u = __shfl_up(v, (unsigned)o, 64);
        if ((tid & 63) >= o) v += u;
      }
      if ((tid & 63) == 63) s_wsum[tid >> 6] = v;
      __syncthreads();
      if (tid < 16) {
        int w = s_wsum[tid];
        #pragma unroll
        for (int o = 1; o < 16; o <<= 1) {
          int u = __shfl_up(w, (unsigned)o, 16);
          if (tid >= o) w += u;
        }
        s_wsum[tid] = w;
      }
      __syncthreads();
      if (tid < nd) {
        int incl = v + ((tid >> 6) ? s_wsum[(tid >> 6) - 1] : 0);
        int cnti = s_poff[t + 1] - s_poff[t];
        int cb = lend + incl - cnti;
        meta[lbeg + tid] = make_int4(t, cb, cnti, 0);
        for (int j = 0; j < cnti; ++j) s_nord[cb + j] = s_ordp[s_poff[t] + j];
      }
      __syncthreads();
    } else {                             // fallback (pathological trees)
      for (int i = tid; i < nd; i += 1024) { int t2 = s_nord[lbeg + i]; s_sc[i] = s_poff[t2 + 1] - s_poff[t2]; }
      __syncthreads();
      for (int o = 1; o < nd; o <<= 1) {
        for (int i = tid; i < nd; i += 1024) s_sc2[i] = s_sc[i] + ((i >= o) ? s_sc[i - o] : 0);
        __syncthreads();
        for (int i = tid; i < nd; i += 1024) s_sc[i] = s_sc2[i];
        __syncthreads();
      }
      for (int i = tid; i < nd; i += 1024) {
        int t2 = s_nord[lbeg + i];
        int cnti = s_poff[t2 + 1] - s_poff[t2];
        int cb = lend + s_sc[i] - cnti;
        meta[lbeg + i] = make_int4(t2, cb, cnti, 0);
        for (int j = 0; j < cnti; ++j) s_nord[cb + j] = s_ordp[s_poff[t2] + j];
      }
      __syncthreads();
    }
  }
  {                                      // deepest level: all leaves
    const int lbeg = s_doff[maxd], lend = s_doff[maxd + 1];
    for (int i = lbeg + tid; i < lend; i += 1024)
      meta[i] = make_int4(s_nord[i], 0, 0, 0);
  }
  for (int i = tid; i <= maxd + 1; i += 1024) doff_g[i] = s_doff[i];
  if (tid == 0) *maxd_out = maxd;
}

// ---------------- bf16 MFMA 64x64 tile (B^T GEMM) for the pre-GEMM ----------------
__device__ void gemm_tile(const unsigned short* __restrict__ A, int nrows,
                          int m0, const unsigned short* __restrict__ B, int n0,
                          float* __restrict__ C, const float* __restrict__ biasC,
                          unsigned short* ldsA, unsigned short* ldsB) {
  const int tid = threadIdx.x;
  const int lane = tid & 63;
  const int wave = tid >> 6;
  const int wr = wave >> 1, wc = wave & 1;
  f4 acc[2][2] = {};
  const int sr = tid >> 2;
  const int sc = (tid & 3) << 3;
  int ar = m0 + sr;
  int arow = (ar < nrows) ? ar : 0;
  const unsigned short* agp = A + (size_t)arow * MD + sc;
  const unsigned short* bgp = B + (size_t)(n0 + sr) * MD + sc;
  const int lr = lane & 15;
  const int kq = (lane >> 4) << 3;

  for (int k0 = 0; k0 < MD; k0 += 32) {
    uint4 av = *(const uint4*)(agp + k0);
    uint4 bv = *(const uint4*)(bgp + k0);
    __syncthreads();
    *(uint4*)&ldsA[sr * 40 + sc] = av;
    *(uint4*)&ldsB[sr * 40 + sc] = bv;
    __syncthreads();
    short8 a0 = *(const short8*)&ldsA[(wr * 32 + lr) * 40 + kq];
    short8 a1 = *(const short8*)&ldsA[(wr * 32 + 16 + lr) * 40 + kq];
    short8 b0 = *(const short8*)&ldsB[(wc * 32 + lr) * 40 + kq];
    short8 b1 = *(const short8*)&ldsB[(wc * 32 + 16 + lr) * 40 + kq];
    acc[0][0] = __builtin_amdgcn_mfma_f32_16x16x32_bf16(a0, b0, acc[0][0], 0, 0, 0);
    acc[0][1] = __builtin_amdgcn_mfma_f32_16x16x32_bf16(a0, b1, acc[0][1], 0, 0, 0);
    acc[1][0] = __builtin_amdgcn_mfma_f32_16x16x32_bf16(a1, b0, acc[1][0], 0, 0, 0);
    acc[1][1] = __builtin_amdgcn_mfma_f32_16x16x32_bf16(a1, b1, acc[1][1], 0, 0, 0);
  }
  for (int r = 0; r < 2; ++r)
    for (int c = 0; c < 2; ++c)
      for (int q = 0; q < 4; ++q) {
        int row = m0 + wr * 32 + r * 16 + (lane >> 4) * 4 + q;
        int col = n0 + wc * 32 + c * 16 + lr;
        if (row < nrows) C[(size_t)row * NOUT + col] = acc[r][c][q] + biasC[col];
      }
}

__global__ __launch_bounds__(256) void pregemm_kernel(const unsigned short* __restrict__ Xb,
                                                      const unsigned short* __restrict__ Wb,
                                                      float* __restrict__ XW,
                                                      const float* __restrict__ biasC) {
  __shared__ alignas(16) unsigned short ldsA[64 * 40];
  __shared__ alignas(16) unsigned short ldsB[64 * 40];
  int tn = blockIdx.x & 63;
  int tm = blockIdx.x >> 6;
  gemm_tile(Xb, NN, tm * 64, Wb, tn * 64, XW, biasC, ldsA, ldsB);
}

// ---------------- cooperative recurrence: fence-free barrier, 1 sync/level ----------------
struct RP {
  const int4* meta;           // [NN] (node, cbeg_pos, cnt, 0)
  const int* doff;            // [NN+2]
  const int* maxd;
  const float* XW;            // [NN][4096] x-side preactivation (+ all biases)
  float* G2;                  // [GBLK][NN][32] block-local: h @ Wstrip^T, position-indexed
  float* CbB;                 // [GBLK][NN][8]  block-local c values (block's 8 cols)
  unsigned short* Hb;         // [NN][1024] bf16 h (only cross-block data; LLC-coherent)
  const unsigned short* Wrec; // [4096][1024] bf16 [Wiouh;Wfh]
  float* out;                 // [2048]: c_root | h_root
  int* sync_cnt;
};

// Fence-free grid barrier: no buffer_wbl2 / buffer_inv -> per-XCD L2 stays warm.
// Safe because the ONLY cross-block data (Hb) is written via device-coherent
// (sc0 sc1) stores that bypass L2, and each Hb line is read only after the
// barrier that follows its write (never cached earlier).
__device__ __forceinline__ void gsync_nofence(int* cnt, int target) {
  asm volatile("s_waitcnt vmcnt(0)" ::: "memory");   // Hb stores acked at LLC
  __syncthreads();
  if (threadIdx.x == 0) {
    __hip_atomic_fetch_add(cnt, 1, __ATOMIC_RELAXED, __HIP_MEMORY_SCOPE_AGENT);
    while (__hip_atomic_load(cnt, __ATOMIC_RELAXED, __HIP_MEMORY_SCOPE_AGENT) < target)
      __builtin_amdgcn_s_sleep(1);
  }
  __syncthreads();
  asm volatile("" ::: "memory");
}

// one K=32 slice -> 2 MFMA into the 2 col-tiles, prefetch A 4 ahead
#define BSTEP(AREG, KS) do {                                                    \
    const int kch_ = ((KS) << 2) + kq;                                          \
    short8 b0_ = *(const short8*)(wb0 + ((kch_ ^ swz) << 3));                   \
    short8 b1_ = *(const short8*)(wb1 + ((kch_ ^ swz) << 3));                   \
    acc0 = __builtin_amdgcn_mfma_f32_16x16x32_bf16(AREG, b0_, acc0, 0, 0, 0);   \
    acc1 = __builtin_amdgcn_mfma_f32_16x16x32_bf16(AREG, b1_, acc1, 0, 0, 0);   \
    if ((KS) + 4 < 32) AREG = *(const short8*)(ap + (((KS) + 4) << 5));         \
  } while (0)

__global__ __launch_bounds__(GTHR) void recur_kernel(RP p) {
  __shared__ alignas(16) unsigned short ldsW[32 * MD];   // 64 KiB W strip, swizzled
  __shared__ int4 ldsMeta[NN];                           // 32 KiB
  __shared__ int ldsDoff[NN + 2];                        // 8 KiB
  const int tid = threadIdx.x;
  const int bid = blockIdx.x;
  const int lane = tid & 63;
  const int wave = tid >> 6;
  // XCD-swizzled column strip: adjacent strips share an XCD -> 64B XW/Hb lines local
  const int strip = (bid & 7) * 16 + (bid >> 3);
  const int strip8 = strip << 3;

  // Stage W strip: LDS row j (0..31) = global W row (j>>3)*1024 + strip*8 + (j&7).
  for (int idx = tid; idx < 32 * 128; idx += GTHR) {
    int j = idx >> 7, kc = idx & 127;
    uint4 v = *(const uint4*)(p.Wrec +
        (size_t)((j >> 3) * MD + strip8 + (j & 7)) * MD + (kc << 3));
    *(uint4*)(ldsW + j * MD + ((kc ^ (j & 7)) << 3)) = v;
  }
  const int maxd = *p.maxd;
  for (int i = tid; i < NN; i += GTHR) ldsMeta[i] = p.meta[i];
  for (int i = tid; i <= maxd + 1; i += GTHR) ldsDoff[i] = p.doff[i];
  __syncthreads();

  float* G2b  = p.G2  + (size_t)bid * NN * 32;
  float* CbBb = p.CbB + (size_t)bid * NN * 8;
  const int coff = (tid & 1) << 2;       // 4-col half within the 8-col strip
  int step = 0;

  for (int d = maxd; d >= 0; --d) {
    const int lbeg = ldsDoff[d], lend = ldsDoff[d + 1];
    const int nd = lend - lbeg;

    // ---- cell for level d: 2 threads/node x 4 cols, all reads L2-warm ----
    for (int ii = tid >> 1; ii < nd; ii += GTHR / 2) {
      const int pos = lbeg + ii;
      const int4 mt = ldsMeta[pos];
      const int t = mt.x, cbeg = mt.y, cnt = mt.z;
      const float* xw = p.XW + (size_t)t * NOUT + strip8 + coff;
      f4 gi = *(const f4*)(xw);
      f4 go = *(const f4*)(xw + 1024);
      f4 gu = *(const f4*)(xw + 2048);
      f4 gf = *(const f4*)(xw + 3072);
      f4 fc = {0.f, 0.f, 0.f, 0.f};
      for (int k = 0; k < cnt; ++k) {
        const float* g2 = G2b + (size_t)(cbeg + k) * 32 + coff;
        gi += *(const f4*)(g2);
        go += *(const f4*)(g2 + 8);
        gu += *(const f4*)(g2 + 16);
        f4 gff = *(const f4*)(g2 + 24);
        f4 cu = *(const f4*)(CbBb + (size_t)(cbeg + k) * 8 + coff);
        #pragma unroll
        for (int q = 0; q < 4; ++q) fc[q] += sigm(gff[q] + gf[q]) * cu[q];
      }
      f4 cv, hv;
      #pragma unroll
      for (int q = 0; q < 4; ++q) {
        float c0 = sigm(gi[q]) * tanh_(gu[q]) + fc[q];
        cv[q] = c0;
        hv[q] = sigm(go[q]) * tanh_(c0);
      }
      *(f4*)(CbBb + (size_t)pos * 8 + coff) = cv;
      unsigned long long hp =
          (unsigned long long)f2bf(hv[0]) |
          ((unsigned long long)f2bf(hv[1]) << 16) |
          ((unsigned long long)f2bf(hv[2]) << 32) |
          ((unsigned long long)f2bf(hv[3]) << 48);
      __hip_atomic_store((unsigned long long*)(p.Hb + (size_t)t * MD + strip8 + coff),
                         hp, __ATOMIC_RELAXED, __HIP_MEMORY_SCOPE_AGENT);
      if (d == 0) {
        *(f4*)(p.out + strip8 + coff) = cv;
        *(f4*)(p.out + MD + strip8 + coff) = hv;
      }
    }
    if (d == 0) break;

    // ---- single fence-free grid sync: h of level d now visible at LLC ----
    ++step;
    gsync_nofence(p.sync_cnt, step * GBLK);

    // ---- prefetch next level's XW into L2 (one 4B load per 64B line) ----
    {
      const int lbeg2 = ldsDoff[d - 1];
      const int nd2 = lbeg - lbeg2;
      for (int q2 = tid; q2 < nd2 * 4; q2 += GTHR) {
        const int ii = q2 >> 2, g = q2 & 3;
        float v = *(p.XW + (size_t)ldsMeta[lbeg2 + ii].x * NOUT + (g << 10) + strip8);
        asm volatile("" :: "v"(v));      // keep-alive (no DCE)
      }
    }

    // ---- gemm: G2b[pos][0..31] = h[node(pos)] @ Wstrip^T for level-d positions ----
    {
      const int ntr = (nd + 15) >> 4;
      const int lr = lane & 15;
      const int kq = lane >> 4;
      const int kqo = kq << 3;
      const int swz = lr & 7;
      const unsigned short* wb0 = ldsW + lr * MD;
      const unsigned short* wb1 = wb0 + 16 * MD;
      for (int rt = wave; rt < ntr; rt += GTHR / 64) {
        const int r = (rt << 4) + lr;
        const int pos = lbeg + ((r < nd) ? r : 0);
        const int node = ldsMeta[pos].x;
        const unsigned short* ap = p.Hb + (size_t)node * MD + kqo;
        short8 a0 = *(const short8*)(ap);
        short8 a1 = *(const short8*)(ap + 32);
        short8 a2 = *(const short8*)(ap + 64);
        short8 a3 = *(const short8*)(ap + 96);
        f4 acc0 = {0.f, 0.f, 0.f, 0.f}, acc1 = {0.f, 0.f, 0.f, 0.f};
        #pragma unroll
        for (int kb = 0; kb < 32; kb += 4) {
          BSTEP(a0, kb);
          BSTEP(a1, kb + 1);
          BSTEP(a2, kb + 2);
          BSTEP(a3, kb + 3);
        }
        const int rb = (rt << 4) + (kq << 2);
        #pragma unroll
        for (int q = 0; q < 4; ++q) {
          const int rr = rb + q;
          if (rr < nd) {
            float* gr = G2b + (size_t)(lbeg + rr) * 32 + lr;
            gr[0]  = acc0[q];
            gr[16] = acc1[q];
          }
        }
      }
    }
    __syncthreads();   // block-local handoff to next cell
  }
}

// ---------------- launch ----------------
extern "C" void kernel_launch(void* const* d_in, const int* in_sizes, int n_in,
                              void* d_out, int out_size, void* d_ws, size_t ws_size,
                              hipStream_t stream) {
  const float* X     = (const float*)d_in[0];
  const int*   parent= (const int*)d_in[1];
  const float* Wioux = (const float*)d_in[2];
  const float* bioux = (const float*)d_in[3];
  const float* Wiouh = (const float*)d_in[4];
  const float* biouh = (const float*)d_in[5];
  const float* Wfx   = (const float*)d_in[6];
  const float* bfx   = (const float*)d_in[7];
  const float* Wfh   = (const float*)d_in[8];
  const float* bfh   = (const float*)d_in[9];
  float* out = (float*)d_out;

  char* ws = (char*)d_ws;
  size_t o = 0;
  auto alloc = [&](size_t bytes) { size_t r = o; o += (bytes + 255) & ~(size_t)255; return r; };
  unsigned short* Xb   = (unsigned short*)(ws + alloc((size_t)NN * MD * 2));
  unsigned short* Wpre = (unsigned short*)(ws + alloc((size_t)NOUT * MD * 2));
  unsigned short* Wrec = (unsigned short*)(ws + alloc((size_t)NOUT * MD * 2));
  float* XW            = (float*)(ws + alloc((size_t)NN * NOUT * 4));
  float* G2            = (float*)(ws + alloc((size_t)GBLK * NN * 32 * 4));
  float* CbB           = (float*)(ws + alloc((size_t)GBLK * NN * 8 * 4));
  unsigned short* Hb   = (unsigned short*)(ws + alloc((size_t)NN * MD * 2));
  float* biasC         = (float*)(ws + alloc((size_t)NOUT * 4));
  int4* meta           = (int4*)(ws + alloc((size_t)NN * 16));
  int* doff            = (int*)(ws + alloc((NN + 4) * 4));
  int* maxd            = (int*)(ws + alloc(256));
  int* sync_cnt        = (int*)(ws + alloc(256));

  {
    int n4;
    n4 = NN * MD / 4;
    cvt_bf16_kernel<<<(n4 + 255) / 256, 256, 0, stream>>>(X, Xb, n4);
    n4 = 3072 * MD / 4;
    cvt_bf16_kernel<<<(n4 + 255) / 256, 256, 0, stream>>>(Wioux, Wpre, n4);
    n4 = 1024 * MD / 4;
    cvt_bf16_kernel<<<(n4 + 255) / 256, 256, 0, stream>>>(Wfx, Wpre + (size_t)3072 * MD, n4);
    n4 = 3072 * MD / 4;
    cvt_bf16_kernel<<<(n4 + 255) / 256, 256, 0, stream>>>(Wiouh, Wrec, n4);
    n4 = 1024 * MD / 4;
    cvt_bf16_kernel<<<(n4 + 255) / 256, 256, 0, stream>>>(Wfh, Wrec + (size_t)3072 * MD, n4);
  }

  bias_combine_kernel<<<16, 256, 0, stream>>>(bioux, biouh, bfx, bfh, biasC);

  prep_kernel<<<1, 1024, 0, stream>>>(parent, meta, doff, maxd, sync_cnt);

  pregemm_kernel<<<(NN / 64) * (NOUT / 64), 256, 0, stream>>>(Xb, Wpre, XW, biasC);

  RP p;
  p.meta = meta; p.doff = doff; p.maxd = maxd;
  p.XW = XW; p.G2 = G2; p.CbB = CbB; p.Hb = Hb; p.Wrec = Wrec;
  p.out = out; p.sync_cnt = sync_cnt;
  void* args[] = {&p};
  hipLaunchCooperativeKernel((const void*)recur_kernel, dim3(GBLK), dim3(GTHR), args, 0, stream);

  (void)in_sizes; (void)n_in; (void)out_size; (void)ws_size;
}

// Round 5
// 576.124 us; speedup vs baseline: 3.3884x; 1.0789x over previous
//
#include <hip/hip_runtime.h>

#define NN 2048          // nodes
#define MD 1024          // mem/input dim
#define NOUT 4096        // 3M (iou) + M (f) output columns
#define GBLK 256         // cooperative grid blocks: one 4-col strip each
#define GTHR 512         // threads per block (8 waves)

typedef __attribute__((ext_vector_type(8))) short short8;   // 8 x bf16 fragment
typedef __attribute__((ext_vector_type(4))) float f4;

__device__ __forceinline__ unsigned short f2bf(float f) {
  unsigned u = __float_as_uint(f);
  u += 0x7fffu + ((u >> 16) & 1u);      // RNE
  return (unsigned short)(u >> 16);
}
__device__ __forceinline__ float blo(unsigned u) { return __uint_as_float(u << 16); }
__device__ __forceinline__ float bhi(unsigned u) { return __uint_as_float(u & 0xffff0000u); }
__device__ __forceinline__ float sigm(float x) { return 1.0f / (1.0f + __expf(-x)); }
__device__ __forceinline__ float tanh_(float x) { return 1.0f - 2.0f / (1.0f + __expf(2.0f * x)); }

// ---------------- fp32 -> bf16 conversion (vector x4) ----------------
__global__ __launch_bounds__(256) void cvt_bf16_kernel(const float* __restrict__ s,
                                                       unsigned short* __restrict__ d, int n4) {
  int i = blockIdx.x * 256 + threadIdx.x;
  if (i < n4) {
    f4 v = *((const f4*)s + i);
    unsigned lo = f2bf(v[0]) | ((unsigned)f2bf(v[1]) << 16);
    unsigned hi = f2bf(v[2]) | ((unsigned)f2bf(v[3]) << 16);
    uint2 r; r.x = lo; r.y = hi;
    *((uint2*)d + i) = r;
  }
}

// ---------------- combined bias: biasC = [bioux+biouh ; bfx+bfh] ----------------
__global__ __launch_bounds__(256) void bias_combine_kernel(const float* __restrict__ bioux,
                                                           const float* __restrict__ biouh,
                                                           const float* __restrict__ bfx,
                                                           const float* __restrict__ bfh,
                                                           float* __restrict__ biasC) {
  int i = blockIdx.x * 256 + threadIdx.x;
  if (i < 3072) biasC[i] = bioux[i] + biouh[i];
  else if (i < 4096) biasC[i] = bfx[i - 3072] + bfh[i - 3072];
}

// ---------------- prep: depth, parent-sort, BFS parent-grouped level order ----------------
__global__ __launch_bounds__(1024) void prep_kernel(const int* __restrict__ parent,
                                                    int4* __restrict__ meta,
                                                    int* __restrict__ doff_g,
                                                    int* __restrict__ maxd_out,
                                                    int* __restrict__ flags) {
  __shared__ int s_anc[NN], s_dep[NN];
  __shared__ int s_t1[NN + 2], s_t2[NN + 2];
  __shared__ int s_poff[NN + 2], s_cur[NN + 2];
  __shared__ int s_ordp[NN], s_nord[NN];
  __shared__ int s_doff[NN + 2];
  __shared__ int s_sc[NN], s_sc2[NN];
  __shared__ int s_wsum[17];
  __shared__ int s_maxd;
  const int tid = threadIdx.x;

  if (tid == 0) s_maxd = 0;
  for (int i = tid; i < GBLK; i += 1024) flags[i] = 0;   // reset barrier epochs
  for (int t = tid; t < NN; t += 1024) {
    bool root = (t == NN - 1);
    s_anc[t] = root ? t : parent[t];
    s_dep[t] = root ? 0 : 1;
  }
  __syncthreads();
  for (int it = 0; it < 11; ++it) {     // 2^11 >= NN
    for (int t = tid; t < NN; t += 1024) { int a = s_anc[t]; s_t1[t] = s_dep[t] + s_dep[a]; s_t2[t] = s_anc[a]; }
    __syncthreads();
    for (int t = tid; t < NN; t += 1024) { s_dep[t] = s_t1[t]; s_anc[t] = s_t2[t]; }
    __syncthreads();
  }
  for (int t = tid; t < NN; t += 1024) atomicMax(&s_maxd, s_dep[t]);

  // ---- counting sort by parent -> s_ordp with offsets s_poff ----
  for (int i = tid; i < NN + 2; i += 1024) s_t2[i] = 0;
  __syncthreads();
  for (int t = tid; t < NN; t += 1024) atomicAdd(&s_t2[parent[t]], 1);
  __syncthreads();
  {
    const int L = NN + 2;
    int* src = s_t2; int* dst = s_t1;
    for (int o = 1; o < L; o <<= 1) {
      for (int i = tid; i < L; i += 1024) dst[i] = src[i] + ((i >= o) ? src[i - o] : 0);
      __syncthreads();
      int* tmp = src; src = dst; dst = tmp;
    }
    for (int i = tid; i < L; i += 1024) { int v = (i ? src[i - 1] : 0); s_poff[i] = v; s_cur[i] = v; }
    __syncthreads();
    for (int t = tid; t < NN; t += 1024) {
      int pos = atomicAdd(&s_cur[parent[t]], 1);
      s_ordp[pos] = t;
    }
    __syncthreads();
    for (int p = tid; p < NN + 1; p += 1024) {    // determinism within bucket
      int b = s_poff[p], e = s_poff[p + 1];
      for (int i = b + 1; i < e; ++i) {
        int v = s_ordp[i], j = i - 1;
        while (j >= b && s_ordp[j] > v) { s_ordp[j + 1] = s_ordp[j]; --j; }
        s_ordp[j + 1] = v;
      }
    }
    __syncthreads();
  }

  // ---- counts by depth -> s_doff ----
  for (int i = tid; i < NN + 2; i += 1024) s_t2[i] = 0;
  __syncthreads();
  for (int t = tid; t < NN; t += 1024) atomicAdd(&s_t2[s_dep[t]], 1);
  __syncthreads();
  {
    const int L = NN + 1;
    int* src = s_t2; int* dst = s_t1;
    for (int o = 1; o < L; o <<= 1) {
      for (int i = tid; i < L; i += 1024) dst[i] = src[i] + ((i >= o) ? src[i - o] : 0);
      __syncthreads();
      int* tmp = src; src = dst; dst = tmp;
    }
    for (int i = tid; i < L + 1; i += 1024) s_doff[i] = (i ? src[i - 1] : 0);
    __syncthreads();
  }

  // ---- BFS: parent-grouped order per level ----
  const int maxd = s_maxd;
  if (tid == 0) s_nord[0] = NN - 1;     // root at position 0
  __syncthreads();
  for (int d = 0; d < maxd; ++d) {
    const int lbeg = s_doff[d], lend = s_doff[d + 1];
    const int nd = lend - lbeg;
    if (nd <= 1024) {
      int t = -1, v = 0;
      if (tid < nd) { t = s_nord[lbeg + tid]; v = s_poff[t + 1] - s_poff[t]; }
      #pragma unroll
      for (int o = 1; o < 64; o <<= 1) {
        int u = __shfl_up(v, (unsigned)o, 64);
        if ((tid & 63) >= o) v += u;
      }
      if ((tid & 63) == 63) s_wsum[tid >> 6] = v;
      __syncthreads();
      if (tid < 16) {
        int w = s_wsum[tid];
        #pragma unroll
        for (int o = 1; o < 16; o <<= 1) {
          int u = __shfl_up(w, (unsigned)o, 16);
          if (tid >= o) w += u;
        }
        s_wsum[tid] = w;
      }
      __syncthreads();
      if (tid < nd) {
        int incl = v + ((tid >> 6) ? s_wsum[(tid >> 6) - 1] : 0);
        int cnti = s_poff[t + 1] - s_poff[t];
        int cb = lend + incl - cnti;
        meta[lbeg + tid] = make_int4(t, cb, cnti, 0);
        for (int j = 0; j < cnti; ++j) s_nord[cb + j] = s_ordp[s_poff[t] + j];
      }
      __syncthreads();
    } else {                             // fallback (pathological trees)
      for (int i = tid; i < nd; i += 1024) { int t2 = s_nord[lbeg + i]; s_sc[i] = s_poff[t2 + 1] - s_poff[t2]; }
      __syncthreads();
      for (int o = 1; o < nd; o <<= 1) {
        for (int i = tid; i < nd; i += 1024) s_sc2[i] = s_sc[i] + ((i >= o) ? s_sc[i - o] : 0);
        __syncthreads();
        for (int i = tid; i < nd; i += 1024) s_sc[i] = s_sc2[i];
        __syncthreads();
      }
      for (int i = tid; i < nd; i += 1024) {
        int t2 = s_nord[lbeg + i];
        int cnti = s_poff[t2 + 1] - s_poff[t2];
        int cb = lend + s_sc[i] - cnti;
        meta[lbeg + i] = make_int4(t2, cb, cnti, 0);
        for (int j = 0; j < cnti; ++j) s_nord[cb + j] = s_ordp[s_poff[t2] + j];
      }
      __syncthreads();
    }
  }
  {                                      // deepest level: all leaves
    const int lbeg = s_doff[maxd], lend = s_doff[maxd + 1];
    for (int i = lbeg + tid; i < lend; i += 1024)
      meta[i] = make_int4(s_nord[i], 0, 0, 0);
  }
  for (int i = tid; i <= maxd + 1; i += 1024) doff_g[i] = s_doff[i];
  if (tid == 0) *maxd_out = maxd;
}

// ---------------- bf16 MFMA 64x64 tile (B^T GEMM) for the pre-GEMM ----------------
__device__ void gemm_tile(const unsigned short* __restrict__ A, int nrows,
                          int m0, const unsigned short* __restrict__ B, int n0,
                          float* __restrict__ C, const float* __restrict__ biasC,
                          unsigned short* ldsA, unsigned short* ldsB) {
  const int tid = threadIdx.x;
  const int lane = tid & 63;
  const int wave = tid >> 6;
  const int wr = wave >> 1, wc = wave & 1;
  f4 acc[2][2] = {};
  const int sr = tid >> 2;
  const int sc = (tid & 3) << 3;
  int ar = m0 + sr;
  int arow = (ar < nrows) ? ar : 0;
  const unsigned short* agp = A + (size_t)arow * MD + sc;
  const unsigned short* bgp = B + (size_t)(n0 + sr) * MD + sc;
  const int lr = lane & 15;
  const int kq = (lane >> 4) << 3;

  for (int k0 = 0; k0 < MD; k0 += 32) {
    uint4 av = *(const uint4*)(agp + k0);
    uint4 bv = *(const uint4*)(bgp + k0);
    __syncthreads();
    *(uint4*)&ldsA[sr * 40 + sc] = av;
    *(uint4*)&ldsB[sr * 40 + sc] = bv;
    __syncthreads();
    short8 a0 = *(const short8*)&ldsA[(wr * 32 + lr) * 40 + kq];
    short8 a1 = *(const short8*)&ldsA[(wr * 32 + 16 + lr) * 40 + kq];
    short8 b0 = *(const short8*)&ldsB[(wc * 32 + lr) * 40 + kq];
    short8 b1 = *(const short8*)&ldsB[(wc * 32 + 16 + lr) * 40 + kq];
    acc[0][0] = __builtin_amdgcn_mfma_f32_16x16x32_bf16(a0, b0, acc[0][0], 0, 0, 0);
    acc[0][1] = __builtin_amdgcn_mfma_f32_16x16x32_bf16(a0, b1, acc[0][1], 0, 0, 0);
    acc[1][0] = __builtin_amdgcn_mfma_f32_16x16x32_bf16(a1, b0, acc[1][0], 0, 0, 0);
    acc[1][1] = __builtin_amdgcn_mfma_f32_16x16x32_bf16(a1, b1, acc[1][1], 0, 0, 0);
  }
  for (int r = 0; r < 2; ++r)
    for (int c = 0; c < 2; ++c)
      for (int q = 0; q < 4; ++q) {
        int row = m0 + wr * 32 + r * 16 + (lane >> 4) * 4 + q;
        int col = n0 + wc * 32 + c * 16 + lr;
        if (row < nrows) C[(size_t)row * NOUT + col] = acc[r][c][q] + biasC[col];
      }
}

__global__ __launch_bounds__(256) void pregemm_kernel(const unsigned short* __restrict__ Xb,
                                                      const unsigned short* __restrict__ Wb,
                                                      float* __restrict__ XW,
                                                      const float* __restrict__ biasC) {
  __shared__ alignas(16) unsigned short ldsA[64 * 40];
  __shared__ alignas(16) unsigned short ldsB[64 * 40];
  int tn = blockIdx.x & 63;
  int tm = blockIdx.x >> 6;
  gemm_tile(Xb, NN, tm * 64, Wb, tn * 64, XW, biasC, ldsA, ldsB);
}

// ---------------- cooperative recurrence ----------------
struct RP {
  const int4* meta;           // [NN] (node, cbeg_pos, cnt, 0)
  const int* doff;            // [NN+2]
  const int* maxd;
  const float* XW;            // [NN][4096] x-side preactivation (+ all biases)
  unsigned short* G2;         // [GBLK][NN][16] bf16: block's 4 cols x 4 gates per node
  float* CbB;                 // [GBLK][NN][4]  block's 4 c-cols per node (position-indexed)
  unsigned short* Hb;         // [NN][1024] bf16 h (only cross-block data; LLC-coherent)
  const unsigned short* Wrec; // [4096][1024] bf16 [Wiouh;Wfh]
  float* out;                 // [2048]: c_root | h_root
  int* flags;                 // [GBLK] per-block barrier epochs
};

// Flag-array grid barrier: no RMW serialization, no L2 flush.
// Each block WRITES flag[bid]=step (device-coherent), wave 0 polls all flags.
__device__ __forceinline__ void flag_barrier(int* flags, int step) {
  asm volatile("s_waitcnt vmcnt(0)" ::: "memory");   // this wave's stores acked
  __syncthreads();                                   // all waves drained
  if (threadIdx.x == 0)
    __hip_atomic_store(&flags[blockIdx.x], step, __ATOMIC_RELAXED, __HIP_MEMORY_SCOPE_AGENT);
  if (threadIdx.x < 64) {
    const int l = threadIdx.x;
    for (;;) {
      int a = __hip_atomic_load(&flags[l],       __ATOMIC_RELAXED, __HIP_MEMORY_SCOPE_AGENT);
      int b = __hip_atomic_load(&flags[l + 64],  __ATOMIC_RELAXED, __HIP_MEMORY_SCOPE_AGENT);
      int c = __hip_atomic_load(&flags[l + 128], __ATOMIC_RELAXED, __HIP_MEMORY_SCOPE_AGENT);
      int d = __hip_atomic_load(&flags[l + 192], __ATOMIC_RELAXED, __HIP_MEMORY_SCOPE_AGENT);
      if (__all(a >= step && b >= step && c >= step && d >= step)) break;
      __builtin_amdgcn_s_sleep(2);
    }
  }
  __syncthreads();
  asm volatile("" ::: "memory");
}

__global__ __launch_bounds__(GTHR, 4) void recur_kernel(RP p) {
  __shared__ alignas(16) unsigned short ldsW[16 * MD];   // 32 KiB W strip, swizzled
  __shared__ int ldsDoff[NN + 2];                        // 8 KiB
  const int tid = threadIdx.x;
  const int bid = blockIdx.x;
  const int lane = tid & 63;
  const int wave = tid >> 6;
  // XCD-swizzled strip: blocks on one XCD cover contiguous 128-col windows
  const int strip = (bid & 7) * 32 + (bid >> 3);
  const int s4 = strip << 2;             // this block's 4 columns

  // Stage W strip: LDS row j (0..15) = global W row (j>>2)*1024 + s4 + (j&3).
  // 16B chunk kc stored at (kc ^ (j&7)) within the row (bank swizzle).
  for (int idx = tid; idx < 16 * 128; idx += GTHR) {
    int j = idx >> 7, kc = idx & 127;
    uint4 v = *(const uint4*)(p.Wrec + (size_t)((j >> 2) * MD + s4 + (j & 3)) * MD + (kc << 3));
    *(uint4*)(ldsW + j * MD + ((kc ^ (j & 7)) << 3)) = v;
  }
  const int maxd = *p.maxd;
  for (int i = tid; i <= maxd + 1; i += GTHR) ldsDoff[i] = p.doff[i];
  __syncthreads();

  unsigned short* G2b = p.G2 + (size_t)bid * NN * 16;
  float* CbBb = p.CbB + (size_t)bid * NN * 4;
  const int chalf = tid & 1;             // which half of the children this thread sums

  for (int d = maxd; d >= 0; --d) {
    const int lbeg = ldsDoff[d], lend = ldsDoff[d + 1];
    const int nd = lend - lbeg;

    // ---- cell: 2 threads/node (child-halves), 4 cols each; shfl_xor(1) reduce ----
    for (int ii = tid >> 1; ii < nd; ii += GTHR / 2) {
      const int pos = lbeg + ii;
      const int4 mt = p.meta[pos];
      const int t = mt.x, cbeg = mt.y, cnt = mt.z;
      const float* xw = p.XW + (size_t)t * NOUT + s4;
      f4 gf = *(const f4*)(xw + 3072);
      f4 gi = {0.f, 0.f, 0.f, 0.f}, go = gi, gu = gi, fc = gi;
      if (chalf == 0) {
        gi = *(const f4*)(xw);
        go = *(const f4*)(xw + 1024);
        gu = *(const f4*)(xw + 2048);
      }
      for (int k = chalf; k < cnt; k += 2) {
        const unsigned short* g2 = G2b + (size_t)(cbeg + k) * 16;
        uint4 ga = *(const uint4*)(g2);        // i0..3, o0..3
        uint4 gb = *(const uint4*)(g2 + 8);    // u0..3, f0..3
        f4 cu = *(const f4*)(CbBb + (size_t)(cbeg + k) * 4);
        gi[0] += blo(ga.x); gi[1] += bhi(ga.x); gi[2] += blo(ga.y); gi[3] += bhi(ga.y);
        go[0] += blo(ga.z); go[1] += bhi(ga.z); go[2] += blo(ga.w); go[3] += bhi(ga.w);
        gu[0] += blo(gb.x); gu[1] += bhi(gb.x); gu[2] += blo(gb.y); gu[3] += bhi(gb.y);
        f4 gff = {blo(gb.z), bhi(gb.z), blo(gb.w), bhi(gb.w)};
        #pragma unroll
        for (int q = 0; q < 4; ++q) fc[q] += sigm(gff[q] + gf[q]) * cu[q];
      }
      #pragma unroll
      for (int q = 0; q < 4; ++q) {          // pairwise reduce the two child-halves
        gi[q] += __shfl_xor(gi[q], 1);
        go[q] += __shfl_xor(go[q], 1);
        gu[q] += __shfl_xor(gu[q], 1);
        fc[q] += __shfl_xor(fc[q], 1);
      }
      if (chalf == 0) {
        f4 cv, hv;
        #pragma unroll
        for (int q = 0; q < 4; ++q) {
          float c0 = sigm(gi[q]) * tanh_(gu[q]) + fc[q];
          cv[q] = c0;
          hv[q] = sigm(go[q]) * tanh_(c0);
        }
        *(f4*)(CbBb + (size_t)pos * 4) = cv;
        unsigned long long hp =
            (unsigned long long)f2bf(hv[0]) |
            ((unsigned long long)f2bf(hv[1]) << 16) |
            ((unsigned long long)f2bf(hv[2]) << 32) |
            ((unsigned long long)f2bf(hv[3]) << 48);
        __hip_atomic_store((unsigned long long*)(p.Hb + (size_t)t * MD + s4),
                           hp, __ATOMIC_RELAXED, __HIP_MEMORY_SCOPE_AGENT);
        if (t == NN - 1) {                   // root: output (c | h) fp32
          *(f4*)(p.out + s4) = cv;
          *(f4*)(p.out + MD + s4) = hv;
        }
      }
    }
    if (d == 0) break;

    // ---- grid barrier: h of level d now visible at LLC ----
    flag_barrier(p.flags, maxd - d + 1);

    // ---- gemm: G2b[pos][0..15] = h[node(pos)] @ Wstrip^T (16 G-cols) ----
    {
      const int ntr = (nd + 15) >> 4;
      const int lr = lane & 15;
      const int kq = lane >> 4;
      const int swz = lr & 7;
      const unsigned short* wb0 = ldsW + lr * MD;
      for (int rt = wave; rt < ntr; rt += GTHR / 64) {
        const int r = (rt << 4) + lr;
        const int pos = lbeg + ((r < nd) ? r : 0);
        const int node = p.meta[pos].x;
        const unsigned short* ap = p.Hb + (size_t)node * MD + (kq << 3);
        short8 ar[8];                        // 8-deep load ring (fully unrolled -> regs)
        #pragma unroll
        for (int ks = 0; ks < 8; ++ks) ar[ks] = *(const short8*)(ap + (ks << 5));
        f4 ae = {0.f, 0.f, 0.f, 0.f}, ao = {0.f, 0.f, 0.f, 0.f};
        #pragma unroll
        for (int kb = 0; kb < 32; ++kb) {
          const int kch = (kb << 2) + kq;
          short8 b = *(const short8*)(wb0 + ((kch ^ swz) << 3));
          if (kb & 1) ao = __builtin_amdgcn_mfma_f32_16x16x32_bf16(ar[kb & 7], b, ao, 0, 0, 0);
          else        ae = __builtin_amdgcn_mfma_f32_16x16x32_bf16(ar[kb & 7], b, ae, 0, 0, 0);
          if (kb + 8 < 32) ar[kb & 7] = *(const short8*)(ap + ((kb + 8) << 5));
        }
        const int rb = (rt << 4) + (kq << 2);
        #pragma unroll
        for (int q = 0; q < 4; ++q) {        // C/D: col = lane&15, row = kq*4+q
          const int rr = rb + q;
          if (rr < nd) G2b[(size_t)(lbeg + rr) * 16 + lr] = f2bf(ae[q] + ao[q]);
        }
      }
    }
    __syncthreads();   // block-local G2/CbB handoff to next cell
  }
}

// ---------------- launch ----------------
extern "C" void kernel_launch(void* const* d_in, const int* in_sizes, int n_in,
                              void* d_out, int out_size, void* d_ws, size_t ws_size,
                              hipStream_t stream) {
  const float* X     = (const float*)d_in[0];
  const int*   parent= (const int*)d_in[1];
  const float* Wioux = (const float*)d_in[2];
  const float* bioux = (const float*)d_in[3];
  const float* Wiouh = (const float*)d_in[4];
  const float* biouh = (const float*)d_in[5];
  const float* Wfx   = (const float*)d_in[6];
  const float* bfx   = (const float*)d_in[7];
  const float* Wfh   = (const float*)d_in[8];
  const float* bfh   = (const float*)d_in[9];
  float* out = (float*)d_out;

  char* ws = (char*)d_ws;
  size_t o = 0;
  auto alloc = [&](size_t bytes) { size_t r = o; o += (bytes + 255) & ~(size_t)255; return r; };
  unsigned short* Xb   = (unsigned short*)(ws + alloc((size_t)NN * MD * 2));
  unsigned short* Wpre = (unsigned short*)(ws + alloc((size_t)NOUT * MD * 2));
  unsigned short* Wrec = (unsigned short*)(ws + alloc((size_t)NOUT * MD * 2));
  float* XW            = (float*)(ws + alloc((size_t)NN * NOUT * 4));
  unsigned short* G2   = (unsigned short*)(ws + alloc((size_t)GBLK * NN * 16 * 2));
  float* CbB           = (float*)(ws + alloc((size_t)GBLK * NN * 4 * 4));
  unsigned short* Hb   = (unsigned short*)(ws + alloc((size_t)NN * MD * 2));
  float* biasC         = (float*)(ws + alloc((size_t)NOUT * 4));
  int4* meta           = (int4*)(ws + alloc((size_t)NN * 16));
  int* doff            = (int*)(ws + alloc((NN + 4) * 4));
  int* maxd            = (int*)(ws + alloc(256));
  int* flags           = (int*)(ws + alloc((GBLK + 64) * 4));

  {
    int n4;
    n4 = NN * MD / 4;
    cvt_bf16_kernel<<<(n4 + 255) / 256, 256, 0, stream>>>(X, Xb, n4);
    n4 = 3072 * MD / 4;
    cvt_bf16_kernel<<<(n4 + 255) / 256, 256, 0, stream>>>(Wioux, Wpre, n4);
    n4 = 1024 * MD / 4;
    cvt_bf16_kernel<<<(n4 + 255) / 256, 256, 0, stream>>>(Wfx, Wpre + (size_t)3072 * MD, n4);
    n4 = 3072 * MD / 4;
    cvt_bf16_kernel<<<(n4 + 255) / 256, 256, 0, stream>>>(Wiouh, Wrec, n4);
    n4 = 1024 * MD / 4;
    cvt_bf16_kernel<<<(n4 + 255) / 256, 256, 0, stream>>>(Wfh, Wrec + (size_t)3072 * MD, n4);
  }

  bias_combine_kernel<<<16, 256, 0, stream>>>(bioux, biouh, bfx, bfh, biasC);

  prep_kernel<<<1, 1024, 0, stream>>>(parent, meta, doff, maxd, flags);

  pregemm_kernel<<<(NN / 64) * (NOUT / 64), 256, 0, stream>>>(Xb, Wpre, XW, biasC);

  RP p;
  p.meta = meta; p.doff = doff; p.maxd = maxd;
  p.XW = XW; p.G2 = G2; p.CbB = CbB; p.Hb = Hb; p.Wrec = Wrec;
  p.out = out; p.flags = flags;
  void* args[] = {&p};
  hipLaunchCooperativeKernel((const void*)recur_kernel, dim3(GBLK), dim3(GTHR), args, 0, stream);

  (void)in_sizes; (void)n_in; (void)out_size; (void)ws_size;
}

// Round 6
// 551.935 us; speedup vs baseline: 3.5369x; 1.0438x over previous
//
#include <hip/hip_runtime.h>

#define NN 2048          // nodes
#define MD 1024          // mem/input dim
#define NOUT 4096        // 3M (iou) + M (f) output columns
#define GBLK 256         // cooperative grid blocks: one 4-col strip each
#define GTHR 1024        // threads per block (16 waves)

typedef __attribute__((ext_vector_type(8))) short short8;   // 8 x bf16 fragment
typedef __attribute__((ext_vector_type(4))) float f4;

__device__ __forceinline__ unsigned short f2bf(float f) {
  unsigned u = __float_as_uint(f);
  u += 0x7fffu + ((u >> 16) & 1u);      // RNE
  return (unsigned short)(u >> 16);
}
__device__ __forceinline__ float blo(unsigned u) { return __uint_as_float(u << 16); }
__device__ __forceinline__ float bhi(unsigned u) { return __uint_as_float(u & 0xffff0000u); }
__device__ __forceinline__ float sigm(float x) { return 1.0f / (1.0f + __expf(-x)); }
__device__ __forceinline__ float tanh_(float x) { return 1.0f - 2.0f / (1.0f + __expf(2.0f * x)); }

// ---------------- fp32 -> bf16 conversion (vector x4) ----------------
__global__ __launch_bounds__(256) void cvt_bf16_kernel(const float* __restrict__ s,
                                                       unsigned short* __restrict__ d, int n4) {
  int i = blockIdx.x * 256 + threadIdx.x;
  if (i < n4) {
    f4 v = *((const f4*)s + i);
    unsigned lo = f2bf(v[0]) | ((unsigned)f2bf(v[1]) << 16);
    unsigned hi = f2bf(v[2]) | ((unsigned)f2bf(v[3]) << 16);
    uint2 r; r.x = lo; r.y = hi;
    *((uint2*)d + i) = r;
  }
}

// ---------------- combined bias: biasC = [bioux+biouh ; bfx+bfh] ----------------
__global__ __launch_bounds__(256) void bias_combine_kernel(const float* __restrict__ bioux,
                                                           const float* __restrict__ biouh,
                                                           const float* __restrict__ bfx,
                                                           const float* __restrict__ bfh,
                                                           float* __restrict__ biasC) {
  int i = blockIdx.x * 256 + threadIdx.x;
  if (i < 3072) biasC[i] = bioux[i] + biouh[i];
  else if (i < 4096) biasC[i] = bfx[i - 3072] + bfh[i - 3072];
}

// ---------------- prep: depth, parent-sort, BFS parent-grouped level order ----------------
__global__ __launch_bounds__(1024) void prep_kernel(const int* __restrict__ parent,
                                                    int4* __restrict__ meta,
                                                    int* __restrict__ doff_g,
                                                    int* __restrict__ maxd_out,
                                                    int* __restrict__ flags) {
  __shared__ int s_anc[NN], s_dep[NN];
  __shared__ int s_t1[NN + 2], s_t2[NN + 2];
  __shared__ int s_poff[NN + 2], s_cur[NN + 2];
  __shared__ int s_ordp[NN], s_nord[NN];
  __shared__ int s_doff[NN + 2];
  __shared__ int s_sc[NN], s_sc2[NN];
  __shared__ int s_wsum[17];
  __shared__ int s_maxd;
  const int tid = threadIdx.x;

  if (tid == 0) s_maxd = 0;
  for (int i = tid; i < GBLK + 64; i += 1024) flags[i] = 0;   // reset barrier epochs
  for (int t = tid; t < NN; t += 1024) {
    bool root = (t == NN - 1);
    s_anc[t] = root ? t : parent[t];
    s_dep[t] = root ? 0 : 1;
  }
  __syncthreads();
  for (int it = 0; it < 11; ++it) {     // 2^11 >= NN
    for (int t = tid; t < NN; t += 1024) { int a = s_anc[t]; s_t1[t] = s_dep[t] + s_dep[a]; s_t2[t] = s_anc[a]; }
    __syncthreads();
    for (int t = tid; t < NN; t += 1024) { s_dep[t] = s_t1[t]; s_anc[t] = s_t2[t]; }
    __syncthreads();
  }
  for (int t = tid; t < NN; t += 1024) atomicMax(&s_maxd, s_dep[t]);

  // ---- counting sort by parent -> s_ordp with offsets s_poff ----
  for (int i = tid; i < NN + 2; i += 1024) s_t2[i] = 0;
  __syncthreads();
  for (int t = tid; t < NN; t += 1024) atomicAdd(&s_t2[parent[t]], 1);
  __syncthreads();
  {
    const int L = NN + 2;
    int* src = s_t2; int* dst = s_t1;
    for (int o = 1; o < L; o <<= 1) {
      for (int i = tid; i < L; i += 1024) dst[i] = src[i] + ((i >= o) ? src[i - o] : 0);
      __syncthreads();
      int* tmp = src; src = dst; dst = tmp;
    }
    for (int i = tid; i < L; i += 1024) { int v = (i ? src[i - 1] : 0); s_poff[i] = v; s_cur[i] = v; }
    __syncthreads();
    for (int t = tid; t < NN; t += 1024) {
      int pos = atomicAdd(&s_cur[parent[t]], 1);
      s_ordp[pos] = t;
    }
    __syncthreads();
    for (int p = tid; p < NN + 1; p += 1024) {    // determinism within bucket
      int b = s_poff[p], e = s_poff[p + 1];
      for (int i = b + 1; i < e; ++i) {
        int v = s_ordp[i], j = i - 1;
        while (j >= b && s_ordp[j] > v) { s_ordp[j + 1] = s_ordp[j]; --j; }
        s_ordp[j + 1] = v;
      }
    }
    __syncthreads();
  }

  // ---- counts by depth -> s_doff ----
  for (int i = tid; i < NN + 2; i += 1024) s_t2[i] = 0;
  __syncthreads();
  for (int t = tid; t < NN; t += 1024) atomicAdd(&s_t2[s_dep[t]], 1);
  __syncthreads();
  {
    const int L = NN + 1;
    int* src = s_t2; int* dst = s_t1;
    for (int o = 1; o < L; o <<= 1) {
      for (int i = tid; i < L; i += 1024) dst[i] = src[i] + ((i >= o) ? src[i - o] : 0);
      __syncthreads();
      int* tmp = src; src = dst; dst = tmp;
    }
    for (int i = tid; i < L + 1; i += 1024) s_doff[i] = (i ? src[i - 1] : 0);
    __syncthreads();
  }

  // ---- BFS: parent-grouped order per level ----
  const int maxd = s_maxd;
  if (tid == 0) s_nord[0] = NN - 1;     // root at position 0
  __syncthreads();
  for (int d = 0; d < maxd; ++d) {
    const int lbeg = s_doff[d], lend = s_doff[d + 1];
    const int nd = lend - lbeg;
    if (nd <= 1024) {
      int t = -1, v = 0;
      if (tid < nd) { t = s_nord[lbeg + tid]; v = s_poff[t + 1] - s_poff[t]; }
      #pragma unroll
      for (int o = 1; o < 64; o <<= 1) {
        int u = __shfl_up(v, (unsigned)o, 64);
        if ((tid & 63) >= o) v += u;
      }
      if ((tid & 63) == 63) s_wsum[tid >> 6] = v;
      __syncthreads();
      if (tid < 16) {
        int w = s_wsum[tid];
        #pragma unroll
        for (int o = 1; o < 16; o <<= 1) {
          int u = __shfl_up(w, (unsigned)o, 16);
          if (tid >= o) w += u;
        }
        s_wsum[tid] = w;
      }
      __syncthreads();
      if (tid < nd) {
        int incl = v + ((tid >> 6) ? s_wsum[(tid >> 6) - 1] : 0);
        int cnti = s_poff[t + 1] - s_poff[t];
        int cb = lend + incl - cnti;
        meta[lbeg + tid] = make_int4(t, cb, cnti, 0);
        for (int j = 0; j < cnti; ++j) s_nord[cb + j] = s_ordp[s_poff[t] + j];
      }
      __syncthreads();
    } else {                             // fallback (pathological trees)
      for (int i = tid; i < nd; i += 1024) { int t2 = s_nord[lbeg + i]; s_sc[i] = s_poff[t2 + 1] - s_poff[t2]; }
      __syncthreads();
      for (int o = 1; o < nd; o <<= 1) {
        for (int i = tid; i < nd; i += 1024) s_sc2[i] = s_sc[i] + ((i >= o) ? s_sc[i - o] : 0);
        __syncthreads();
        for (int i = tid; i < nd; i += 1024) s_sc[i] = s_sc2[i];
        __syncthreads();
      }
      for (int i = tid; i < nd; i += 1024) {
        int t2 = s_nord[lbeg + i];
        int cnti = s_poff[t2 + 1] - s_poff[t2];
        int cb = lend + s_sc[i] - cnti;
        meta[lbeg + i] = make_int4(t2, cb, cnti, 0);
        for (int j = 0; j < cnti; ++j) s_nord[cb + j] = s_ordp[s_poff[t2] + j];
      }
      __syncthreads();
    }
  }
  {                                      // deepest level: all leaves
    const int lbeg = s_doff[maxd], lend = s_doff[maxd + 1];
    for (int i = lbeg + tid; i < lend; i += 1024)
      meta[i] = make_int4(s_nord[i], 0, 0, 0);
  }
  for (int i = tid; i <= maxd + 1; i += 1024) doff_g[i] = s_doff[i];
  if (tid == 0) *maxd_out = maxd;
}

// ---------------- pre-GEMM: XWb[strip][node][16] bf16 = X @ [Wioux;Wfx]^T + biasC ----------------
__global__ __launch_bounds__(256) void pregemm_kernel(const unsigned short* __restrict__ Xb,
                                                      const unsigned short* __restrict__ Wb,
                                                      unsigned short* __restrict__ XWb,
                                                      const float* __restrict__ biasC) {
  __shared__ alignas(16) unsigned short ldsA[64 * 40];
  __shared__ alignas(16) unsigned short ldsB[64 * 40];
  const int tn = blockIdx.x & 63;
  const int tm = blockIdx.x >> 6;
  const int m0 = tm * 64, n0 = tn * 64;
  const int tid = threadIdx.x;
  const int lane = tid & 63;
  const int wave = tid >> 6;
  const int wr = wave >> 1, wc = wave & 1;
  f4 acc[2][2] = {};
  const int sr = tid >> 2;
  const int sc = (tid & 3) << 3;
  const unsigned short* agp = Xb + (size_t)(m0 + sr) * MD + sc;
  const unsigned short* bgp = Wb + (size_t)(n0 + sr) * MD + sc;
  const int lr = lane & 15;
  const int kq = (lane >> 4) << 3;

  for (int k0 = 0; k0 < MD; k0 += 32) {
    uint4 av = *(const uint4*)(agp + k0);
    uint4 bv = *(const uint4*)(bgp + k0);
    __syncthreads();
    *(uint4*)&ldsA[sr * 40 + sc] = av;
    *(uint4*)&ldsB[sr * 40 + sc] = bv;
    __syncthreads();
    short8 a0 = *(const short8*)&ldsA[(wr * 32 + lr) * 40 + kq];
    short8 a1 = *(const short8*)&ldsA[(wr * 32 + 16 + lr) * 40 + kq];
    short8 b0 = *(const short8*)&ldsB[(wc * 32 + lr) * 40 + kq];
    short8 b1 = *(const short8*)&ldsB[(wc * 32 + 16 + lr) * 40 + kq];
    acc[0][0] = __builtin_amdgcn_mfma_f32_16x16x32_bf16(a0, b0, acc[0][0], 0, 0, 0);
    acc[0][1] = __builtin_amdgcn_mfma_f32_16x16x32_bf16(a0, b1, acc[0][1], 0, 0, 0);
    acc[1][0] = __builtin_amdgcn_mfma_f32_16x16x32_bf16(a1, b0, acc[1][0], 0, 0, 0);
    acc[1][1] = __builtin_amdgcn_mfma_f32_16x16x32_bf16(a1, b1, acc[1][1], 0, 0, 0);
  }
  // C/D layout: col = lane&15, row = (lane>>4)*4 + q  -> scatter into XWb bf16
  for (int r = 0; r < 2; ++r)
    for (int c = 0; c < 2; ++c)
      for (int q = 0; q < 4; ++q) {
        const int row = m0 + wr * 32 + r * 16 + (lane >> 4) * 4 + q;   // node
        const int col = n0 + wc * 32 + c * 16 + lr;                    // 0..4095
        const float v = acc[r][c][q] + biasC[col];
        const int g = col >> 10, cj = col & 1023;
        XWb[((size_t)(cj >> 2) * NN + row) * 16 + (g << 2) + (cj & 3)] = f2bf(v);
      }
}

// ---------------- cooperative recurrence ----------------
struct RP {
  const int4* meta;           // [NN] (node, cbeg_pos, cnt, 0)
  const int* doff;            // [NN+2]
  const int* maxd;
  const unsigned short* XWb;  // [256 strips][NN][16] bf16 x-side preactivation (+ biases)
  unsigned short* G2;         // [GBLK][NN][16] bf16: block's 4 cols x 4 gates per node
  float* CbB;                 // [GBLK][NN][4]  block's 4 c-cols per node (position-indexed)
  unsigned short* Hb;         // [NN][1024] bf16 h (only cross-block data; LLC-coherent)
  const unsigned short* Wrec; // [4096][1024] bf16 [Wiouh;Wfh]
  float* out;                 // [2048]: c_root | h_root
  int* flags;                 // [GBLK] arrival flags + [GBLK] epoch word
};

// Hierarchical fence-free grid barrier: blocks write flag[bid]; block 0 polls all
// 256 flags and publishes a single epoch word; others poll 4B. No L2 flush.
__device__ __forceinline__ void grid_barrier(int* flags, int step) {
  asm volatile("s_waitcnt vmcnt(0)" ::: "memory");   // this wave's stores acked at LLC
  __syncthreads();                                   // all waves drained
  int* epoch = flags + GBLK;
  if (blockIdx.x == 0) {
    if (threadIdx.x < 64) {
      if (threadIdx.x == 0)
        __hip_atomic_store(&flags[0], step, __ATOMIC_RELAXED, __HIP_MEMORY_SCOPE_AGENT);
      const int base = threadIdx.x << 2;
      for (;;) {
        int a = __hip_atomic_load(&flags[base + 0], __ATOMIC_RELAXED, __HIP_MEMORY_SCOPE_AGENT);
        int b = __hip_atomic_load(&flags[base + 1], __ATOMIC_RELAXED, __HIP_MEMORY_SCOPE_AGENT);
        int c = __hip_atomic_load(&flags[base + 2], __ATOMIC_RELAXED, __HIP_MEMORY_SCOPE_AGENT);
        int d = __hip_atomic_load(&flags[base + 3], __ATOMIC_RELAXED, __HIP_MEMORY_SCOPE_AGENT);
        if (__all(a >= step && b >= step && c >= step && d >= step)) break;
        __builtin_amdgcn_s_sleep(4);
      }
      if (threadIdx.x == 0)
        __hip_atomic_store(epoch, step, __ATOMIC_RELAXED, __HIP_MEMORY_SCOPE_AGENT);
    }
  } else if (threadIdx.x == 0) {
    __hip_atomic_store(&flags[blockIdx.x], step, __ATOMIC_RELAXED, __HIP_MEMORY_SCOPE_AGENT);
    while (__hip_atomic_load(epoch, __ATOMIC_RELAXED, __HIP_MEMORY_SCOPE_AGENT) < step)
      __builtin_amdgcn_s_sleep(4);
  }
  __syncthreads();
  asm volatile("" ::: "memory");
}

__global__ __launch_bounds__(GTHR, 2) void recur_kernel(RP p) {
  __shared__ alignas(16) unsigned short ldsW[16 * MD];   // 32 KiB W strip, swizzled
  __shared__ int4 ldsMeta[NN];                           // 32 KiB
  __shared__ int ldsDoff[NN + 2];                        // 8 KiB
  const int tid = threadIdx.x;
  const int bid = blockIdx.x;
  const int lane = tid & 63;
  const int wave = tid >> 6;
  // XCD-swizzled strip: one XCD's 32 blocks cover a contiguous 128-col window
  const int strip = (bid & 7) * 32 + (bid >> 3);
  const int s4 = strip << 2;             // this block's 4 columns

  // Stage W strip: LDS row j (0..15) = global W row (j>>2)*1024 + s4 + (j&3).
  for (int idx = tid; idx < 16 * 128; idx += GTHR) {
    int j = idx >> 7, kc = idx & 127;
    uint4 v = *(const uint4*)(p.Wrec + (size_t)((j >> 2) * MD + s4 + (j & 3)) * MD + (kc << 3));
    *(uint4*)(ldsW + j * MD + ((kc ^ (j & 7)) << 3)) = v;
  }
  const int maxd = *p.maxd;
  for (int i = tid; i < NN; i += GTHR) ldsMeta[i] = p.meta[i];
  for (int i = tid; i <= maxd + 1; i += GTHR) ldsDoff[i] = p.doff[i];
  __syncthreads();

  unsigned short* G2b = p.G2 + (size_t)bid * NN * 16;
  float* CbBb = p.CbB + (size_t)bid * NN * 4;
  const unsigned short* xwb = p.XWb + (size_t)strip * NN * 16;
  const int chalf = tid & 1;             // which half of the children this thread sums

  for (int d = maxd; d >= 0; --d) {
    const int lbeg = ldsDoff[d], lend = ldsDoff[d + 1];
    const int nd = lend - lbeg;

    // ---- cell: 2 threads/node (child-halves), 4 cols each; shfl_xor(1) reduce ----
    for (int ii = tid >> 1; ii < nd; ii += GTHR / 2) {
      const int pos = lbeg + ii;
      const int4 mt = ldsMeta[pos];
      const int t = mt.x, cbeg = mt.y, cnt = mt.z;
      const unsigned short* xwp = xwb + (size_t)t * 16;
      uint4 xa = *(const uint4*)xwp;         // i0..3, o0..3
      uint4 xb = *(const uint4*)(xwp + 8);   // u0..3, f0..3
      f4 gf; gf[0] = blo(xb.z); gf[1] = bhi(xb.z); gf[2] = blo(xb.w); gf[3] = bhi(xb.w);
      f4 gi = {0.f, 0.f, 0.f, 0.f}, go = gi, gu = gi, fc = gi;
      if (chalf == 0) {
        gi[0] = blo(xa.x); gi[1] = bhi(xa.x); gi[2] = blo(xa.y); gi[3] = bhi(xa.y);
        go[0] = blo(xa.z); go[1] = bhi(xa.z); go[2] = blo(xa.w); go[3] = bhi(xa.w);
        gu[0] = blo(xb.x); gu[1] = bhi(xb.x); gu[2] = blo(xb.y); gu[3] = bhi(xb.y);
      }
      for (int k = chalf; k < cnt; k += 2) {
        const unsigned short* g2 = G2b + (size_t)(cbeg + k) * 16;
        uint4 ga = *(const uint4*)(g2);        // i0..3, o0..3
        uint4 gb = *(const uint4*)(g2 + 8);    // u0..3, f0..3
        f4 cu = *(const f4*)(CbBb + (size_t)(cbeg + k) * 4);
        gi[0] += blo(ga.x); gi[1] += bhi(ga.x); gi[2] += blo(ga.y); gi[3] += bhi(ga.y);
        go[0] += blo(ga.z); go[1] += bhi(ga.z); go[2] += blo(ga.w); go[3] += bhi(ga.w);
        gu[0] += blo(gb.x); gu[1] += bhi(gb.x); gu[2] += blo(gb.y); gu[3] += bhi(gb.y);
        f4 gff; gff[0] = blo(gb.z); gff[1] = bhi(gb.z); gff[2] = blo(gb.w); gff[3] = bhi(gb.w);
        #pragma unroll
        for (int q = 0; q < 4; ++q) fc[q] += sigm(gff[q] + gf[q]) * cu[q];
      }
      #pragma unroll
      for (int q = 0; q < 4; ++q) {          // pairwise reduce the two child-halves
        gi[q] += __shfl_xor(gi[q], 1);
        go[q] += __shfl_xor(go[q], 1);
        gu[q] += __shfl_xor(gu[q], 1);
        fc[q] += __shfl_xor(fc[q], 1);
      }
      if (chalf == 0) {
        f4 cv, hv;
        #pragma unroll
        for (int q = 0; q < 4; ++q) {
          float c0 = sigm(gi[q]) * tanh_(gu[q]) + fc[q];
          cv[q] = c0;
          hv[q] = sigm(go[q]) * tanh_(c0);
        }
        *(f4*)(CbBb + (size_t)pos * 4) = cv;
        unsigned long long hp =
            (unsigned long long)f2bf(hv[0]) |
            ((unsigned long long)f2bf(hv[1]) << 16) |
            ((unsigned long long)f2bf(hv[2]) << 32) |
            ((unsigned long long)f2bf(hv[3]) << 48);
        __hip_atomic_store((unsigned long long*)(p.Hb + (size_t)t * MD + s4),
                           hp, __ATOMIC_RELAXED, __HIP_MEMORY_SCOPE_AGENT);
        if (t == NN - 1) {                   // root: output (c | h) fp32
          *(f4*)(p.out + s4) = cv;
          *(f4*)(p.out + MD + s4) = hv;
        }
      }
    }
    if (d == 0) break;

    // ---- grid barrier: h of level d now visible at LLC ----
    grid_barrier(p.flags, maxd - d + 1);

    // ---- gemm: G2b[pos][0..15] = h[node(pos)] @ Wstrip^T (16 G-cols) ----
    {
      const int ntr = (nd + 15) >> 4;
      const int lr = lane & 15;
      const int kq = lane >> 4;
      const int swz = lr & 7;
      const unsigned short* wb0 = ldsW + lr * MD;
      for (int rt = wave; rt < ntr; rt += GTHR / 64) {
        const int r = (rt << 4) + lr;
        const int pos = lbeg + ((r < nd) ? r : 0);
        const int node = ldsMeta[pos].x;
        const unsigned short* ap = p.Hb + (size_t)node * MD + (kq << 3);
        short8 ar[8];                        // 8-deep load ring (fully unrolled -> regs)
        #pragma unroll
        for (int ks = 0; ks < 8; ++ks) ar[ks] = *(const short8*)(ap + (ks << 5));
        f4 ae = {0.f, 0.f, 0.f, 0.f}, ao = {0.f, 0.f, 0.f, 0.f};
        #pragma unroll
        for (int kb = 0; kb < 32; ++kb) {
          const int kch = (kb << 2) + kq;
          short8 b = *(const short8*)(wb0 + ((kch ^ swz) << 3));
          if (kb & 1) ao = __builtin_amdgcn_mfma_f32_16x16x32_bf16(ar[kb & 7], b, ao, 0, 0, 0);
          else        ae = __builtin_amdgcn_mfma_f32_16x16x32_bf16(ar[kb & 7], b, ae, 0, 0, 0);
          if (kb + 8 < 32) ar[kb & 7] = *(const short8*)(ap + ((kb + 8) << 5));
        }
        const int rb = (rt << 4) + (kq << 2);
        #pragma unroll
        for (int q = 0; q < 4; ++q) {        // C/D: col = lane&15, row = kq*4+q
          const int rr = rb + q;
          if (rr < nd) G2b[(size_t)(lbeg + rr) * 16 + lr] = f2bf(ae[q] + ao[q]);
        }
      }
    }
    __syncthreads();   // block-local G2/CbB handoff to next cell
  }
}

// ---------------- launch ----------------
extern "C" void kernel_launch(void* const* d_in, const int* in_sizes, int n_in,
                              void* d_out, int out_size, void* d_ws, size_t ws_size,
                              hipStream_t stream) {
  const float* X     = (const float*)d_in[0];
  const int*   parent= (const int*)d_in[1];
  const float* Wioux = (const float*)d_in[2];
  const float* bioux = (const float*)d_in[3];
  const float* Wiouh = (const float*)d_in[4];
  const float* biouh = (const float*)d_in[5];
  const float* Wfx   = (const float*)d_in[6];
  const float* bfx   = (const float*)d_in[7];
  const float* Wfh   = (const float*)d_in[8];
  const float* bfh   = (const float*)d_in[9];
  float* out = (float*)d_out;

  char* ws = (char*)d_ws;
  size_t o = 0;
  auto alloc = [&](size_t bytes) { size_t r = o; o += (bytes + 255) & ~(size_t)255; return r; };
  unsigned short* Xb   = (unsigned short*)(ws + alloc((size_t)NN * MD * 2));
  unsigned short* Wpre = (unsigned short*)(ws + alloc((size_t)NOUT * MD * 2));
  unsigned short* Wrec = (unsigned short*)(ws + alloc((size_t)NOUT * MD * 2));
  unsigned short* XWb  = (unsigned short*)(ws + alloc((size_t)GBLK * NN * 16 * 2));
  unsigned short* G2   = (unsigned short*)(ws + alloc((size_t)GBLK * NN * 16 * 2));
  float* CbB           = (float*)(ws + alloc((size_t)GBLK * NN * 4 * 4));
  unsigned short* Hb   = (unsigned short*)(ws + alloc((size_t)NN * MD * 2));
  float* biasC         = (float*)(ws + alloc((size_t)NOUT * 4));
  int4* meta           = (int4*)(ws + alloc((size_t)NN * 16));
  int* doff            = (int*)(ws + alloc((NN + 4) * 4));
  int* maxd            = (int*)(ws + alloc(256));
  int* flags           = (int*)(ws + alloc((GBLK + 64) * 4));

  {
    int n4;
    n4 = NN * MD / 4;
    cvt_bf16_kernel<<<(n4 + 255) / 256, 256, 0, stream>>>(X, Xb, n4);
    n4 = 3072 * MD / 4;
    cvt_bf16_kernel<<<(n4 + 255) / 256, 256, 0, stream>>>(Wioux, Wpre, n4);
    n4 = 1024 * MD / 4;
    cvt_bf16_kernel<<<(n4 + 255) / 256, 256, 0, stream>>>(Wfx, Wpre + (size_t)3072 * MD, n4);
    n4 = 3072 * MD / 4;
    cvt_bf16_kernel<<<(n4 + 255) / 256, 256, 0, stream>>>(Wiouh, Wrec, n4);
    n4 = 1024 * MD / 4;
    cvt_bf16_kernel<<<(n4 + 255) / 256, 256, 0, stream>>>(Wfh, Wrec + (size_t)3072 * MD, n4);
  }

  bias_combine_kernel<<<16, 256, 0, stream>>>(bioux, biouh, bfx, bfh, biasC);

  prep_kernel<<<1, 1024, 0, stream>>>(parent, meta, doff, maxd, flags);

  pregemm_kernel<<<(NN / 64) * (NOUT / 64), 256, 0, stream>>>(Xb, Wpre, XWb, biasC);

  RP p;
  p.meta = meta; p.doff = doff; p.maxd = maxd;
  p.XWb = XWb; p.G2 = G2; p.CbB = CbB; p.Hb = Hb; p.Wrec = Wrec;
  p.out = out; p.flags = flags;
  void* args[] = {&p};
  hipLaunchCooperativeKernel((const void*)recur_kernel, dim3(GBLK), dim3(GTHR), args, 0, stream);

  (void)in_sizes; (void)n_in; (void)out_size; (void)ws_size;
}

// Round 7
// 482.610 us; speedup vs baseline: 4.0450x; 1.1436x over previous
//
#include <hip/hip_runtime.h>

#define NN 2048          // nodes
#define MD 1024          // mem/input dim
#define NOUT 4096        // 3M (iou) + M (f) output columns
#define GBLK 256         // cooperative grid blocks: one 4-col strip each
#define GTHR 1024        // threads per block (16 waves)
#define CAP 1024         // max level width held in LDS (spill to global beyond)

typedef __attribute__((ext_vector_type(8))) short short8;   // 8 x bf16 fragment
typedef __attribute__((ext_vector_type(4))) float f4;

__device__ __forceinline__ unsigned short f2bf(float f) {
  unsigned u = __float_as_uint(f);
  u += 0x7fffu + ((u >> 16) & 1u);      // RNE
  return (unsigned short)(u >> 16);
}
__device__ __forceinline__ float blo(unsigned u) { return __uint_as_float(u << 16); }
__device__ __forceinline__ float bhi(unsigned u) { return __uint_as_float(u & 0xffff0000u); }
__device__ __forceinline__ float sigm(float x) { return 1.0f / (1.0f + __expf(-x)); }
__device__ __forceinline__ float tanh_(float x) { return 1.0f - 2.0f / (1.0f + __expf(2.0f * x)); }

// ---------------- fp32 -> bf16 conversion (vector x4) ----------------
__global__ __launch_bounds__(256) void cvt_bf16_kernel(const float* __restrict__ s,
                                                       unsigned short* __restrict__ d, int n4) {
  int i = blockIdx.x * 256 + threadIdx.x;
  if (i < n4) {
    f4 v = *((const f4*)s + i);
    unsigned lo = f2bf(v[0]) | ((unsigned)f2bf(v[1]) << 16);
    unsigned hi = f2bf(v[2]) | ((unsigned)f2bf(v[3]) << 16);
    uint2 r; r.x = lo; r.y = hi;
    *((uint2*)d + i) = r;
  }
}

// ---------------- combined bias: biasC = [bioux+biouh ; bfx+bfh] ----------------
__global__ __launch_bounds__(256) void bias_combine_kernel(const float* __restrict__ bioux,
                                                           const float* __restrict__ biouh,
                                                           const float* __restrict__ bfx,
                                                           const float* __restrict__ bfh,
                                                           float* __restrict__ biasC) {
  int i = blockIdx.x * 256 + threadIdx.x;
  if (i < 3072) biasC[i] = bioux[i] + biouh[i];
  else if (i < 4096) biasC[i] = bfx[i - 3072] + bfh[i - 3072];
}

// ---------------- prep: depth, parent-sort, BFS parent-grouped level order ----------------
// meta[pos] = (node, (crel<<16)|cnt) with crel = child start RELATIVE to child level.
__global__ __launch_bounds__(1024) void prep_kernel(const int* __restrict__ parent,
                                                    int2* __restrict__ meta,
                                                    int* __restrict__ doff_g,
                                                    int* __restrict__ maxd_out,
                                                    int* __restrict__ flags) {
  __shared__ int s_anc[NN], s_dep[NN];
  __shared__ int s_t1[NN + 2], s_t2[NN + 2];
  __shared__ int s_poff[NN + 2], s_cur[NN + 2];
  __shared__ int s_ordp[NN], s_nord[NN];
  __shared__ int s_doff[NN + 2];
  __shared__ int s_sc[NN], s_sc2[NN];
  __shared__ int s_wsum[17];
  __shared__ int s_maxd;
  const int tid = threadIdx.x;

  if (tid == 0) s_maxd = 0;
  for (int i = tid; i < GBLK + 64; i += 1024) flags[i] = 0;   // reset barrier epochs
  for (int t = tid; t < NN; t += 1024) {
    bool root = (t == NN - 1);
    s_anc[t] = root ? t : parent[t];
    s_dep[t] = root ? 0 : 1;
  }
  __syncthreads();
  for (int it = 0; it < 11; ++it) {     // 2^11 >= NN
    for (int t = tid; t < NN; t += 1024) { int a = s_anc[t]; s_t1[t] = s_dep[t] + s_dep[a]; s_t2[t] = s_anc[a]; }
    __syncthreads();
    for (int t = tid; t < NN; t += 1024) { s_dep[t] = s_t1[t]; s_anc[t] = s_t2[t]; }
    __syncthreads();
  }
  for (int t = tid; t < NN; t += 1024) atomicMax(&s_maxd, s_dep[t]);

  // ---- counting sort by parent -> s_ordp with offsets s_poff ----
  for (int i = tid; i < NN + 2; i += 1024) s_t2[i] = 0;
  __syncthreads();
  for (int t = tid; t < NN; t += 1024) atomicAdd(&s_t2[parent[t]], 1);
  __syncthreads();
  {
    const int L = NN + 2;
    int* src = s_t2; int* dst = s_t1;
    for (int o = 1; o < L; o <<= 1) {
      for (int i = tid; i < L; i += 1024) dst[i] = src[i] + ((i >= o) ? src[i - o] : 0);
      __syncthreads();
      int* tmp = src; src = dst; dst = tmp;
    }
    for (int i = tid; i < L; i += 1024) { int v = (i ? src[i - 1] : 0); s_poff[i] = v; s_cur[i] = v; }
    __syncthreads();
    for (int t = tid; t < NN; t += 1024) {
      int pos = atomicAdd(&s_cur[parent[t]], 1);
      s_ordp[pos] = t;
    }
    __syncthreads();
    for (int p = tid; p < NN + 1; p += 1024) {    // determinism within bucket
      int b = s_poff[p], e = s_poff[p + 1];
      for (int i = b + 1; i < e; ++i) {
        int v = s_ordp[i], j = i - 1;
        while (j >= b && s_ordp[j] > v) { s_ordp[j + 1] = s_ordp[j]; --j; }
        s_ordp[j + 1] = v;
      }
    }
    __syncthreads();
  }

  // ---- counts by depth -> s_doff ----
  for (int i = tid; i < NN + 2; i += 1024) s_t2[i] = 0;
  __syncthreads();
  for (int t = tid; t < NN; t += 1024) atomicAdd(&s_t2[s_dep[t]], 1);
  __syncthreads();
  {
    const int L = NN + 1;
    int* src = s_t2; int* dst = s_t1;
    for (int o = 1; o < L; o <<= 1) {
      for (int i = tid; i < L; i += 1024) dst[i] = src[i] + ((i >= o) ? src[i - o] : 0);
      __syncthreads();
      int* tmp = src; src = dst; dst = tmp;
    }
    for (int i = tid; i < L + 1; i += 1024) s_doff[i] = (i ? src[i - 1] : 0);
    __syncthreads();
  }

  // ---- BFS: parent-grouped order per level; child indices level-relative ----
  const int maxd = s_maxd;
  if (tid == 0) s_nord[0] = NN - 1;     // root at position 0
  __syncthreads();
  for (int d = 0; d < maxd; ++d) {
    const int lbeg = s_doff[d], lend = s_doff[d + 1];
    const int nd = lend - lbeg;
    if (nd <= 1024) {
      int t = -1, v = 0;
      if (tid < nd) { t = s_nord[lbeg + tid]; v = s_poff[t + 1] - s_poff[t]; }
      #pragma unroll
      for (int o = 1; o < 64; o <<= 1) {
        int u = __shfl_up(v, (unsigned)o, 64);
        if ((tid & 63) >= o) v += u;
      }
      if ((tid & 63) == 63) s_wsum[tid >> 6] = v;
      __syncthreads();
      if (tid < 16) {
        int w = s_wsum[tid];
        #pragma unroll
        for (int o = 1; o < 16; o <<= 1) {
          int u = __shfl_up(w, (unsigned)o, 16);
          if (tid >= o) w += u;
        }
        s_wsum[tid] = w;
      }
      __syncthreads();
      if (tid < nd) {
        int incl = v + ((tid >> 6) ? s_wsum[(tid >> 6) - 1] : 0);
        int cnti = s_poff[t + 1] - s_poff[t];
        int crel = incl - cnti;                    // relative to level d+1 start
        meta[lbeg + tid] = make_int2(t, (crel << 16) | cnti);
        for (int j = 0; j < cnti; ++j) s_nord[lend + crel + j] = s_ordp[s_poff[t] + j];
      }
      __syncthreads();
    } else {                             // fallback (pathological trees)
      for (int i = tid; i < nd; i += 1024) { int t2 = s_nord[lbeg + i]; s_sc[i] = s_poff[t2 + 1] - s_poff[t2]; }
      __syncthreads();
      for (int o = 1; o < nd; o <<= 1) {
        for (int i = tid; i < nd; i += 1024) s_sc2[i] = s_sc[i] + ((i >= o) ? s_sc[i - o] : 0);
        __syncthreads();
        for (int i = tid; i < nd; i += 1024) s_sc[i] = s_sc2[i];
        __syncthreads();
      }
      for (int i = tid; i < nd; i += 1024) {
        int t2 = s_nord[lbeg + i];
        int cnti = s_poff[t2 + 1] - s_poff[t2];
        int crel = s_sc[i] - cnti;
        meta[lbeg + i] = make_int2(t2, (crel << 16) | cnti);
        for (int j = 0; j < cnti; ++j) s_nord[lend + crel + j] = s_ordp[s_poff[t2] + j];
      }
      __syncthreads();
    }
  }
  {                                      // deepest level: all leaves
    const int lbeg = s_doff[maxd], lend = s_doff[maxd + 1];
    for (int i = lbeg + tid; i < lend; i += 1024)
      meta[i] = make_int2(s_nord[i], 0);
  }
  for (int i = tid; i <= maxd + 1; i += 1024) doff_g[i] = s_doff[i];
  if (tid == 0) *maxd_out = maxd;
}

// ---------------- pre-GEMM: XWb[strip][node][16] bf16 = X @ [Wioux;Wfx]^T + biasC ----------------
__global__ __launch_bounds__(256) void pregemm_kernel(const unsigned short* __restrict__ Xb,
                                                      const unsigned short* __restrict__ Wb,
                                                      unsigned short* __restrict__ XWb,
                                                      const float* __restrict__ biasC) {
  __shared__ alignas(16) unsigned short ldsA[64 * 40];
  __shared__ alignas(16) unsigned short ldsB[64 * 40];
  const int tn = blockIdx.x & 63;
  const int tm = blockIdx.x >> 6;
  const int m0 = tm * 64, n0 = tn * 64;
  const int tid = threadIdx.x;
  const int lane = tid & 63;
  const int wave = tid >> 6;
  const int wr = wave >> 1, wc = wave & 1;
  f4 acc[2][2] = {};
  const int sr = tid >> 2;
  const int sc = (tid & 3) << 3;
  const unsigned short* agp = Xb + (size_t)(m0 + sr) * MD + sc;
  const unsigned short* bgp = Wb + (size_t)(n0 + sr) * MD + sc;
  const int lr = lane & 15;
  const int kq = (lane >> 4) << 3;

  for (int k0 = 0; k0 < MD; k0 += 32) {
    uint4 av = *(const uint4*)(agp + k0);
    uint4 bv = *(const uint4*)(bgp + k0);
    __syncthreads();
    *(uint4*)&ldsA[sr * 40 + sc] = av;
    *(uint4*)&ldsB[sr * 40 + sc] = bv;
    __syncthreads();
    short8 a0 = *(const short8*)&ldsA[(wr * 32 + lr) * 40 + kq];
    short8 a1 = *(const short8*)&ldsA[(wr * 32 + 16 + lr) * 40 + kq];
    short8 b0 = *(const short8*)&ldsB[(wc * 32 + lr) * 40 + kq];
    short8 b1 = *(const short8*)&ldsB[(wc * 32 + 16 + lr) * 40 + kq];
    acc[0][0] = __builtin_amdgcn_mfma_f32_16x16x32_bf16(a0, b0, acc[0][0], 0, 0, 0);
    acc[0][1] = __builtin_amdgcn_mfma_f32_16x16x32_bf16(a0, b1, acc[0][1], 0, 0, 0);
    acc[1][0] = __builtin_amdgcn_mfma_f32_16x16x32_bf16(a1, b0, acc[1][0], 0, 0, 0);
    acc[1][1] = __builtin_amdgcn_mfma_f32_16x16x32_bf16(a1, b1, acc[1][1], 0, 0, 0);
  }
  // C/D layout: col = lane&15, row = (lane>>4)*4 + q  -> scatter into XWb bf16
  for (int r = 0; r < 2; ++r)
    for (int c = 0; c < 2; ++c)
      for (int q = 0; q < 4; ++q) {
        const int row = m0 + wr * 32 + r * 16 + (lane >> 4) * 4 + q;   // node
        const int col = n0 + wc * 32 + c * 16 + lr;                    // 0..4095
        const float v = acc[r][c][q] + biasC[col];
        const int g = col >> 10, cj = col & 1023;
        XWb[((size_t)(cj >> 2) * NN + row) * 16 + (g << 2) + (cj & 3)] = f2bf(v);
      }
}

// ---------------- cooperative recurrence ----------------
struct RP {
  const int2* meta;           // [NN] (node, (crel<<16)|cnt)
  const int* doff;            // [NN+2]
  const int* maxd;
  const unsigned short* XWb;  // [256 strips][NN][16] bf16 x-side preactivation (+ biases)
  unsigned short* G2;         // [GBLK][NN][16] bf16 spill (level width > CAP only)
  float* CbB;                 // [GBLK][NN][4]  fp32 spill
  unsigned short* Hb;         // [NN][1024] bf16 h (only cross-block data; LLC-coherent)
  const unsigned short* Wrec; // [4096][1024] bf16 [Wiouh;Wfh]
  float* out;                 // [2048]: c_root | h_root
  int* flags;                 // [GBLK] arrival flags + epoch word
};

// Hierarchical fence-free grid barrier: blocks write flag[bid]; block 0 polls all
// 256 flags and publishes a single epoch word; others poll 4B. No L2 flush.
__device__ __forceinline__ void grid_barrier(int* flags, int step) {
  asm volatile("s_waitcnt vmcnt(0)" ::: "memory");   // this wave's stores acked at LLC
  __syncthreads();                                   // all waves drained
  int* epoch = flags + GBLK;
  if (blockIdx.x == 0) {
    if (threadIdx.x < 64) {
      if (threadIdx.x == 0)
        __hip_atomic_store(&flags[0], step, __ATOMIC_RELAXED, __HIP_MEMORY_SCOPE_AGENT);
      const int base = threadIdx.x << 2;
      for (;;) {
        int a = __hip_atomic_load(&flags[base + 0], __ATOMIC_RELAXED, __HIP_MEMORY_SCOPE_AGENT);
        int b = __hip_atomic_load(&flags[base + 1], __ATOMIC_RELAXED, __HIP_MEMORY_SCOPE_AGENT);
        int c = __hip_atomic_load(&flags[base + 2], __ATOMIC_RELAXED, __HIP_MEMORY_SCOPE_AGENT);
        int d = __hip_atomic_load(&flags[base + 3], __ATOMIC_RELAXED, __HIP_MEMORY_SCOPE_AGENT);
        if (__all(a >= step && b >= step && c >= step && d >= step)) break;
        __builtin_amdgcn_s_sleep(2);
      }
      if (threadIdx.x == 0)
        __hip_atomic_store(epoch, step, __ATOMIC_RELAXED, __HIP_MEMORY_SCOPE_AGENT);
    }
  } else if (threadIdx.x == 0) {
    __hip_atomic_store(&flags[blockIdx.x], step, __ATOMIC_RELAXED, __HIP_MEMORY_SCOPE_AGENT);
    while (__hip_atomic_load(epoch, __ATOMIC_RELAXED, __HIP_MEMORY_SCOPE_AGENT) < step)
      __builtin_amdgcn_s_sleep(2);
  }
  __syncthreads();
  asm volatile("" ::: "memory");
}

__global__ __launch_bounds__(GTHR, 1) void recur_kernel(RP p) {
  __shared__ alignas(16) unsigned short ldsW[16 * MD];   // 32 KiB W strip, swizzled
  __shared__ alignas(16) unsigned short G2L[CAP * 16];   // 32 KiB level-local G (bf16)
  __shared__ alignas(16) float CbL[2 * CAP * 4];         // 32 KiB level-local c (ping-pong)
  __shared__ int2 ldsMeta[NN];                           // 16 KiB
  __shared__ int ldsDoff[NN + 2];                        // 8 KiB
  const int tid = threadIdx.x;
  const int bid = blockIdx.x;
  const int lane = tid & 63;
  const int wave = tid >> 6;
  // XCD-swizzled strip: one XCD's 32 blocks cover a contiguous 128-col window
  const int strip = (bid & 7) * 32 + (bid >> 3);
  const int s4 = strip << 2;             // this block's 4 columns

  // Stage W strip: LDS row j (0..15) = global W row (j>>2)*1024 + s4 + (j&3).
  for (int idx = tid; idx < 16 * 128; idx += GTHR) {
    int j = idx >> 7, kc = idx & 127;
    uint4 v = *(const uint4*)(p.Wrec + (size_t)((j >> 2) * MD + s4 + (j & 3)) * MD + (kc << 3));
    *(uint4*)(ldsW + j * MD + ((kc ^ (j & 7)) << 3)) = v;
  }
  const int maxd = *p.maxd;
  for (int i = tid; i < NN; i += GTHR) ldsMeta[i] = p.meta[i];
  for (int i = tid; i <= maxd + 1; i += GTHR) ldsDoff[i] = p.doff[i];
  __syncthreads();

  const unsigned short* xwb = p.XWb + (size_t)strip * NN * 16;
  unsigned short* G2g = p.G2 + (size_t)bid * NN * 16;    // spill only
  float* CbBg = p.CbB + (size_t)bid * NN * 4;            // spill only
  const int chalf = tid & 1;             // which half of the children this thread sums

  for (int d = maxd; d >= 0; --d) {
    const int lbeg = ldsDoff[d], lend = ldsDoff[d + 1];
    const int nd = lend - lbeg;
    float* cbw = CbL + (size_t)(d & 1) * CAP * 4;        // this level's c
    const float* cbr = CbL + (size_t)((d + 1) & 1) * CAP * 4;  // child level's c

    // ---- cell: 2 threads/node (child-halves), 4 cols each; shfl_xor(1) reduce ----
    for (int ii = tid >> 1; ii < nd; ii += GTHR / 2) {
      const int2 mt = ldsMeta[lbeg + ii];
      const int t = mt.x, crel = mt.y >> 16, cnt = mt.y & 0xffff;
      const unsigned short* xwp = xwb + (size_t)t * 16;
      uint4 xa = *(const uint4*)xwp;         // i0..3, o0..3
      uint4 xb = *(const uint4*)(xwp + 8);   // u0..3, f0..3
      f4 gf; gf[0] = blo(xb.z); gf[1] = bhi(xb.z); gf[2] = blo(xb.w); gf[3] = bhi(xb.w);
      f4 gi = {0.f, 0.f, 0.f, 0.f}, go = gi, gu = gi, fc = gi;
      if (chalf == 0) {
        gi[0] = blo(xa.x); gi[1] = bhi(xa.x); gi[2] = blo(xa.y); gi[3] = bhi(xa.y);
        go[0] = blo(xa.z); go[1] = bhi(xa.z); go[2] = blo(xa.w); go[3] = bhi(xa.w);
        gu[0] = blo(xb.x); gu[1] = bhi(xb.x); gu[2] = blo(xb.y); gu[3] = bhi(xb.y);
      }
      for (int k = chalf; k < cnt; k += 2) {
        const int ci = crel + k;
        uint4 ga, gb; f4 cu;
        if (ci < CAP) {                       // LDS-resident child (normal path)
          ga = *(const uint4*)(G2L + ci * 16);
          gb = *(const uint4*)(G2L + ci * 16 + 8);
          cu = *(const f4*)(cbr + ci * 4);
        } else {                              // spill (level wider than CAP)
          const unsigned short* g2 = G2g + (size_t)(lend + ci) * 16;
          ga = *(const uint4*)(g2);
          gb = *(const uint4*)(g2 + 8);
          cu = *(const f4*)(CbBg + (size_t)(lend + ci) * 4);
        }
        gi[0] += blo(ga.x); gi[1] += bhi(ga.x); gi[2] += blo(ga.y); gi[3] += bhi(ga.y);
        go[0] += blo(ga.z); go[1] += bhi(ga.z); go[2] += blo(ga.w); go[3] += bhi(ga.w);
        gu[0] += blo(gb.x); gu[1] += bhi(gb.x); gu[2] += blo(gb.y); gu[3] += bhi(gb.y);
        f4 gff; gff[0] = blo(gb.z); gff[1] = bhi(gb.z); gff[2] = blo(gb.w); gff[3] = bhi(gb.w);
        #pragma unroll
        for (int q = 0; q < 4; ++q) fc[q] += sigm(gff[q] + gf[q]) * cu[q];
      }
      #pragma unroll
      for (int q = 0; q < 4; ++q) {          // pairwise reduce the two child-halves
        gi[q] += __shfl_xor(gi[q], 1);
        go[q] += __shfl_xor(go[q], 1);
        gu[q] += __shfl_xor(gu[q], 1);
        fc[q] += __shfl_xor(fc[q], 1);
      }
      if (chalf == 0) {
        f4 cv, hv;
        #pragma unroll
        for (int q = 0; q < 4; ++q) {
          float c0 = sigm(gi[q]) * tanh_(gu[q]) + fc[q];
          cv[q] = c0;
          hv[q] = sigm(go[q]) * tanh_(c0);
        }
        if (ii < CAP) *(f4*)(cbw + ii * 4) = cv;
        else          *(f4*)(CbBg + (size_t)(lbeg + ii) * 4) = cv;
        unsigned long long hp =
            (unsigned long long)f2bf(hv[0]) |
            ((unsigned long long)f2bf(hv[1]) << 16) |
            ((unsigned long long)f2bf(hv[2]) << 32) |
            ((unsigned long long)f2bf(hv[3]) << 48);
        __hip_atomic_store((unsigned long long*)(p.Hb + (size_t)t * MD + s4),
                           hp, __ATOMIC_RELAXED, __HIP_MEMORY_SCOPE_AGENT);
        if (t == NN - 1) {                   // root: output (c | h) fp32
          *(f4*)(p.out + s4) = cv;
          *(f4*)(p.out + MD + s4) = hv;
        }
      }
    }
    if (d == 0) break;

    // ---- grid barrier: h of level d now visible at LLC (also block-syncs) ----
    grid_barrier(p.flags, maxd - d + 1);

    // ---- gemm: G2L[rr][0..15] = h[node(rr)] @ Wstrip^T (16 G-cols) ----
    {
      const int ntr = (nd + 15) >> 4;
      const int lr = lane & 15;
      const int kq = lane >> 4;
      const int swz = lr & 7;
      const unsigned short* wb0 = ldsW + lr * MD;
      for (int rt = wave; rt < ntr; rt += GTHR / 64) {
        const int r = (rt << 4) + lr;
        const int pos = lbeg + ((r < nd) ? r : 0);
        const int node = ldsMeta[pos].x;
        const unsigned short* ap = p.Hb + (size_t)node * MD + (kq << 3);
        short8 ar[8];                        // 8-deep load ring (fully unrolled -> regs)
        #pragma unroll
        for (int ks = 0; ks < 8; ++ks) ar[ks] = *(const short8*)(ap + (ks << 5));
        f4 ae = {0.f, 0.f, 0.f, 0.f}, ao = {0.f, 0.f, 0.f, 0.f};
        #pragma unroll
        for (int kb = 0; kb < 32; ++kb) {
          const int kch = (kb << 2) + kq;
          short8 b = *(const short8*)(wb0 + ((kch ^ swz) << 3));
          if (kb & 1) ao = __builtin_amdgcn_mfma_f32_16x16x32_bf16(ar[kb & 7], b, ao, 0, 0, 0);
          else        ae = __builtin_amdgcn_mfma_f32_16x16x32_bf16(ar[kb & 7], b, ae, 0, 0, 0);
          if (kb + 8 < 32) ar[kb & 7] = *(const short8*)(ap + ((kb + 8) << 5));
        }
        const int rb = (rt << 4) + (kq << 2);
        #pragma unroll
        for (int q = 0; q < 4; ++q) {        // C/D: col = lane&15, row = kq*4+q
          const int rr = rb + q;
          if (rr < nd) {
            unsigned short v = f2bf(ae[q] + ao[q]);
            if (rr < CAP) G2L[rr * 16 + lr] = v;
            else          G2g[(size_t)(lbeg + rr) * 16 + lr] = v;
          }
        }
      }
    }
    __syncthreads();   // G2L/CbL handoff to next cell
  }
}

// ---------------- launch ----------------
extern "C" void kernel_launch(void* const* d_in, const int* in_sizes, int n_in,
                              void* d_out, int out_size, void* d_ws, size_t ws_size,
                              hipStream_t stream) {
  const float* X     = (const float*)d_in[0];
  const int*   parent= (const int*)d_in[1];
  const float* Wioux = (const float*)d_in[2];
  const float* bioux = (const float*)d_in[3];
  const float* Wiouh = (const float*)d_in[4];
  const float* biouh = (const float*)d_in[5];
  const float* Wfx   = (const float*)d_in[6];
  const float* bfx   = (const float*)d_in[7];
  const float* Wfh   = (const float*)d_in[8];
  const float* bfh   = (const float*)d_in[9];
  float* out = (float*)d_out;

  char* ws = (char*)d_ws;
  size_t o = 0;
  auto alloc = [&](size_t bytes) { size_t r = o; o += (bytes + 255) & ~(size_t)255; return r; };
  unsigned short* Xb   = (unsigned short*)(ws + alloc((size_t)NN * MD * 2));
  unsigned short* Wpre = (unsigned short*)(ws + alloc((size_t)NOUT * MD * 2));
  unsigned short* Wrec = (unsigned short*)(ws + alloc((size_t)NOUT * MD * 2));
  unsigned short* XWb  = (unsigned short*)(ws + alloc((size_t)GBLK * NN * 16 * 2));
  unsigned short* G2   = (unsigned short*)(ws + alloc((size_t)GBLK * NN * 16 * 2));
  float* CbB           = (float*)(ws + alloc((size_t)GBLK * NN * 4 * 4));
  unsigned short* Hb   = (unsigned short*)(ws + alloc((size_t)NN * MD * 2));
  float* biasC         = (float*)(ws + alloc((size_t)NOUT * 4));
  int2* meta           = (int2*)(ws + alloc((size_t)NN * 8));
  int* doff            = (int*)(ws + alloc((NN + 4) * 4));
  int* maxd            = (int*)(ws + alloc(256));
  int* flags           = (int*)(ws + alloc((GBLK + 64) * 4));

  {
    int n4;
    n4 = NN * MD / 4;
    cvt_bf16_kernel<<<(n4 + 255) / 256, 256, 0, stream>>>(X, Xb, n4);
    n4 = 3072 * MD / 4;
    cvt_bf16_kernel<<<(n4 + 255) / 256, 256, 0, stream>>>(Wioux, Wpre, n4);
    n4 = 1024 * MD / 4;
    cvt_bf16_kernel<<<(n4 + 255) / 256, 256, 0, stream>>>(Wfx, Wpre + (size_t)3072 * MD, n4);
    n4 = 3072 * MD / 4;
    cvt_bf16_kernel<<<(n4 + 255) / 256, 256, 0, stream>>>(Wiouh, Wrec, n4);
    n4 = 1024 * MD / 4;
    cvt_bf16_kernel<<<(n4 + 255) / 256, 256, 0, stream>>>(Wfh, Wrec + (size_t)3072 * MD, n4);
  }

  bias_combine_kernel<<<16, 256, 0, stream>>>(bioux, biouh, bfx, bfh, biasC);

  prep_kernel<<<1, 1024, 0, stream>>>(parent, meta, doff, maxd, flags);

  pregemm_kernel<<<(NN / 64) * (NOUT / 64), 256, 0, stream>>>(Xb, Wpre, XWb, biasC);

  RP p;
  p.meta = meta; p.doff = doff; p.maxd = maxd;
  p.XWb = XWb; p.G2 = G2; p.CbB = CbB; p.Hb = Hb; p.Wrec = Wrec;
  p.out = out; p.flags = flags;
  void* args[] = {&p};
  hipLaunchCooperativeKernel((const void*)recur_kernel, dim3(GBLK), dim3(GTHR), args, 0, stream);

  (void)in_sizes; (void)n_in; (void)out_size; (void)ws_size;
}

// Round 8
// 471.549 us; speedup vs baseline: 4.1399x; 1.0235x over previous
//
#include <hip/hip_runtime.h>

#define NN 2048          // nodes
#define MD 1024          // mem/input dim
#define NOUT 4096        // 3M (iou) + M (f) output columns
#define GBLK 256         // cooperative grid blocks: one 4-col strip each
#define GTHR 1024        // threads per block (16 waves)
#define CAP 1024         // max level width held in LDS (spill to global beyond)

typedef __attribute__((ext_vector_type(8))) short short8;   // 8 x bf16 fragment
typedef __attribute__((ext_vector_type(4))) float f4;

__device__ __forceinline__ unsigned short f2bf(float f) {
  unsigned u = __float_as_uint(f);
  u += 0x7fffu + ((u >> 16) & 1u);      // RNE
  return (unsigned short)(u >> 16);
}
__device__ __forceinline__ uint4 pack8(f4 a, f4 b) {
  uint4 r;
  r.x = f2bf(a[0]) | ((unsigned)f2bf(a[1]) << 16);
  r.y = f2bf(a[2]) | ((unsigned)f2bf(a[3]) << 16);
  r.z = f2bf(b[0]) | ((unsigned)f2bf(b[1]) << 16);
  r.w = f2bf(b[2]) | ((unsigned)f2bf(b[3]) << 16);
  return r;
}
__device__ __forceinline__ float blo(unsigned u) { return __uint_as_float(u << 16); }
__device__ __forceinline__ float bhi(unsigned u) { return __uint_as_float(u & 0xffff0000u); }
__device__ __forceinline__ float sigm(float x) { return 1.0f / (1.0f + __expf(-x)); }
__device__ __forceinline__ float tanh_(float x) { return 1.0f - 2.0f / (1.0f + __expf(2.0f * x)); }

// ---------------- fp32 -> bf16 conversion (vector x4) ----------------
__global__ __launch_bounds__(256) void cvt_bf16_kernel(const float* __restrict__ s,
                                                       unsigned short* __restrict__ d, int n4) {
  int i = blockIdx.x * 256 + threadIdx.x;
  if (i < n4) {
    f4 v = *((const f4*)s + i);
    unsigned lo = f2bf(v[0]) | ((unsigned)f2bf(v[1]) << 16);
    unsigned hi = f2bf(v[2]) | ((unsigned)f2bf(v[3]) << 16);
    uint2 r; r.x = lo; r.y = hi;
    *((uint2*)d + i) = r;
  }
}

// ---------------- prep: depth, parent-sort, BFS order, biasC, flag reset ----------------
// meta[pos] = (node, (crel<<16)|cnt) with crel = child start RELATIVE to child level.
__global__ __launch_bounds__(1024) void prep_kernel(const int* __restrict__ parent,
                                                    int2* __restrict__ meta,
                                                    int* __restrict__ doff_g,
                                                    int* __restrict__ maxd_out,
                                                    int* __restrict__ flags,
                                                    const float* __restrict__ bioux,
                                                    const float* __restrict__ biouh,
                                                    const float* __restrict__ bfx,
                                                    const float* __restrict__ bfh,
                                                    float* __restrict__ biasC) {
  __shared__ int s_anc[NN], s_dep[NN];
  __shared__ int s_t1[NN + 2], s_t2[NN + 2];
  __shared__ int s_poff[NN + 2], s_cur[NN + 2];
  __shared__ int s_ordp[NN], s_nord[NN];
  __shared__ int s_doff[NN + 2];
  __shared__ int s_sc[NN], s_sc2[NN];
  __shared__ int s_wsum[17];
  __shared__ int s_maxd;
  const int tid = threadIdx.x;

  if (tid == 0) s_maxd = 0;
  for (int i = tid; i < GBLK + 64; i += 1024) flags[i] = 0;   // reset barrier epochs
  for (int i = tid; i < NOUT; i += 1024)                       // combined bias
    biasC[i] = (i < 3072) ? (bioux[i] + biouh[i]) : (bfx[i - 3072] + bfh[i - 3072]);
  for (int t = tid; t < NN; t += 1024) {
    bool root = (t == NN - 1);
    s_anc[t] = root ? t : parent[t];
    s_dep[t] = root ? 0 : 1;
  }
  __syncthreads();
  for (int it = 0; it < 11; ++it) {     // 2^11 >= NN
    for (int t = tid; t < NN; t += 1024) { int a = s_anc[t]; s_t1[t] = s_dep[t] + s_dep[a]; s_t2[t] = s_anc[a]; }
    __syncthreads();
    for (int t = tid; t < NN; t += 1024) { s_dep[t] = s_t1[t]; s_anc[t] = s_t2[t]; }
    __syncthreads();
  }
  for (int t = tid; t < NN; t += 1024) atomicMax(&s_maxd, s_dep[t]);

  // ---- counting sort by parent -> s_ordp with offsets s_poff ----
  for (int i = tid; i < NN + 2; i += 1024) s_t2[i] = 0;
  __syncthreads();
  for (int t = tid; t < NN; t += 1024) atomicAdd(&s_t2[parent[t]], 1);
  __syncthreads();
  {
    const int L = NN + 2;
    int* src = s_t2; int* dst = s_t1;
    for (int o = 1; o < L; o <<= 1) {
      for (int i = tid; i < L; i += 1024) dst[i] = src[i] + ((i >= o) ? src[i - o] : 0);
      __syncthreads();
      int* tmp = src; src = dst; dst = tmp;
    }
    for (int i = tid; i < L; i += 1024) { int v = (i ? src[i - 1] : 0); s_poff[i] = v; s_cur[i] = v; }
    __syncthreads();
    for (int t = tid; t < NN; t += 1024) {
      int pos = atomicAdd(&s_cur[parent[t]], 1);
      s_ordp[pos] = t;
    }
    __syncthreads();
    for (int p = tid; p < NN + 1; p += 1024) {    // determinism within bucket
      int b = s_poff[p], e = s_poff[p + 1];
      for (int i = b + 1; i < e; ++i) {
        int v = s_ordp[i], j = i - 1;
        while (j >= b && s_ordp[j] > v) { s_ordp[j + 1] = s_ordp[j]; --j; }
        s_ordp[j + 1] = v;
      }
    }
    __syncthreads();
  }

  // ---- counts by depth -> s_doff ----
  for (int i = tid; i < NN + 2; i += 1024) s_t2[i] = 0;
  __syncthreads();
  for (int t = tid; t < NN; t += 1024) atomicAdd(&s_t2[s_dep[t]], 1);
  __syncthreads();
  {
    const int L = NN + 1;
    int* src = s_t2; int* dst = s_t1;
    for (int o = 1; o < L; o <<= 1) {
      for (int i = tid; i < L; i += 1024) dst[i] = src[i] + ((i >= o) ? src[i - o] : 0);
      __syncthreads();
      int* tmp = src; src = dst; dst = tmp;
    }
    for (int i = tid; i < L + 1; i += 1024) s_doff[i] = (i ? src[i - 1] : 0);
    __syncthreads();
  }

  // ---- BFS: parent-grouped order per level; child indices level-relative ----
  const int maxd = s_maxd;
  if (tid == 0) s_nord[0] = NN - 1;     // root at position 0
  __syncthreads();
  for (int d = 0; d < maxd; ++d) {
    const int lbeg = s_doff[d], lend = s_doff[d + 1];
    const int nd = lend - lbeg;
    if (nd <= 1024) {
      int t = -1, v = 0;
      if (tid < nd) { t = s_nord[lbeg + tid]; v = s_poff[t + 1] - s_poff[t]; }
      #pragma unroll
      for (int o = 1; o < 64; o <<= 1) {
        int u = __shfl_up(v, (unsigned)o, 64);
        if ((tid & 63) >= o) v += u;
      }
      if ((tid & 63) == 63) s_wsum[tid >> 6] = v;
      __syncthreads();
      if (tid < 16) {
        int w = s_wsum[tid];
        #pragma unroll
        for (int o = 1; o < 16; o <<= 1) {
          int u = __shfl_up(w, (unsigned)o, 16);
          if (tid >= o) w += u;
        }
        s_wsum[tid] = w;
      }
      __syncthreads();
      if (tid < nd) {
        int incl = v + ((tid >> 6) ? s_wsum[(tid >> 6) - 1] : 0);
        int cnti = s_poff[t + 1] - s_poff[t];
        int crel = incl - cnti;                    // relative to level d+1 start
        meta[lbeg + tid] = make_int2(t, (crel << 16) | cnti);
        for (int j = 0; j < cnti; ++j) s_nord[lend + crel + j] = s_ordp[s_poff[t] + j];
      }
      __syncthreads();
    } else {                             // fallback (pathological trees)
      for (int i = tid; i < nd; i += 1024) { int t2 = s_nord[lbeg + i]; s_sc[i] = s_poff[t2 + 1] - s_poff[t2]; }
      __syncthreads();
      for (int o = 1; o < nd; o <<= 1) {
        for (int i = tid; i < nd; i += 1024) s_sc2[i] = s_sc[i] + ((i >= o) ? s_sc[i - o] : 0);
        __syncthreads();
        for (int i = tid; i < nd; i += 1024) s_sc[i] = s_sc2[i];
        __syncthreads();
      }
      for (int i = tid; i < nd; i += 1024) {
        int t2 = s_nord[lbeg + i];
        int cnti = s_poff[t2 + 1] - s_poff[t2];
        int crel = s_sc[i] - cnti;
        meta[lbeg + i] = make_int2(t2, (crel << 16) | cnti);
        for (int j = 0; j < cnti; ++j) s_nord[lend + crel + j] = s_ordp[s_poff[t2] + j];
      }
      __syncthreads();
    }
  }
  {                                      // deepest level: all leaves
    const int lbeg = s_doff[maxd], lend = s_doff[maxd + 1];
    for (int i = lbeg + tid; i < lend; i += 1024)
      meta[i] = make_int2(s_nord[i], 0);
  }
  for (int i = tid; i <= maxd + 1; i += 1024) doff_g[i] = s_doff[i];
  if (tid == 0) *maxd_out = maxd;
}

// ---------------- pre-GEMM: XWb[strip][node][16] bf16 = X @ [Wioux;Wfx]^T + biasC ----------------
// XCD-aware tile map: each XCD owns a contiguous 8-wide tn strip (B panel L2-resident).
__global__ __launch_bounds__(256) void pregemm_kernel(const unsigned short* __restrict__ Xb,
                                                      const unsigned short* __restrict__ Wb,
                                                      unsigned short* __restrict__ XWb,
                                                      const float* __restrict__ biasC) {
  __shared__ alignas(16) unsigned short ldsA[64 * 40];
  __shared__ alignas(16) unsigned short ldsB[64 * 40];
  const int xcd = blockIdx.x & 7;
  const int w = blockIdx.x >> 3;          // 0..255
  const int tn = xcd * 8 + (w & 7);       // 0..63
  const int tm = w >> 3;                  // 0..31
  const int m0 = tm * 64, n0 = tn * 64;
  const int tid = threadIdx.x;
  const int lane = tid & 63;
  const int wave = tid >> 6;
  const int wr = wave >> 1, wc = wave & 1;
  f4 acc[2][2] = {};
  const int sr = tid >> 2;
  const int sc = (tid & 3) << 3;
  const unsigned short* agp = Xb + (size_t)(m0 + sr) * MD + sc;
  const unsigned short* bgp = Wb + (size_t)(n0 + sr) * MD + sc;
  const int lr = lane & 15;
  const int kq = (lane >> 4) << 3;

  for (int k0 = 0; k0 < MD; k0 += 32) {
    uint4 av = *(const uint4*)(agp + k0);
    uint4 bv = *(const uint4*)(bgp + k0);
    __syncthreads();
    *(uint4*)&ldsA[sr * 40 + sc] = av;
    *(uint4*)&ldsB[sr * 40 + sc] = bv;
    __syncthreads();
    short8 a0 = *(const short8*)&ldsA[(wr * 32 + lr) * 40 + kq];
    short8 a1 = *(const short8*)&ldsA[(wr * 32 + 16 + lr) * 40 + kq];
    short8 b0 = *(const short8*)&ldsB[(wc * 32 + lr) * 40 + kq];
    short8 b1 = *(const short8*)&ldsB[(wc * 32 + 16 + lr) * 40 + kq];
    acc[0][0] = __builtin_amdgcn_mfma_f32_16x16x32_bf16(a0, b0, acc[0][0], 0, 0, 0);
    acc[0][1] = __builtin_amdgcn_mfma_f32_16x16x32_bf16(a0, b1, acc[0][1], 0, 0, 0);
    acc[1][0] = __builtin_amdgcn_mfma_f32_16x16x32_bf16(a1, b0, acc[1][0], 0, 0, 0);
    acc[1][1] = __builtin_amdgcn_mfma_f32_16x16x32_bf16(a1, b1, acc[1][1], 0, 0, 0);
  }
  // C/D layout: col = lane&15, row = (lane>>4)*4 + q  -> scatter into XWb bf16
  for (int r = 0; r < 2; ++r)
    for (int c = 0; c < 2; ++c)
      for (int q = 0; q < 4; ++q) {
        const int row = m0 + wr * 32 + r * 16 + (lane >> 4) * 4 + q;   // node
        const int col = n0 + wc * 32 + c * 16 + lr;                    // 0..4095
        const float v = acc[r][c][q] + biasC[col];
        const int g = col >> 10, cj = col & 1023;
        XWb[((size_t)(cj >> 2) * NN + row) * 16 + (g << 2) + (cj & 3)] = f2bf(v);
      }
}

// ---------------- cooperative recurrence ----------------
struct RP {
  const int2* meta;           // [NN] (node, (crel<<16)|cnt)
  const int* doff;            // [NN+2]
  const int* maxd;
  const unsigned short* XWb;  // [256 strips][NN][16] bf16 x-side preactivation (+ biases)
  unsigned short* G2;         // [GBLK][NN][16] bf16 spill (level width > CAP only)
  float* CbB;                 // [GBLK][NN][4]  fp32 spill
  unsigned short* Hb;         // [NN][1024] bf16 h (only cross-block data; LLC-coherent)
  const float* Wiouh;         // [3072][1024] fp32 (converted during LDS staging)
  const float* Wfh;           // [1024][1024] fp32
  float* out;                 // [2048]: c_root | h_root
  int* flags;                 // [GBLK] arrival flags + epoch word
};

// Hierarchical fence-free grid barrier: blocks write flag[bid]; block 0 polls all
// 256 flags and publishes a single epoch word; others poll 4B. No L2 flush.
__device__ __forceinline__ void grid_barrier(int* flags, int step) {
  asm volatile("s_waitcnt vmcnt(0)" ::: "memory");   // this wave's stores acked at LLC
  __syncthreads();                                   // all waves drained
  int* epoch = flags + GBLK;
  if (blockIdx.x == 0) {
    if (threadIdx.x < 64) {
      if (threadIdx.x == 0)
        __hip_atomic_store(&flags[0], step, __ATOMIC_RELAXED, __HIP_MEMORY_SCOPE_AGENT);
      const int base = threadIdx.x << 2;
      for (;;) {
        int a = __hip_atomic_load(&flags[base + 0], __ATOMIC_RELAXED, __HIP_MEMORY_SCOPE_AGENT);
        int b = __hip_atomic_load(&flags[base + 1], __ATOMIC_RELAXED, __HIP_MEMORY_SCOPE_AGENT);
        int c = __hip_atomic_load(&flags[base + 2], __ATOMIC_RELAXED, __HIP_MEMORY_SCOPE_AGENT);
        int d = __hip_atomic_load(&flags[base + 3], __ATOMIC_RELAXED, __HIP_MEMORY_SCOPE_AGENT);
        if (__all(a >= step && b >= step && c >= step && d >= step)) break;
        __builtin_amdgcn_s_sleep(1);
      }
      if (threadIdx.x == 0)
        __hip_atomic_store(epoch, step, __ATOMIC_RELAXED, __HIP_MEMORY_SCOPE_AGENT);
    }
  } else if (threadIdx.x == 0) {
    __hip_atomic_store(&flags[blockIdx.x], step, __ATOMIC_RELAXED, __HIP_MEMORY_SCOPE_AGENT);
    while (__hip_atomic_load(epoch, __ATOMIC_RELAXED, __HIP_MEMORY_SCOPE_AGENT) < step)
      __builtin_amdgcn_s_sleep(1);
  }
  __syncthreads();
  asm volatile("" ::: "memory");
}

// one K=32 slice: b-frag from LDS, MFMA into alternating acc, prefetch A 8 ahead.
// A is a NAMED register (never an indexed array -> never scratch).
#define GSTEP(A, KB)                                                                     \
  {                                                                                      \
    short8 bfrag = *(const short8*)(wb0 + ((((KB << 2) + kq) ^ swz) << 3));              \
    if ((KB) & 1) ao = __builtin_amdgcn_mfma_f32_16x16x32_bf16(A, bfrag, ao, 0, 0, 0);   \
    else          ae = __builtin_amdgcn_mfma_f32_16x16x32_bf16(A, bfrag, ae, 0, 0, 0);   \
    if ((KB) + 8 < 32) A = *(const short8*)(ap + (((KB) + 8) << 5));                     \
  }

__global__ __launch_bounds__(GTHR, 1) void recur_kernel(RP p) {
  __shared__ alignas(16) unsigned short ldsW[16 * MD];   // 32 KiB W strip, swizzled
  __shared__ alignas(16) unsigned short G2L[CAP * 16];   // 32 KiB level-local G (bf16)
  __shared__ alignas(16) float CbL[2 * CAP * 4];         // 32 KiB level-local c (ping-pong)
  __shared__ int2 ldsMeta[NN];                           // 16 KiB
  __shared__ int ldsDoff[NN + 2];                        // 8 KiB
  const int tid = threadIdx.x;
  const int bid = blockIdx.x;
  const int lane = tid & 63;
  const int wave = tid >> 6;
  // XCD-swizzled strip: one XCD's 32 blocks cover a contiguous 128-col window
  const int strip = (bid & 7) * 32 + (bid >> 3);
  const int s4 = strip << 2;             // this block's 4 columns

  // Stage W strip from fp32, converting: LDS row j (0..15) = W row (j>>2)*1024 + s4 + (j&3).
  for (int idx = tid; idx < 16 * 128; idx += GTHR) {
    int j = idx >> 7, kc = idx & 127;
    int g = j >> 2, col = s4 + (j & 3);
    const float* src = (g < 3) ? (p.Wiouh + (size_t)(g * MD + col) * MD)
                               : (p.Wfh + (size_t)col * MD);
    f4 lo = *(const f4*)(src + (kc << 3));
    f4 hi = *(const f4*)(src + (kc << 3) + 4);
    *(uint4*)(ldsW + j * MD + ((kc ^ (j & 7)) << 3)) = pack8(lo, hi);
  }
  const int maxd = *p.maxd;
  for (int i = tid; i < NN; i += GTHR) ldsMeta[i] = p.meta[i];
  for (int i = tid; i <= maxd + 1; i += GTHR) ldsDoff[i] = p.doff[i];
  __syncthreads();

  const unsigned short* xwb = p.XWb + (size_t)strip * NN * 16;
  unsigned short* G2g = p.G2 + (size_t)bid * NN * 16;    // spill only
  float* CbBg = p.CbB + (size_t)bid * NN * 4;            // spill only
  const int chalf = tid & 1;             // which half of the children this thread sums

  for (int d = maxd; d >= 0; --d) {
    const int lbeg = ldsDoff[d], lend = ldsDoff[d + 1];
    const int nd = lend - lbeg;
    float* cbw = CbL + (size_t)(d & 1) * CAP * 4;        // this level's c
    const float* cbr = CbL + (size_t)((d + 1) & 1) * CAP * 4;  // child level's c

    // ---- cell: 2 threads/node (child-halves), 4 cols each; shfl_xor(1) reduce ----
    for (int ii = tid >> 1; ii < nd; ii += GTHR / 2) {
      const int2 mt = ldsMeta[lbeg + ii];
      const int t = mt.x, crel = mt.y >> 16, cnt = mt.y & 0xffff;
      const unsigned short* xwp = xwb + (size_t)t * 16;
      uint4 xa = *(const uint4*)xwp;         // i0..3, o0..3
      uint4 xb = *(const uint4*)(xwp + 8);   // u0..3, f0..3
      f4 gf; gf[0] = blo(xb.z); gf[1] = bhi(xb.z); gf[2] = blo(xb.w); gf[3] = bhi(xb.w);
      f4 gi = {0.f, 0.f, 0.f, 0.f}, go = gi, gu = gi, fc = gi;
      if (chalf == 0) {
        gi[0] = blo(xa.x); gi[1] = bhi(xa.x); gi[2] = blo(xa.y); gi[3] = bhi(xa.y);
        go[0] = blo(xa.z); go[1] = bhi(xa.z); go[2] = blo(xa.w); go[3] = bhi(xa.w);
        gu[0] = blo(xb.x); gu[1] = bhi(xb.x); gu[2] = blo(xb.y); gu[3] = bhi(xb.y);
      }
      for (int k = chalf; k < cnt; k += 2) {
        const int ci = crel + k;
        uint4 ga, gb; f4 cu;
        if (ci < CAP) {                       // LDS-resident child (normal path)
          ga = *(const uint4*)(G2L + ci * 16);
          gb = *(const uint4*)(G2L + ci * 16 + 8);
          cu = *(const f4*)(cbr + ci * 4);
        } else {                              // spill (level wider than CAP)
          const unsigned short* g2 = G2g + (size_t)(lend + ci) * 16;
          ga = *(const uint4*)(g2);
          gb = *(const uint4*)(g2 + 8);
          cu = *(const f4*)(CbBg + (size_t)(lend + ci) * 4);
        }
        gi[0] += blo(ga.x); gi[1] += bhi(ga.x); gi[2] += blo(ga.y); gi[3] += bhi(ga.y);
        go[0] += blo(ga.z); go[1] += bhi(ga.z); go[2] += blo(ga.w); go[3] += bhi(ga.w);
        gu[0] += blo(gb.x); gu[1] += bhi(gb.x); gu[2] += blo(gb.y); gu[3] += bhi(gb.y);
        f4 gff; gff[0] = blo(gb.z); gff[1] = bhi(gb.z); gff[2] = blo(gb.w); gff[3] = bhi(gb.w);
        #pragma unroll
        for (int q = 0; q < 4; ++q) fc[q] += sigm(gff[q] + gf[q]) * cu[q];
      }
      #pragma unroll
      for (int q = 0; q < 4; ++q) {          // pairwise reduce the two child-halves
        gi[q] += __shfl_xor(gi[q], 1);
        go[q] += __shfl_xor(go[q], 1);
        gu[q] += __shfl_xor(gu[q], 1);
        fc[q] += __shfl_xor(fc[q], 1);
      }
      if (chalf == 0) {
        f4 cv, hv;
        #pragma unroll
        for (int q = 0; q < 4; ++q) {
          float c0 = sigm(gi[q]) * tanh_(gu[q]) + fc[q];
          cv[q] = c0;
          hv[q] = sigm(go[q]) * tanh_(c0);
        }
        if (ii < CAP) *(f4*)(cbw + ii * 4) = cv;
        else          *(f4*)(CbBg + (size_t)(lbeg + ii) * 4) = cv;
        unsigned long long hp =
            (unsigned long long)f2bf(hv[0]) |
            ((unsigned long long)f2bf(hv[1]) << 16) |
            ((unsigned long long)f2bf(hv[2]) << 32) |
            ((unsigned long long)f2bf(hv[3]) << 48);
        __hip_atomic_store((unsigned long long*)(p.Hb + (size_t)t * MD + s4),
                           hp, __ATOMIC_RELAXED, __HIP_MEMORY_SCOPE_AGENT);
        if (t == NN - 1) {                   // root: output (c | h) fp32
          *(f4*)(p.out + s4) = cv;
          *(f4*)(p.out + MD + s4) = hv;
        }
      }
    }
    if (d == 0) break;

    // ---- grid barrier: h of level d now visible at LLC (also block-syncs) ----
    grid_barrier(p.flags, maxd - d + 1);

    // ---- prefetch next level's XWb lines into L2 (hides LLC latency for the cell) ----
    if (d > 0) {
      const int lbeg2 = ldsDoff[d - 1];
      const int nd2 = lbeg - lbeg2;
      for (int q2 = tid; q2 < nd2; q2 += GTHR) {
        unsigned v = *(const unsigned*)(xwb + (size_t)ldsMeta[lbeg2 + q2].x * 16);
        asm volatile("" :: "v"(v));      // keep-alive (no DCE)
      }
    }

    // ---- gemm: G2L[rr][0..15] = h[node(rr)] @ Wstrip^T (16 G-cols) ----
    // 8-deep NAMED-register A pipeline (no indexed array -> no scratch).
    {
      const int ntr = (nd + 15) >> 4;
      const int lr = lane & 15;
      const int kq = lane >> 4;
      const int swz = lr & 7;
      const unsigned short* wb0 = ldsW + lr * MD;
      for (int rt = wave; rt < ntr; rt += GTHR / 64) {
        const int r = (rt << 4) + lr;
        const int pos = lbeg + ((r < nd) ? r : 0);
        const int node = ldsMeta[pos].x;
        const unsigned short* ap = p.Hb + (size_t)node * MD + (kq << 3);
        short8 A0 = *(const short8*)(ap);
        short8 A1 = *(const short8*)(ap + 32);
        short8 A2 = *(const short8*)(ap + 64);
        short8 A3 = *(const short8*)(ap + 96);
        short8 A4 = *(const short8*)(ap + 128);
        short8 A5 = *(const short8*)(ap + 160);
        short8 A6 = *(const short8*)(ap + 192);
        short8 A7 = *(const short8*)(ap + 224);
        f4 ae = {0.f, 0.f, 0.f, 0.f}, ao = {0.f, 0.f, 0.f, 0.f};
        GSTEP(A0, 0)  GSTEP(A1, 1)  GSTEP(A2, 2)  GSTEP(A3, 3)
        GSTEP(A4, 4)  GSTEP(A5, 5)  GSTEP(A6, 6)  GSTEP(A7, 7)
        GSTEP(A0, 8)  GSTEP(A1, 9)  GSTEP(A2, 10) GSTEP(A3, 11)
        GSTEP(A4, 12) GSTEP(A5, 13) GSTEP(A6, 14) GSTEP(A7, 15)
        GSTEP(A0, 16) GSTEP(A1, 17) GSTEP(A2, 18) GSTEP(A3, 19)
        GSTEP(A4, 20) GSTEP(A5, 21) GSTEP(A6, 22) GSTEP(A7, 23)
        GSTEP(A0, 24) GSTEP(A1, 25) GSTEP(A2, 26) GSTEP(A3, 27)
        GSTEP(A4, 28) GSTEP(A5, 29) GSTEP(A6, 30) GSTEP(A7, 31)
        const int rb = (rt << 4) + (kq << 2);
        #pragma unroll
        for (int q = 0; q < 4; ++q) {        // C/D: col = lane&15, row = kq*4+q
          const int rr = rb + q;
          if (rr < nd) {
            unsigned short v = f2bf(ae[q] + ao[q]);
            if (rr < CAP) G2L[rr * 16 + lr] = v;
            else          G2g[(size_t)(lbeg + rr) * 16 + lr] = v;
          }
        }
      }
    }
    __syncthreads();   // G2L/CbL handoff to next cell
  }
}

// ---------------- launch ----------------
extern "C" void kernel_launch(void* const* d_in, const int* in_sizes, int n_in,
                              void* d_out, int out_size, void* d_ws, size_t ws_size,
                              hipStream_t stream) {
  const float* X     = (const float*)d_in[0];
  const int*   parent= (const int*)d_in[1];
  const float* Wioux = (const float*)d_in[2];
  const float* bioux = (const float*)d_in[3];
  const float* Wiouh = (const float*)d_in[4];
  const float* biouh = (const float*)d_in[5];
  const float* Wfx   = (const float*)d_in[6];
  const float* bfx   = (const float*)d_in[7];
  const float* Wfh   = (const float*)d_in[8];
  const float* bfh   = (const float*)d_in[9];
  float* out = (float*)d_out;

  char* ws = (char*)d_ws;
  size_t o = 0;
  auto alloc = [&](size_t bytes) { size_t r = o; o += (bytes + 255) & ~(size_t)255; return r; };
  unsigned short* Xb   = (unsigned short*)(ws + alloc((size_t)NN * MD * 2));
  unsigned short* Wpre = (unsigned short*)(ws + alloc((size_t)NOUT * MD * 2));
  unsigned short* XWb  = (unsigned short*)(ws + alloc((size_t)GBLK * NN * 16 * 2));
  unsigned short* G2   = (unsigned short*)(ws + alloc((size_t)GBLK * NN * 16 * 2));
  float* CbB           = (float*)(ws + alloc((size_t)GBLK * NN * 4 * 4));
  unsigned short* Hb   = (unsigned short*)(ws + alloc((size_t)NN * MD * 2));
  float* biasC         = (float*)(ws + alloc((size_t)NOUT * 4));
  int2* meta           = (int2*)(ws + alloc((size_t)NN * 8));
  int* doff            = (int*)(ws + alloc((NN + 4) * 4));
  int* maxd            = (int*)(ws + alloc(256));
  int* flags           = (int*)(ws + alloc((GBLK + 64) * 4));

  {
    int n4;
    n4 = NN * MD / 4;
    cvt_bf16_kernel<<<(n4 + 255) / 256, 256, 0, stream>>>(X, Xb, n4);
    n4 = 3072 * MD / 4;
    cvt_bf16_kernel<<<(n4 + 255) / 256, 256, 0, stream>>>(Wioux, Wpre, n4);
    n4 = 1024 * MD / 4;
    cvt_bf16_kernel<<<(n4 + 255) / 256, 256, 0, stream>>>(Wfx, Wpre + (size_t)3072 * MD, n4);
  }

  prep_kernel<<<1, 1024, 0, stream>>>(parent, meta, doff, maxd, flags,
                                      bioux, biouh, bfx, bfh, biasC);

  pregemm_kernel<<<(NN / 64) * (NOUT / 64), 256, 0, stream>>>(Xb, Wpre, XWb, biasC);

  RP p;
  p.meta = meta; p.doff = doff; p.maxd = maxd;
  p.XWb = XWb; p.G2 = G2; p.CbB = CbB; p.Hb = Hb;
  p.Wiouh = Wiouh; p.Wfh = Wfh;
  p.out = out; p.flags = flags;
  void* args[] = {&p};
  hipLaunchCooperativeKernel((const void*)recur_kernel, dim3(GBLK), dim3(GTHR), args, 0, stream);

  (void)in_sizes; (void)n_in; (void)out_size; (void)ws_size;
}

// Round 9
// 352.459 us; speedup vs baseline: 5.5387x; 1.3379x over previous
//
#include <hip/hip_runtime.h>

#define NN 2048          // nodes
#define MD 1024          // mem/input dim
#define NOUT 4096        // 3M (iou) + M (f) output columns
#define GBLK 256         // cooperative grid blocks: one 4-col strip each
#define GTHR 512         // threads per block (8 waves) -> VGPR budget 256, no spill
#define CAP 1024         // max level width held in LDS (spill to global beyond)

typedef __attribute__((ext_vector_type(8))) short short8;   // 8 x bf16 fragment
typedef __attribute__((ext_vector_type(4))) float f4;

__device__ __forceinline__ unsigned short f2bf(float f) {
  unsigned u = __float_as_uint(f);
  u += 0x7fffu + ((u >> 16) & 1u);      // RNE
  return (unsigned short)(u >> 16);
}
__device__ __forceinline__ uint4 pack8(f4 a, f4 b) {
  uint4 r;
  r.x = f2bf(a[0]) | ((unsigned)f2bf(a[1]) << 16);
  r.y = f2bf(a[2]) | ((unsigned)f2bf(a[3]) << 16);
  r.z = f2bf(b[0]) | ((unsigned)f2bf(b[1]) << 16);
  r.w = f2bf(b[2]) | ((unsigned)f2bf(b[3]) << 16);
  return r;
}
__device__ __forceinline__ float blo(unsigned u) { return __uint_as_float(u << 16); }
__device__ __forceinline__ float bhi(unsigned u) { return __uint_as_float(u & 0xffff0000u); }
__device__ __forceinline__ float sigm(float x) { return 1.0f / (1.0f + __expf(-x)); }
__device__ __forceinline__ float tanh_(float x) { return 1.0f - 2.0f / (1.0f + __expf(2.0f * x)); }

// ---------------- fp32 -> bf16 conversion (vector x4) ----------------
__global__ __launch_bounds__(256) void cvt_bf16_kernel(const float* __restrict__ s,
                                                       unsigned short* __restrict__ d, int n4) {
  int i = blockIdx.x * 256 + threadIdx.x;
  if (i < n4) {
    f4 v = *((const f4*)s + i);
    unsigned lo = f2bf(v[0]) | ((unsigned)f2bf(v[1]) << 16);
    unsigned hi = f2bf(v[2]) | ((unsigned)f2bf(v[3]) << 16);
    uint2 r; r.x = lo; r.y = hi;
    *((uint2*)d + i) = r;
  }
}

// ---------------- prep: depth, parent-sort, BFS order, biasC, flag reset ----------------
// meta[pos] = (node, (crel<<16)|cnt) with crel = child start RELATIVE to child level.
__global__ __launch_bounds__(1024) void prep_kernel(const int* __restrict__ parent,
                                                    int2* __restrict__ meta,
                                                    int* __restrict__ doff_g,
                                                    int* __restrict__ maxd_out,
                                                    int* __restrict__ flags,
                                                    const float* __restrict__ bioux,
                                                    const float* __restrict__ biouh,
                                                    const float* __restrict__ bfx,
                                                    const float* __restrict__ bfh,
                                                    float* __restrict__ biasC) {
  __shared__ int s_anc[NN], s_dep[NN];
  __shared__ int s_t1[NN + 2], s_t2[NN + 2];
  __shared__ int s_poff[NN + 2], s_cur[NN + 2];
  __shared__ int s_ordp[NN], s_nord[NN];
  __shared__ int s_doff[NN + 2];
  __shared__ int s_sc[NN], s_sc2[NN];
  __shared__ int s_wsum[17];
  __shared__ int s_maxd;
  const int tid = threadIdx.x;

  if (tid == 0) s_maxd = 0;
  for (int i = tid; i < GBLK + 64; i += 1024) flags[i] = 0;   // reset barrier epochs
  for (int i = tid; i < NOUT; i += 1024)                       // combined bias
    biasC[i] = (i < 3072) ? (bioux[i] + biouh[i]) : (bfx[i - 3072] + bfh[i - 3072]);
  for (int t = tid; t < NN; t += 1024) {
    bool root = (t == NN - 1);
    s_anc[t] = root ? t : parent[t];
    s_dep[t] = root ? 0 : 1;
  }
  __syncthreads();
  for (int it = 0; it < 11; ++it) {     // 2^11 >= NN
    for (int t = tid; t < NN; t += 1024) { int a = s_anc[t]; s_t1[t] = s_dep[t] + s_dep[a]; s_t2[t] = s_anc[a]; }
    __syncthreads();
    for (int t = tid; t < NN; t += 1024) { s_dep[t] = s_t1[t]; s_anc[t] = s_t2[t]; }
    __syncthreads();
  }
  for (int t = tid; t < NN; t += 1024) atomicMax(&s_maxd, s_dep[t]);

  // ---- counting sort by parent -> s_ordp with offsets s_poff ----
  for (int i = tid; i < NN + 2; i += 1024) s_t2[i] = 0;
  __syncthreads();
  for (int t = tid; t < NN; t += 1024) atomicAdd(&s_t2[parent[t]], 1);
  __syncthreads();
  {
    const int L = NN + 2;
    int* src = s_t2; int* dst = s_t1;
    for (int o = 1; o < L; o <<= 1) {
      for (int i = tid; i < L; i += 1024) dst[i] = src[i] + ((i >= o) ? src[i - o] : 0);
      __syncthreads();
      int* tmp = src; src = dst; dst = tmp;
    }
    for (int i = tid; i < L; i += 1024) { int v = (i ? src[i - 1] : 0); s_poff[i] = v; s_cur[i] = v; }
    __syncthreads();
    for (int t = tid; t < NN; t += 1024) {
      int pos = atomicAdd(&s_cur[parent[t]], 1);
      s_ordp[pos] = t;
    }
    __syncthreads();
    for (int p = tid; p < NN + 1; p += 1024) {    // determinism within bucket
      int b = s_poff[p], e = s_poff[p + 1];
      for (int i = b + 1; i < e; ++i) {
        int v = s_ordp[i], j = i - 1;
        while (j >= b && s_ordp[j] > v) { s_ordp[j + 1] = s_ordp[j]; --j; }
        s_ordp[j + 1] = v;
      }
    }
    __syncthreads();
  }

  // ---- counts by depth -> s_doff ----
  for (int i = tid; i < NN + 2; i += 1024) s_t2[i] = 0;
  __syncthreads();
  for (int t = tid; t < NN; t += 1024) atomicAdd(&s_t2[s_dep[t]], 1);
  __syncthreads();
  {
    const int L = NN + 1;
    int* src = s_t2; int* dst = s_t1;
    for (int o = 1; o < L; o <<= 1) {
      for (int i = tid; i < L; i += 1024) dst[i] = src[i] + ((i >= o) ? src[i - o] : 0);
      __syncthreads();
      int* tmp = src; src = dst; dst = tmp;
    }
    for (int i = tid; i < L + 1; i += 1024) s_doff[i] = (i ? src[i - 1] : 0);
    __syncthreads();
  }

  // ---- BFS: parent-grouped order per level; child indices level-relative ----
  const int maxd = s_maxd;
  if (tid == 0) s_nord[0] = NN - 1;     // root at position 0
  __syncthreads();
  for (int d = 0; d < maxd; ++d) {
    const int lbeg = s_doff[d], lend = s_doff[d + 1];
    const int nd = lend - lbeg;
    if (nd <= 1024) {
      int t = -1, v = 0;
      if (tid < nd) { t = s_nord[lbeg + tid]; v = s_poff[t + 1] - s_poff[t]; }
      #pragma unroll
      for (int o = 1; o < 64; o <<= 1) {
        int u = __shfl_up(v, (unsigned)o, 64);
        if ((tid & 63) >= o) v += u;
      }
      if ((tid & 63) == 63) s_wsum[tid >> 6] = v;
      __syncthreads();
      if (tid < 16) {
        int w = s_wsum[tid];
        #pragma unroll
        for (int o = 1; o < 16; o <<= 1) {
          int u = __shfl_up(w, (unsigned)o, 16);
          if (tid >= o) w += u;
        }
        s_wsum[tid] = w;
      }
      __syncthreads();
      if (tid < nd) {
        int incl = v + ((tid >> 6) ? s_wsum[(tid >> 6) - 1] : 0);
        int cnti = s_poff[t + 1] - s_poff[t];
        int crel = incl - cnti;                    // relative to level d+1 start
        meta[lbeg + tid] = make_int2(t, (crel << 16) | cnti);
        for (int j = 0; j < cnti; ++j) s_nord[lend + crel + j] = s_ordp[s_poff[t] + j];
      }
      __syncthreads();
    } else {                             // fallback (pathological trees)
      for (int i = tid; i < nd; i += 1024) { int t2 = s_nord[lbeg + i]; s_sc[i] = s_poff[t2 + 1] - s_poff[t2]; }
      __syncthreads();
      for (int o = 1; o < nd; o <<= 1) {
        for (int i = tid; i < nd; i += 1024) s_sc2[i] = s_sc[i] + ((i >= o) ? s_sc[i - o] : 0);
        __syncthreads();
        for (int i = tid; i < nd; i += 1024) s_sc[i] = s_sc2[i];
        __syncthreads();
      }
      for (int i = tid; i < nd; i += 1024) {
        int t2 = s_nord[lbeg + i];
        int cnti = s_poff[t2 + 1] - s_poff[t2];
        int crel = s_sc[i] - cnti;
        meta[lbeg + i] = make_int2(t2, (crel << 16) | cnti);
        for (int j = 0; j < cnti; ++j) s_nord[lend + crel + j] = s_ordp[s_poff[t2] + j];
      }
      __syncthreads();
    }
  }
  {                                      // deepest level: all leaves
    const int lbeg = s_doff[maxd], lend = s_doff[maxd + 1];
    for (int i = lbeg + tid; i < lend; i += 1024)
      meta[i] = make_int2(s_nord[i], 0);
  }
  for (int i = tid; i <= maxd + 1; i += 1024) doff_g[i] = s_doff[i];
  if (tid == 0) *maxd_out = maxd;
}

// ---------------- pre-GEMM: XWb[strip][node][16] bf16 = X @ [Wioux;Wfx]^T + biasC ----------------
// XCD-aware tile map: each XCD owns a contiguous 8-wide tn strip (B panel L2-resident).
__global__ __launch_bounds__(256) void pregemm_kernel(const unsigned short* __restrict__ Xb,
                                                      const unsigned short* __restrict__ Wb,
                                                      unsigned short* __restrict__ XWb,
                                                      const float* __restrict__ biasC) {
  __shared__ alignas(16) unsigned short ldsA[64 * 40];
  __shared__ alignas(16) unsigned short ldsB[64 * 40];
  const int xcd = blockIdx.x & 7;
  const int w = blockIdx.x >> 3;          // 0..255
  const int tn = xcd * 8 + (w & 7);       // 0..63
  const int tm = w >> 3;                  // 0..31
  const int m0 = tm * 64, n0 = tn * 64;
  const int tid = threadIdx.x;
  const int lane = tid & 63;
  const int wave = tid >> 6;
  const int wr = wave >> 1, wc = wave & 1;
  f4 acc[2][2] = {};
  const int sr = tid >> 2;
  const int sc = (tid & 3) << 3;
  const unsigned short* agp = Xb + (size_t)(m0 + sr) * MD + sc;
  const unsigned short* bgp = Wb + (size_t)(n0 + sr) * MD + sc;
  const int lr = lane & 15;
  const int kq = (lane >> 4) << 3;

  for (int k0 = 0; k0 < MD; k0 += 32) {
    uint4 av = *(const uint4*)(agp + k0);
    uint4 bv = *(const uint4*)(bgp + k0);
    __syncthreads();
    *(uint4*)&ldsA[sr * 40 + sc] = av;
    *(uint4*)&ldsB[sr * 40 + sc] = bv;
    __syncthreads();
    short8 a0 = *(const short8*)&ldsA[(wr * 32 + lr) * 40 + kq];
    short8 a1 = *(const short8*)&ldsA[(wr * 32 + 16 + lr) * 40 + kq];
    short8 b0 = *(const short8*)&ldsB[(wc * 32 + lr) * 40 + kq];
    short8 b1 = *(const short8*)&ldsB[(wc * 32 + 16 + lr) * 40 + kq];
    acc[0][0] = __builtin_amdgcn_mfma_f32_16x16x32_bf16(a0, b0, acc[0][0], 0, 0, 0);
    acc[0][1] = __builtin_amdgcn_mfma_f32_16x16x32_bf16(a0, b1, acc[0][1], 0, 0, 0);
    acc[1][0] = __builtin_amdgcn_mfma_f32_16x16x32_bf16(a1, b0, acc[1][0], 0, 0, 0);
    acc[1][1] = __builtin_amdgcn_mfma_f32_16x16x32_bf16(a1, b1, acc[1][1], 0, 0, 0);
  }
  // C/D layout: col = lane&15, row = (lane>>4)*4 + q  -> scatter into XWb bf16
  for (int r = 0; r < 2; ++r)
    for (int c = 0; c < 2; ++c)
      for (int q = 0; q < 4; ++q) {
        const int row = m0 + wr * 32 + r * 16 + (lane >> 4) * 4 + q;   // node
        const int col = n0 + wc * 32 + c * 16 + lr;                    // 0..4095
        const float v = acc[r][c][q] + biasC[col];
        const int g = col >> 10, cj = col & 1023;
        XWb[((size_t)(cj >> 2) * NN + row) * 16 + (g << 2) + (cj & 3)] = f2bf(v);
      }
}

// ---------------- cooperative recurrence ----------------
struct RP {
  const int2* meta;           // [NN] (node, (crel<<16)|cnt)
  const int* doff;            // [NN+2]
  const int* maxd;
  const unsigned short* XWb;  // [256 strips][NN][16] bf16 x-side preactivation (+ biases)
  unsigned short* G2;         // [GBLK][NN][16] bf16 spill (level width > CAP only)
  float* CbB;                 // [GBLK][NN][4]  fp32 spill
  unsigned short* Hb;         // [NN][1024] bf16 h (only cross-block data; LLC-coherent)
  const float* Wiouh;         // [3072][1024] fp32 (converted during LDS staging)
  const float* Wfh;           // [1024][1024] fp32
  float* out;                 // [2048]: c_root | h_root
  int* flags;                 // [GBLK] arrival flags + epoch word
};

// Hierarchical fence-free grid barrier: blocks write flag[bid]; block 0 polls all
// 256 flags and publishes a single epoch word; others poll 4B. No L2 flush.
__device__ __forceinline__ void grid_barrier(int* flags, int step) {
  asm volatile("s_waitcnt vmcnt(0)" ::: "memory");   // this wave's stores acked at LLC
  __syncthreads();                                   // all waves drained
  int* epoch = flags + GBLK;
  if (blockIdx.x == 0) {
    if (threadIdx.x < 64) {
      if (threadIdx.x == 0)
        __hip_atomic_store(&flags[0], step, __ATOMIC_RELAXED, __HIP_MEMORY_SCOPE_AGENT);
      const int base = threadIdx.x << 2;
      for (;;) {
        int a = __hip_atomic_load(&flags[base + 0], __ATOMIC_RELAXED, __HIP_MEMORY_SCOPE_AGENT);
        int b = __hip_atomic_load(&flags[base + 1], __ATOMIC_RELAXED, __HIP_MEMORY_SCOPE_AGENT);
        int c = __hip_atomic_load(&flags[base + 2], __ATOMIC_RELAXED, __HIP_MEMORY_SCOPE_AGENT);
        int d = __hip_atomic_load(&flags[base + 3], __ATOMIC_RELAXED, __HIP_MEMORY_SCOPE_AGENT);
        if (__all(a >= step && b >= step && c >= step && d >= step)) break;
        __builtin_amdgcn_s_sleep(1);
      }
      if (threadIdx.x == 0)
        __hip_atomic_store(epoch, step, __ATOMIC_RELAXED, __HIP_MEMORY_SCOPE_AGENT);
    }
  } else if (threadIdx.x == 0) {
    __hip_atomic_store(&flags[blockIdx.x], step, __ATOMIC_RELAXED, __HIP_MEMORY_SCOPE_AGENT);
    while (__hip_atomic_load(epoch, __ATOMIC_RELAXED, __HIP_MEMORY_SCOPE_AGENT) < step)
      __builtin_amdgcn_s_sleep(1);
  }
  __syncthreads();
  asm volatile("" ::: "memory");
}

// one K=32 slice: b-frag from LDS, MFMA into alternating acc, prefetch A 8 ahead.
// A is a NAMED register (never an indexed array -> never scratch).
#define GSTEP(A, KB)                                                                     \
  {                                                                                      \
    short8 bfrag = *(const short8*)(wb0 + ((((KB << 2) + kq) ^ swz) << 3));              \
    if ((KB) & 1) ao = __builtin_amdgcn_mfma_f32_16x16x32_bf16(A, bfrag, ao, 0, 0, 0);   \
    else          ae = __builtin_amdgcn_mfma_f32_16x16x32_bf16(A, bfrag, ae, 0, 0, 0);   \
    if ((KB) + 8 < 32) A = *(const short8*)(ap + (((KB) + 8) << 5));                     \
  }

__global__ __launch_bounds__(GTHR) void recur_kernel(RP p) {
  __shared__ alignas(16) unsigned short ldsW[16 * MD];   // 32 KiB W strip, swizzled
  __shared__ alignas(16) unsigned short G2L[CAP * 16];   // 32 KiB level-local G (bf16)
  __shared__ alignas(16) float CbL[2 * CAP * 4];         // 32 KiB level-local c (ping-pong)
  __shared__ int2 ldsMeta[NN];                           // 16 KiB
  __shared__ int ldsDoff[NN + 2];                        // 8 KiB
  const int tid = threadIdx.x;
  const int bid = blockIdx.x;
  const int lane = tid & 63;
  const int wave = tid >> 6;
  // XCD-swizzled strip: one XCD's 32 blocks cover a contiguous 128-col window
  const int strip = (bid & 7) * 32 + (bid >> 3);
  const int s4 = strip << 2;             // this block's 4 columns

  // Stage W strip from fp32, converting: LDS row j (0..15) = W row (j>>2)*1024 + s4 + (j&3).
  for (int idx = tid; idx < 16 * 128; idx += GTHR) {
    int j = idx >> 7, kc = idx & 127;
    int g = j >> 2, col = s4 + (j & 3);
    const float* src = (g < 3) ? (p.Wiouh + (size_t)(g * MD + col) * MD)
                               : (p.Wfh + (size_t)col * MD);
    f4 lo = *(const f4*)(src + (kc << 3));
    f4 hi = *(const f4*)(src + (kc << 3) + 4);
    *(uint4*)(ldsW + j * MD + ((kc ^ (j & 7)) << 3)) = pack8(lo, hi);
  }
  const int maxd = *p.maxd;
  for (int i = tid; i < NN; i += GTHR) ldsMeta[i] = p.meta[i];
  for (int i = tid; i <= maxd + 1; i += GTHR) ldsDoff[i] = p.doff[i];
  __syncthreads();

  const unsigned short* xwb = p.XWb + (size_t)strip * NN * 16;
  unsigned short* G2g = p.G2 + (size_t)bid * NN * 16;    // spill only
  float* CbBg = p.CbB + (size_t)bid * NN * 4;            // spill only
  const int chalf = tid & 1;             // which half of the children this thread sums

  for (int d = maxd; d >= 0; --d) {
    const int lbeg = ldsDoff[d], lend = ldsDoff[d + 1];
    const int nd = lend - lbeg;
    float* cbw = CbL + (size_t)(d & 1) * CAP * 4;        // this level's c
    const float* cbr = CbL + (size_t)((d + 1) & 1) * CAP * 4;  // child level's c

    // ---- cell: 2 threads/node (child-halves), 4 cols each; shfl_xor(1) reduce ----
    for (int ii = tid >> 1; ii < nd; ii += GTHR / 2) {
      const int2 mt = ldsMeta[lbeg + ii];
      const int t = mt.x, crel = mt.y >> 16, cnt = mt.y & 0xffff;
      const unsigned short* xwp = xwb + (size_t)t * 16;
      uint4 xa = *(const uint4*)xwp;         // i0..3, o0..3
      uint4 xb = *(const uint4*)(xwp + 8);   // u0..3, f0..3
      f4 gf; gf[0] = blo(xb.z); gf[1] = bhi(xb.z); gf[2] = blo(xb.w); gf[3] = bhi(xb.w);
      f4 gi = {0.f, 0.f, 0.f, 0.f}, go = gi, gu = gi, fc = gi;
      if (chalf == 0) {
        gi[0] = blo(xa.x); gi[1] = bhi(xa.x); gi[2] = blo(xa.y); gi[3] = bhi(xa.y);
        go[0] = blo(xa.z); go[1] = bhi(xa.z); go[2] = blo(xa.w); go[3] = bhi(xa.w);
        gu[0] = blo(xb.x); gu[1] = bhi(xb.x); gu[2] = blo(xb.y); gu[3] = bhi(xb.y);
      }
      for (int k = chalf; k < cnt; k += 2) {
        const int ci = crel + k;
        uint4 ga, gb; f4 cu;
        if (ci < CAP) {                       // LDS-resident child (normal path)
          ga = *(const uint4*)(G2L + ci * 16);
          gb = *(const uint4*)(G2L + ci * 16 + 8);
          cu = *(const f4*)(cbr + ci * 4);
        } else {                              // spill (level wider than CAP)
          const unsigned short* g2 = G2g + (size_t)(lend + ci) * 16;
          ga = *(const uint4*)(g2);
          gb = *(const uint4*)(g2 + 8);
          cu = *(const f4*)(CbBg + (size_t)(lend + ci) * 4);
        }
        gi[0] += blo(ga.x); gi[1] += bhi(ga.x); gi[2] += blo(ga.y); gi[3] += bhi(ga.y);
        go[0] += blo(ga.z); go[1] += bhi(ga.z); go[2] += blo(ga.w); go[3] += bhi(ga.w);
        gu[0] += blo(gb.x); gu[1] += bhi(gb.x); gu[2] += blo(gb.y); gu[3] += bhi(gb.y);
        f4 gff; gff[0] = blo(gb.z); gff[1] = bhi(gb.z); gff[2] = blo(gb.w); gff[3] = bhi(gb.w);
        #pragma unroll
        for (int q = 0; q < 4; ++q) fc[q] += sigm(gff[q] + gf[q]) * cu[q];
      }
      #pragma unroll
      for (int q = 0; q < 4; ++q) {          // pairwise reduce the two child-halves
        gi[q] += __shfl_xor(gi[q], 1);
        go[q] += __shfl_xor(go[q], 1);
        gu[q] += __shfl_xor(gu[q], 1);
        fc[q] += __shfl_xor(fc[q], 1);
      }
      if (chalf == 0) {
        f4 cv, hv;
        #pragma unroll
        for (int q = 0; q < 4; ++q) {
          float c0 = sigm(gi[q]) * tanh_(gu[q]) + fc[q];
          cv[q] = c0;
          hv[q] = sigm(go[q]) * tanh_(c0);
        }
        if (ii < CAP) *(f4*)(cbw + ii * 4) = cv;
        else          *(f4*)(CbBg + (size_t)(lbeg + ii) * 4) = cv;
        unsigned long long hp =
            (unsigned long long)f2bf(hv[0]) |
            ((unsigned long long)f2bf(hv[1]) << 16) |
            ((unsigned long long)f2bf(hv[2]) << 32) |
            ((unsigned long long)f2bf(hv[3]) << 48);
        __hip_atomic_store((unsigned long long*)(p.Hb + (size_t)t * MD + s4),
                           hp, __ATOMIC_RELAXED, __HIP_MEMORY_SCOPE_AGENT);
        if (t == NN - 1) {                   // root: output (c | h) fp32
          *(f4*)(p.out + s4) = cv;
          *(f4*)(p.out + MD + s4) = hv;
        }
      }
    }
    if (d == 0) break;

    // ---- grid barrier: h of level d now visible at LLC (also block-syncs) ----
    grid_barrier(p.flags, maxd - d + 1);

    // ---- prefetch next level's XWb lines into L2 (hides LLC latency for the cell) ----
    if (d > 0) {
      const int lbeg2 = ldsDoff[d - 1];
      const int nd2 = lbeg - lbeg2;
      for (int q2 = tid; q2 < nd2; q2 += GTHR) {
        unsigned v = *(const unsigned*)(xwb + (size_t)ldsMeta[lbeg2 + q2].x * 16);
        asm volatile("" :: "v"(v));      // keep-alive (no DCE)
      }
    }

    // ---- gemm: G2L[rr][0..15] = h[node(rr)] @ Wstrip^T (16 G-cols) ----
    // 8-deep NAMED-register A pipeline (no indexed array -> no scratch).
    {
      const int ntr = (nd + 15) >> 4;
      const int lr = lane & 15;
      const int kq = lane >> 4;
      const int swz = lr & 7;
      const unsigned short* wb0 = ldsW + lr * MD;
      for (int rt = wave; rt < ntr; rt += GTHR / 64) {
        const int r = (rt << 4) + lr;
        const int pos = lbeg + ((r < nd) ? r : 0);
        const int node = ldsMeta[pos].x;
        const unsigned short* ap = p.Hb + (size_t)node * MD + (kq << 3);
        short8 A0 = *(const short8*)(ap);
        short8 A1 = *(const short8*)(ap + 32);
        short8 A2 = *(const short8*)(ap + 64);
        short8 A3 = *(const short8*)(ap + 96);
        short8 A4 = *(const short8*)(ap + 128);
        short8 A5 = *(const short8*)(ap + 160);
        short8 A6 = *(const short8*)(ap + 192);
        short8 A7 = *(const short8*)(ap + 224);
        f4 ae = {0.f, 0.f, 0.f, 0.f}, ao = {0.f, 0.f, 0.f, 0.f};
        GSTEP(A0, 0)  GSTEP(A1, 1)  GSTEP(A2, 2)  GSTEP(A3, 3)
        GSTEP(A4, 4)  GSTEP(A5, 5)  GSTEP(A6, 6)  GSTEP(A7, 7)
        GSTEP(A0, 8)  GSTEP(A1, 9)  GSTEP(A2, 10) GSTEP(A3, 11)
        GSTEP(A4, 12) GSTEP(A5, 13) GSTEP(A6, 14) GSTEP(A7, 15)
        GSTEP(A0, 16) GSTEP(A1, 17) GSTEP(A2, 18) GSTEP(A3, 19)
        GSTEP(A4, 20) GSTEP(A5, 21) GSTEP(A6, 22) GSTEP(A7, 23)
        GSTEP(A0, 24) GSTEP(A1, 25) GSTEP(A2, 26) GSTEP(A3, 27)
        GSTEP(A4, 28) GSTEP(A5, 29) GSTEP(A6, 30) GSTEP(A7, 31)
        const int rb = (rt << 4) + (kq << 2);
        #pragma unroll
        for (int q = 0; q < 4; ++q) {        // C/D: col = lane&15, row = kq*4+q
          const int rr = rb + q;
          if (rr < nd) {
            unsigned short v = f2bf(ae[q] + ao[q]);
            if (rr < CAP) G2L[rr * 16 + lr] = v;
            else          G2g[(size_t)(lbeg + rr) * 16 + lr] = v;
          }
        }
      }
    }
    __syncthreads();   // G2L/CbL handoff to next cell
  }
}

// ---------------- launch ----------------
extern "C" void kernel_launch(void* const* d_in, const int* in_sizes, int n_in,
                              void* d_out, int out_size, void* d_ws, size_t ws_size,
                              hipStream_t stream) {
  const float* X     = (const float*)d_in[0];
  const int*   parent= (const int*)d_in[1];
  const float* Wioux = (const float*)d_in[2];
  const float* bioux = (const float*)d_in[3];
  const float* Wiouh = (const float*)d_in[4];
  const float* biouh = (const float*)d_in[5];
  const float* Wfx   = (const float*)d_in[6];
  const float* bfx   = (const float*)d_in[7];
  const float* Wfh   = (const float*)d_in[8];
  const float* bfh   = (const float*)d_in[9];
  float* out = (float*)d_out;

  char* ws = (char*)d_ws;
  size_t o = 0;
  auto alloc = [&](size_t bytes) { size_t r = o; o += (bytes + 255) & ~(size_t)255; return r; };
  unsigned short* Xb   = (unsigned short*)(ws + alloc((size_t)NN * MD * 2));
  unsigned short* Wpre = (unsigned short*)(ws + alloc((size_t)NOUT * MD * 2));
  unsigned short* XWb  = (unsigned short*)(ws + alloc((size_t)GBLK * NN * 16 * 2));
  unsigned short* G2   = (unsigned short*)(ws + alloc((size_t)GBLK * NN * 16 * 2));
  float* CbB           = (float*)(ws + alloc((size_t)GBLK * NN * 4 * 4));
  unsigned short* Hb   = (unsigned short*)(ws + alloc((size_t)NN * MD * 2));
  float* biasC         = (float*)(ws + alloc((size_t)NOUT * 4));
  int2* meta           = (int2*)(ws + alloc((size_t)NN * 8));
  int* doff            = (int*)(ws + alloc((NN + 4) * 4));
  int* maxd            = (int*)(ws + alloc(256));
  int* flags           = (int*)(ws + alloc((GBLK + 64) * 4));

  {
    int n4;
    n4 = NN * MD / 4;
    cvt_bf16_kernel<<<(n4 + 255) / 256, 256, 0, stream>>>(X, Xb, n4);
    n4 = 3072 * MD / 4;
    cvt_bf16_kernel<<<(n4 + 255) / 256, 256, 0, stream>>>(Wioux, Wpre, n4);
    n4 = 1024 * MD / 4;
    cvt_bf16_kernel<<<(n4 + 255) / 256, 256, 0, stream>>>(Wfx, Wpre + (size_t)3072 * MD, n4);
  }

  prep_kernel<<<1, 1024, 0, stream>>>(parent, meta, doff, maxd, flags,
                                      bioux, biouh, bfx, bfh, biasC);

  pregemm_kernel<<<(NN / 64) * (NOUT / 64), 256, 0, stream>>>(Xb, Wpre, XWb, biasC);

  RP p;
  p.meta = meta; p.doff = doff; p.maxd = maxd;
  p.XWb = XWb; p.G2 = G2; p.CbB = CbB; p.Hb = Hb;
  p.Wiouh = Wiouh; p.Wfh = Wfh;
  p.out = out; p.flags = flags;
  void* args[] = {&p};
  hipLaunchCooperativeKernel((const void*)recur_kernel, dim3(GBLK), dim3(GTHR), args, 0, stream);

  (void)in_sizes; (void)n_in; (void)out_size; (void)ws_size;
}